// Round 9
// baseline (7652.150 us; speedup 1.0000x reference)
//
#include <hip/hip_runtime.h>

typedef unsigned short u16;
typedef __bf16 bf16x8 __attribute__((ext_vector_type(8)));
typedef unsigned short u16x8 __attribute__((ext_vector_type(8)));
typedef float f32x4 __attribute__((ext_vector_type(4)));

#define B_    64
#define NTOK  197
#define DIM   768
#define NH    12
#define LAY   12
#define HID_  3072
#define MROWS (B_*NTOK)   // 12608

#define EPI_BF16  0
#define EPI_PROJ  2
#define EPI_GELU  3
#define EPI_FC2   4
#define EPI_PATCH 5

__device__ __forceinline__ u16 f2bf(float f) {
  unsigned u = __float_as_uint(f);
  u += 0x7FFFu + ((u >> 16) & 1u);          // RNE
  return (u16)(u >> 16);
}
__device__ __forceinline__ float bf2f(u16 h) {
  return __uint_as_float(((unsigned)h) << 16);
}

__device__ __forceinline__ void gld_lds16(const void* g, void* l) {
  __builtin_amdgcn_global_load_lds(
      (const __attribute__((address_space(1))) void*)g,
      (__attribute__((address_space(3))) void*)l, 16, 0, 0);
}

// ---------------- diagnostic fill ----------------
__global__ void fill_k(float* __restrict__ o, float v, int n) {
  int i = blockIdx.x * blockDim.x + threadIdx.x;
  const int st = gridDim.x * blockDim.x;
  for (; i < n; i += st) o[i] = v;
}

// ---------------- f32 -> bf16 convert ----------------
__global__ void cvt_bf16(const float* __restrict__ in, u16* __restrict__ out, int n4) {
  int i = blockIdx.x * blockDim.x + threadIdx.x;
  const int st = gridDim.x * blockDim.x;
  for (; i < n4; i += st) {
    float4 v = ((const float4*)in)[i];
    ushort4 o;
    o.x = f2bf(v.x); o.y = f2bf(v.y); o.z = f2bf(v.z); o.w = f2bf(v.w);
    ((ushort4*)out)[i] = o;
  }
}

// ---------------- fused 4-way f32 -> bf16 convert ----------------
__global__ void cvt4_k(const float* __restrict__ s0, const float* __restrict__ s1,
                       const float* __restrict__ s2, const float* __restrict__ s3,
                       u16* __restrict__ d0, u16* __restrict__ d1,
                       u16* __restrict__ d2, u16* __restrict__ d3,
                       int n0, int n1, int n2, int n3)   // float4 counts
{
  int i = blockIdx.x * blockDim.x + threadIdx.x;
  const int st = gridDim.x * blockDim.x;
  const int total = n0 + n1 + n2 + n3;
  for (; i < total; i += st) {
    const float* s; u16* d; int j = i;
    if (j < n0) { s = s0; d = d0; }
    else { j -= n0;
      if (j < n1) { s = s1; d = d1; }
      else { j -= n1;
        if (j < n2) { s = s2; d = d2; }
        else { j -= n2; s = s3; d = d3; } } }
    float4 v = ((const float4*)s)[j];
    ushort4 o;
    o.x = f2bf(v.x); o.y = f2bf(v.y); o.z = f2bf(v.z); o.w = f2bf(v.w);
    ((ushort4*)d)[j] = o;
  }
}

// ---------------- im2col for patch conv ----------------
__global__ void im2col_k(const float* __restrict__ x, u16* __restrict__ out) {
  int i = blockIdx.x * blockDim.x + threadIdx.x;
  const int st = gridDim.x * blockDim.x;
  const int total = 12544 * 768;
  for (; i < total; i += st) {
    int row = i / 768, col = i - row * 768;
    int b = row / 196, pr = row - b * 196;
    int py = pr / 14, px = pr - py * 14;
    int cin = col >> 8, rr = col & 255;
    int ky = rr >> 4, kx = rr & 15;
    out[i] = f2bf(x[((b * 3 + cin) * 224 + py * 16 + ky) * 224 + px * 16 + kx]);
  }
}

// ---------------- cls token + pos embed row 0 ----------------
__global__ void clspos_k(const float* __restrict__ cls, const float* __restrict__ pos,
                         float* __restrict__ t) {
  int i = blockIdx.x * blockDim.x + threadIdx.x;
  if (i >= B_ * DIM) return;
  int b = i / DIM, d = i - b * DIM;
  t[(size_t)b * NTOK * DIM + d] = cls[d] + pos[d];
}

// ---------------- modulation (fp32, exact) ----------------
__global__ __launch_bounds__(256)
void modk(const float* __restrict__ lat, const float* __restrict__ w,
          const float* __restrict__ bias, float* __restrict__ out, int ldb)
{
  __shared__ float ls[32][65];
  __shared__ float wsm[64][33];
  const int tid = threadIdx.x;
  const int mat = blockIdx.y;
  const int n0 = blockIdx.x * 64;
  const int nl = tid & 63;
  const int bg = tid >> 6;
  float acc[16];
  #pragma unroll
  for (int j = 0; j < 16; ++j) acc[j] = 0.f;
  for (int k0 = 0; k0 < 768; k0 += 32) {
    __syncthreads();
    #pragma unroll
    for (int i = 0; i < 8; ++i) {
      int idx = tid + i * 256;
      int rr = idx >> 5, kk = idx & 31;
      ls[kk][rr]  = lat[rr * 768 + k0 + kk];
      wsm[rr][kk] = w[((size_t)mat * 768 + n0 + rr) * 768 + k0 + kk];
    }
    __syncthreads();
    #pragma unroll 4
    for (int kk = 0; kk < 32; ++kk) {
      float wv = wsm[nl][kk];
      #pragma unroll
      for (int j = 0; j < 16; ++j)
        acc[j] += ls[kk][bg * 16 + j] * wv;
    }
  }
  const float EQS = 0.036084391824351615f;    // 1/sqrt(768)
  const float* bs = bias + (size_t)mat * 768 + n0;
  #pragma unroll
  for (int j = 0; j < 16; ++j) {
    int b = bg * 16 + j;
    out[(size_t)b * ldb + mat * 768 + n0 + nl] = acc[j] * EQS + bs[nl];
  }
}

// ---------------- SelfModulatedLayerNorm apply ----------------
__global__ __launch_bounds__(256)
void smln_k(const float* __restrict__ x,
            const float* __restrict__ gamma, const float* __restrict__ beta, int ldg,
            float* __restrict__ oF, u16* __restrict__ oB)
{
  const int row = blockIdx.x;
  const int tid = threadIdx.x;
  const float* xr = x + (size_t)row * DIM;
  float v0 = xr[tid], v1 = xr[tid + 256], v2 = xr[tid + 512];
  float s1 = v0 + v1 + v2;
  float s2 = v0 * v0 + v1 * v1 + v2 * v2;
  #pragma unroll
  for (int o = 32; o; o >>= 1) { s1 += __shfl_xor(s1, o); s2 += __shfl_xor(s2, o); }
  __shared__ float rs[8];
  const int lane = tid & 63, wv = tid >> 6;
  if (lane == 0) { rs[wv] = s1; rs[4 + wv] = s2; }
  __syncthreads();
  s1 = rs[0] + rs[1] + rs[2] + rs[3];
  s2 = rs[4] + rs[5] + rs[6] + rs[7];
  const float mean = s1 * (1.f / 768.f);
  const float var  = s2 * (1.f / 768.f) - mean * mean;
  const float rstd = rsqrtf(var + 1e-3f);
  const int b = row / NTOK;
  const float* g  = gamma + (size_t)b * ldg;
  const float* be = beta  + (size_t)b * ldg;
  const size_t base = (size_t)row * DIM;
  float vv[3] = {v0, v1, v2};
  #pragma unroll
  for (int j = 0; j < 3; ++j) {
    int d = tid + j * 256;
    float y = (vv[j] - mean) * rstd;
    y = y * (1.f + g[d]) + be[d];
    oF[base + d] = y;
    if (oB) oB[base + d] = f2bf(y);
  }
}

// ---------------- MFMA attention: one block per (b,h) ----------------
__global__ __launch_bounds__(256)
void attn_k(const u16* __restrict__ qkv, u16* __restrict__ ao)
{
  __shared__ u16 Ks[208 * 68];
  __shared__ u16 Vt[64 * 226];
  __shared__ u16 Ps[4][16 * 228];
  const int bh = blockIdx.x;
  const int b = bh / NH, h = bh - (bh / NH) * NH;
  const int tid = threadIdx.x;
  const int lane = tid & 63, wv = tid >> 6;
  const int lr = lane & 15, kg = lane >> 4;
  const size_t tb = (size_t)(b * NTOK) * 2304 + h * 64;

  for (int t = tid; t < 1576; t += 256) {
    int n = t >> 3, c = t & 7;
    *(u16x8*)&Ks[n * 68 + c * 8] =
        *(const u16x8*)&qkv[tb + (size_t)n * 2304 + 768 + c * 8];
  }
  for (int t = tid; t < 1576; t += 256) {
    int n = t >> 3, dc = t & 7;
    u16x8 v = *(const u16x8*)&qkv[tb + (size_t)n * 2304 + 1536 + dc * 8];
    #pragma unroll
    for (int j = 0; j < 8; ++j) Vt[(dc * 8 + j) * 226 + n] = v[j];
  }
  for (int i = tid; i < 11 * 68; i += 256) Ks[197 * 68 + i] = 0;
  for (int i = tid; i < 64 * 29; i += 256) {
    int d = i / 29, c = i - d * 29;
    Vt[d * 226 + 197 + c] = 0;
  }
  for (int i = tid; i < 4 * 16 * 20; i += 256) {
    int w = i / 320, rm = i - w * 320, r = rm / 20, c = rm - r * 20;
    Ps[w][r * 228 + 208 + c] = 0;
  }
  __syncthreads();

  const f32x4 z4 = {0.f, 0.f, 0.f, 0.f};
  u16* pw = Ps[wv];

  for (int qt = wv; qt < 13; qt += 4) {
    const int q0 = qt * 16;
    const int qrow = min(q0 + lr, 196);
    const bf16x8 aq0 = *(const bf16x8*)&qkv[tb + (size_t)qrow * 2304 + kg * 8];
    const bf16x8 aq1 = *(const bf16x8*)&qkv[tb + (size_t)qrow * 2304 + 32 + kg * 8];

    f32x4 acc[13];
    #pragma unroll
    for (int ct = 0; ct < 13; ++ct) acc[ct] = z4;
    #pragma unroll
    for (int ct = 0; ct < 13; ++ct) {
      const bf16x8 bk0 = *(const bf16x8*)&Ks[(ct * 16 + lr) * 68 + kg * 8];
      const bf16x8 bk1 = *(const bf16x8*)&Ks[(ct * 16 + lr) * 68 + 32 + kg * 8];
      acc[ct] = __builtin_amdgcn_mfma_f32_16x16x32_bf16(aq0, bk0, acc[ct], 0, 0, 0);
      acc[ct] = __builtin_amdgcn_mfma_f32_16x16x32_bf16(aq1, bk1, acc[ct], 0, 0, 0);
    }

    float mx[4], sm[4], inv[4];
    #pragma unroll
    for (int r = 0; r < 4; ++r) mx[r] = -1e30f;
    #pragma unroll
    for (int ct = 0; ct < 13; ++ct)
      #pragma unroll
      for (int r = 0; r < 4; ++r) {
        float s = acc[ct][r] * 0.125f;
        if (ct * 16 + lr >= 197) s = -1e30f;
        acc[ct][r] = s;
        mx[r] = fmaxf(mx[r], s);
      }
    #pragma unroll
    for (int o = 1; o < 16; o <<= 1)
      #pragma unroll
      for (int r = 0; r < 4; ++r) mx[r] = fmaxf(mx[r], __shfl_xor(mx[r], o));
    #pragma unroll
    for (int r = 0; r < 4; ++r) sm[r] = 0.f;
    #pragma unroll
    for (int ct = 0; ct < 13; ++ct)
      #pragma unroll
      for (int r = 0; r < 4; ++r) {
        float p = __expf(acc[ct][r] - mx[r]);
        acc[ct][r] = p;
        sm[r] += p;
      }
    #pragma unroll
    for (int o = 1; o < 16; o <<= 1)
      #pragma unroll
      for (int r = 0; r < 4; ++r) sm[r] += __shfl_xor(sm[r], o);
    #pragma unroll
    for (int r = 0; r < 4; ++r) inv[r] = 1.f / sm[r];

    #pragma unroll
    for (int ct = 0; ct < 13; ++ct)
      #pragma unroll
      for (int r = 0; r < 4; ++r)
        pw[(kg * 4 + r) * 228 + ct * 16 + lr] = f2bf(acc[ct][r]);
    asm volatile("s_waitcnt lgkmcnt(0)" ::: "memory");
    __builtin_amdgcn_sched_barrier(0);

    f32x4 accO[4];
    #pragma unroll
    for (int dt = 0; dt < 4; ++dt) accO[dt] = z4;
    #pragma unroll
    for (int kt = 0; kt < 7; ++kt) {
      const bf16x8 ap = *(const bf16x8*)&pw[lr * 228 + kt * 32 + kg * 8];
      #pragma unroll
      for (int dt = 0; dt < 4; ++dt) {
        const bf16x8 bv = *(const bf16x8*)&Vt[(dt * 16 + lr) * 226 + kt * 32 + kg * 8];
        accO[dt] = __builtin_amdgcn_mfma_f32_16x16x32_bf16(ap, bv, accO[dt], 0, 0, 0);
      }
    }

    #pragma unroll
    for (int r = 0; r < 4; ++r) {
      const int q = q0 + kg * 4 + r;
      if (q < NTOK) {
        const size_t base = ((size_t)(b * NTOK + q)) * DIM + h * 64;
        #pragma unroll
        for (int dt = 0; dt < 4; ++dt)
          ao[base + dt * 16 + lr] = f2bf(accO[dt][r] * inv[r]);
      }
    }
  }
}

// ---------------- gemm8: 256x256 8-wave 4-phase bf16 GEMM (qkv / fc1) ----------------
// BK=64, 512 threads (2M x 4N waves, each 128x64 out), 128 KB double-buffered LDS,
// XOR swizzle chunk^= row&7 (rows are 128B -> T2 regime), per-phase
// {ds_read || stage} -> barrier -> lgkmcnt(0) -> setprio(1) 16 MFMA -> barrier.
// Staging for tile t+1 issued in phases 0-1 of tile t, waited at the boundary.
template<int EPI>
__global__ __launch_bounds__(512, 2)
void gemm8(const u16* __restrict__ A, int lda,
           const u16* __restrict__ Bw, int ldb,
           int M, int K, int gn,
           const float* __restrict__ bias,
           u16* __restrict__ outB, int ldo)
{
  __shared__ u16 SA[2][16384];   // [256 rows][64 k]
  __shared__ u16 SB[2][16384];
  const int tid = threadIdx.x;
  const int lane = tid & 63, wv = tid >> 6;
  const int lr = lane & 15, kg = lane >> 4;
  const int wm = wv >> 2, wn = wv & 3;

  // bijective XCD swizzle; v = tm*gn + tn (tn fastest)
  const int nwg = gridDim.x;
  const int qq = nwg >> 3, rr2 = nwg & 7;
  const int xcd = blockIdx.x & 7, loc = blockIdx.x >> 3;
  const int v = (xcd < rr2 ? xcd * (qq + 1) : rr2 * (qq + 1) + (xcd - rr2) * qq) + loc;
  const int tm = v / gn, tn = v - tm * gn;

  // staging: chunk c (16B) -> LDS row c>>3, phys slot c&7 holds k-chunk (c&7)^(row&7)
  const u16* aSrc[4];
  const u16* bSrc[4];
  #pragma unroll
  for (int j = 0; j < 4; ++j) {
    const int c = tid + j * 512;
    const int r = c >> 3, q = (c & 7) ^ (r & 7);
    int am = tm * 256 + r; if (am >= M) am = M - 1;
    aSrc[j] = A  + (size_t)am * lda + q * 8;
    bSrc[j] = Bw + (size_t)(tn * 256 + r) * ldb + q * 8;
  }

  f32x4 acc[8][4];
  const f32x4 z = {0.f, 0.f, 0.f, 0.f};
  #pragma unroll
  for (int m = 0; m < 8; ++m)
    #pragma unroll
    for (int n = 0; n < 4; ++n) acc[m][n] = z;

  const int KT = K >> 6;   // 12
  // prologue: stage tile 0 into buf 0
  #pragma unroll
  for (int j = 0; j < 4; ++j) {
    gld_lds16(aSrc[j], &SA[0][(tid + j * 512) * 8]);
    gld_lds16(bSrc[j], &SB[0][(tid + j * 512) * 8]);
  }
  asm volatile("s_waitcnt vmcnt(0)" ::: "memory");
  __builtin_amdgcn_s_barrier();
  __builtin_amdgcn_sched_barrier(0);

#define G8_PHASE(p) do { \
    bf16x8 af[2][2]; \
    _Pragma("unroll") \
    for (int ks = 0; ks < 2; ++ks) \
      _Pragma("unroll") \
      for (int mm = 0; mm < 2; ++mm) { \
        const int rrow = wm * 128 + ((p) * 2 + mm) * 16 + lr; \
        af[ks][mm] = *(const bf16x8*)&sa[rrow * 64 + ((((ks * 4 + kg) ^ (rrow & 7))) << 3)]; \
      } \
    if ((p) < 2 && pf) { \
      const int j0 = (p) * 2, j1 = (p) * 2 + 1; \
      gld_lds16(aSrc[j0] + ko, &san[(tid + j0 * 512) * 8]); \
      gld_lds16(aSrc[j1] + ko, &san[(tid + j1 * 512) * 8]); \
      gld_lds16(bSrc[j0] + ko, &sbn[(tid + j0 * 512) * 8]); \
      gld_lds16(bSrc[j1] + ko, &sbn[(tid + j1 * 512) * 8]); \
    } \
    __builtin_amdgcn_s_barrier(); \
    asm volatile("s_waitcnt lgkmcnt(0)" ::: "memory"); \
    __builtin_amdgcn_sched_barrier(0); \
    __builtin_amdgcn_s_setprio(1); \
    _Pragma("unroll") \
    for (int ks = 0; ks < 2; ++ks) \
      _Pragma("unroll") \
      for (int mm = 0; mm < 2; ++mm) \
        _Pragma("unroll") \
        for (int n = 0; n < 4; ++n) \
          acc[(p) * 2 + mm][n] = __builtin_amdgcn_mfma_f32_16x16x32_bf16( \
              af[ks][mm], bfr[ks][n], acc[(p) * 2 + mm][n], 0, 0, 0); \
    __builtin_amdgcn_s_setprio(0); \
  } while (0)

  for (int kt = 0; kt < KT; ++kt) {
    const int bu = kt & 1;
    const u16* sa = SA[bu];
    const u16* sb = SB[bu];
    u16* san = SA[bu ^ 1];
    u16* sbn = SB[bu ^ 1];
    const int ko = (kt + 1) * 64;
    const bool pf = (kt + 1 < KT);

    bf16x8 bfr[2][4];
    #pragma unroll
    for (int ks = 0; ks < 2; ++ks)
      #pragma unroll
      for (int n = 0; n < 4; ++n) {
        const int rrow = wn * 64 + n * 16 + lr;
        bfr[ks][n] = *(const bf16x8*)&sb[rrow * 64 + ((((ks * 4 + kg) ^ (rrow & 7))) << 3)];
      }

    G8_PHASE(0);
    __builtin_amdgcn_s_barrier();
    G8_PHASE(1);
    __builtin_amdgcn_s_barrier();
    G8_PHASE(2);
    __builtin_amdgcn_s_barrier();
    G8_PHASE(3);
    if (pf) { asm volatile("s_waitcnt vmcnt(0)" ::: "memory"); }
    __builtin_amdgcn_s_barrier();
    __builtin_amdgcn_sched_barrier(0);
  }
#undef G8_PHASE

  // ---- epilogue: per-wave LDS transpose -> 16B vector stores ----
  const int gr0 = tm * 256 + wm * 128;
  const int gc0 = tn * 256 + wn * 64;
  u16* T = (u16*)SA + wv * 1152;            // [16][72] per wave (private)
  #pragma unroll
  for (int m = 0; m < 8; ++m) {
    #pragma unroll
    for (int n = 0; n < 4; ++n) {
      #pragma unroll
      for (int r = 0; r < 4; ++r) {
        float val = acc[m][n][r];
        if constexpr (EPI == EPI_GELU) {
          float u = val + bias[gc0 + n * 16 + lr];
          val = 0.5f * u * (1.f + erff(u * 0.70710678118654752f));
        }
        T[(kg * 4 + r) * 72 + n * 16 + lr] = f2bf(val);
      }
    }
    asm volatile("s_waitcnt lgkmcnt(0)" ::: "memory");
    __builtin_amdgcn_sched_barrier(0);
    #pragma unroll
    for (int half = 0; half < 2; ++half) {
      int row = (lane >> 3) + half * 8;
      int c8 = lane & 7;
      u16x8 vv = *(const u16x8*)&T[row * 72 + c8 * 8];
      int gr = gr0 + m * 16 + row;
      if (gr < M) *(u16x8*)&outB[(size_t)gr * ldo + gc0 + c8 * 8] = vv;
    }
    asm volatile("s_waitcnt lgkmcnt(0)" ::: "memory");
    __builtin_amdgcn_sched_barrier(0);
  }
}

// ---------------- ring gemm: BM=BN=128, 3-buffer, counted vmcnt ----------------
// (proj / fc2 / patch: N=768 keeps the grid full where 256-wide tiles would not)
template<int EPI>
__global__ __launch_bounds__(256)
void gemm_bt(const u16* __restrict__ A, int lda,
             const u16* __restrict__ Bw, int ldb,
             int M, int K, int gn,
             const float* __restrict__ bias,
             const float* __restrict__ res,
             float* __restrict__ outF, u16* __restrict__ outB, int ldo,
             const float* __restrict__ aux)
{
  __shared__ u16 SA[3][4096];   // [128 rows][32 k] x3 ring
  __shared__ u16 SB[3][4096];
  const int tid = threadIdx.x;
  const int lane = tid & 63, wv = tid >> 6;
  const int lr = lane & 15, kg = lane >> 4;
  const int wm = wv >> 1, wn = wv & 1;

  const int nwg = gridDim.x;
  const int qq = nwg >> 3, rr2 = nwg & 7;
  const int xcd = blockIdx.x & 7, loc = blockIdx.x >> 3;
  const int v = (xcd < rr2 ? xcd * (qq + 1) : rr2 * (qq + 1) + (xcd - rr2) * qq) + loc;
  const int tm = v / gn, tn = v - tm * gn;

  const int c0 = tid, c1 = tid + 256;
  const int r0 = c0 >> 2, q0 = (c0 & 3) ^ (r0 & 3) ^ ((r0 >> 2) & 3);
  const int r1 = c1 >> 2, q1 = (c1 & 3) ^ (r1 & 3) ^ ((r1 >> 2) & 3);
  int am0 = tm * 128 + r0; if (am0 >= M) am0 = M - 1;
  int am1 = tm * 128 + r1; if (am1 >= M) am1 = M - 1;
  const u16* aS0 = A  + (size_t)am0 * lda + q0 * 8;
  const u16* aS1 = A  + (size_t)am1 * lda + q1 * 8;
  const u16* bS0 = Bw + (size_t)(tn * 128 + r0) * ldb + q0 * 8;
  const u16* bS1 = Bw + (size_t)(tn * 128 + r1) * ldb + q1 * 8;

  f32x4 acc[4][4];
  const f32x4 z = {0.f, 0.f, 0.f, 0.f};
  #pragma unroll
  for (int m = 0; m < 4; ++m)
    #pragma unroll
    for (int n = 0; n < 4; ++n) acc[m][n] = z;

#define STG(buf, ko) do { \
    u16* aD = &SA[buf][wv * 512]; u16* bD = &SB[buf][wv * 512]; \
    gld_lds16(aS0 + (ko), aD);        gld_lds16(aS1 + (ko), aD + 2048); \
    gld_lds16(bS0 + (ko), bD);        gld_lds16(bS1 + (ko), bD + 2048); \
  } while (0)

  const int KT = K >> 5;   // 24 or 96 (divisible by 3)
  STG(0, 0);
  STG(1, 32);
  asm volatile("s_waitcnt vmcnt(4)" ::: "memory");
  __builtin_amdgcn_s_barrier();
  __builtin_amdgcn_sched_barrier(0);

  #pragma unroll 1
  for (int t0 = 0; t0 < KT; t0 += 3) {
    #pragma unroll
    for (int u = 0; u < 3; ++u) {          // buf = u (compile-time)
      const int t = t0 + u;
      if (t) {
        asm volatile("s_waitcnt lgkmcnt(0)" ::: "memory");
        __builtin_amdgcn_sched_barrier(0);
        if (t + 1 < KT) asm volatile("s_waitcnt vmcnt(4)" ::: "memory");
        else            asm volatile("s_waitcnt vmcnt(0)" ::: "memory");
        __builtin_amdgcn_s_barrier();
        __builtin_amdgcn_sched_barrier(0);
      }
      if (t + 2 < KT) STG((u + 2) % 3, (t + 2) * 32);
      bf16x8 af[4], bfr[4];
      #pragma unroll
      for (int m = 0; m < 4; ++m) {
        int row = wm * 64 + m * 16 + lr;
        af[m] = *(const bf16x8*)&SA[u][row * 32 + (((kg ^ row ^ (row >> 2)) & 3) << 3)];
      }
      #pragma unroll
      for (int n = 0; n < 4; ++n) {
        int row = wn * 64 + n * 16 + lr;
        bfr[n] = *(const bf16x8*)&SB[u][row * 32 + (((kg ^ row ^ (row >> 2)) & 3) << 3)];
      }
      #pragma unroll
      for (int m = 0; m < 4; ++m)
        #pragma unroll
        for (int n = 0; n < 4; ++n)
          acc[m][n] = __builtin_amdgcn_mfma_f32_16x16x32_bf16(af[m], bfr[n], acc[m][n], 0, 0, 0);
    }
  }
#undef STG
  __syncthreads();

  // ---- epilogue: LDS transpose -> full-line vector stores ----
  const int gr0 = tm * 128 + wm * 64;
  const int gc0 = tn * 128 + wn * 64;
  if constexpr (EPI == EPI_BF16 || EPI == EPI_GELU) {
    u16* T = (u16*)SA + wv * 1152;            // [16][72] per wave
    #pragma unroll
    for (int m = 0; m < 4; ++m) {
      #pragma unroll
      for (int n = 0; n < 4; ++n) {
        #pragma unroll
        for (int r = 0; r < 4; ++r) {
          float val = acc[m][n][r];
          if constexpr (EPI == EPI_GELU) {
            float u = val + bias[gc0 + n * 16 + lr];
            val = 0.5f * u * (1.f + erff(u * 0.70710678118654752f));
          }
          T[(kg * 4 + r) * 72 + n * 16 + lr] = f2bf(val);
        }
      }
      asm volatile("s_waitcnt lgkmcnt(0)" ::: "memory");
      __builtin_amdgcn_sched_barrier(0);
      #pragma unroll
      for (int half = 0; half < 2; ++half) {
        int row = (lane >> 3) + half * 8;
        int c8 = lane & 7;
        u16x8 vv = *(const u16x8*)&T[row * 72 + c8 * 8];
        int gr = gr0 + m * 16 + row;
        if (gr < M) *(u16x8*)&outB[(size_t)gr * ldo + gc0 + c8 * 8] = vv;
      }
      asm volatile("s_waitcnt lgkmcnt(0)" ::: "memory");
      __builtin_amdgcn_sched_barrier(0);
    }
  } else {
    float* T = (float*)SA + wv * 1088;        // [16][68] per wave
    #pragma unroll
    for (int m = 0; m < 4; ++m) {
      #pragma unroll
      for (int n = 0; n < 4; ++n)
        #pragma unroll
        for (int r = 0; r < 4; ++r)
          T[(kg * 4 + r) * 68 + n * 16 + lr] = acc[m][n][r];
      asm volatile("s_waitcnt lgkmcnt(0)" ::: "memory");
      __builtin_amdgcn_sched_barrier(0);
      #pragma unroll
      for (int qu = 0; qu < 4; ++qu) {
        int row = (lane >> 4) + qu * 4;
        int c4 = lane & 15;
        f32x4 vv = *(const f32x4*)&T[row * 68 + c4 * 4];
        int gr = gr0 + m * 16 + row;
        int gc = gc0 + c4 * 4;
        if (gr < M) {
          f32x4 bv = *(const f32x4*)&bias[gc];
          if constexpr (EPI == EPI_PROJ) {
            size_t o = (size_t)gr * ldo + gc;
            f32x4 rv = *(const f32x4*)&res[o];
            f32x4 ov = vv + bv + 2.f * rv;
            *(f32x4*)&outF[o] = ov;
          } else if constexpr (EPI == EPI_FC2) {
            size_t o = (size_t)gr * ldo + gc;
            f32x4 rv = *(const f32x4*)&res[o];
            f32x4 ov = vv + bv + rv;
            *(f32x4*)&outF[o] = ov;
          } else {  // EPI_PATCH
            int pb = gr / 196, pp = gr - pb * 196;
            size_t o = ((size_t)pb * NTOK + 1 + pp) * DIM + gc;
            f32x4 av = *(const f32x4*)&aux[(size_t)(1 + pp) * DIM + gc];
            f32x4 ov;
            #pragma unroll
            for (int j = 0; j < 4; ++j) ov[j] = sinf(vv[j] + bv[j]) + av[j];
            *(f32x4*)&outF[o] = ov;
          }
        }
      }
      asm volatile("s_waitcnt lgkmcnt(0)" ::: "memory");
      __builtin_amdgcn_sched_barrier(0);
    }
  }
}

// ---------------- host ----------------
extern "C" void kernel_launch(void* const* d_in, const int* in_sizes, int n_in,
                              void* d_out, int out_size, void* d_ws, size_t ws_size,
                              hipStream_t stream)
{
  (void)in_sizes; (void)n_in;
  const float* X     = (const float*)d_in[0];
  const float* LAT   = (const float*)d_in[1];
  const float* CONVW = (const float*)d_in[2];
  const float* CONVB = (const float*)d_in[3];
  const float* CLS   = (const float*)d_in[4];
  const float* POS   = (const float*)d_in[5];
  const float* G1W   = (const float*)d_in[6];
  const float* G1B   = (const float*)d_in[7];
  const float* B1W   = (const float*)d_in[8];
  const float* B1B   = (const float*)d_in[9];
  const float* QKVW  = (const float*)d_in[10];
  const float* PROJW = (const float*)d_in[11];
  const float* PROJB = (const float*)d_in[12];
  const float* G2W   = (const float*)d_in[13];
  const float* G2B   = (const float*)d_in[14];
  const float* B2W   = (const float*)d_in[15];
  const float* B2B   = (const float*)d_in[16];
  const float* FC1W  = (const float*)d_in[17];
  const float* FC1B  = (const float*)d_in[18];
  const float* FC2W  = (const float*)d_in[19];
  const float* FC2B  = (const float*)d_in[20];
  const float* GNW   = (const float*)d_in[21];
  const float* GNB   = (const float*)d_in[22];
  const float* BNW   = (const float*)d_in[23];
  const float* BNB   = (const float*)d_in[24];

  char* p = (char*)d_ws;
  auto carve = [&](size_t bytes) { char* r = p; p += (bytes + 255) & ~(size_t)255; return r; };

  // union buffer: patches (pre-loop) / qkvb (qkv->attn) / hb (fc1->fc2)
  char* Ubuf  = carve((size_t)MROWS * HID_ * 2);            // 77.5 MB
  u16* patches = (u16*)Ubuf;
  u16* qkvb    = (u16*)Ubuf;
  u16* hb      = (u16*)Ubuf;
  u16* wconv  = (u16*)carve((size_t)768 * 768 * 2);
  u16* wqkv_l = (u16*)carve((size_t)2304 * 768 * 2);
  u16* wproj_l= (u16*)carve((size_t)768 * 768 * 2);
  u16* wfc1_l = (u16*)carve((size_t)3072 * 768 * 2);
  u16* wfc2_l = (u16*)carve((size_t)768 * 3072 * 2);
  float* tf   = (float*)carve((size_t)MROWS * 768 * 4);
  float* xnf  = (float*)carve((size_t)MROWS * 768 * 4);
  u16* xnb    = (u16*)carve((size_t)MROWS * 768 * 2);
  u16* aob    = (u16*)carve((size_t)MROWS * 768 * 2);
  float* gam1 = (float*)carve((size_t)B_ * 9216 * 4);
  float* bet1 = (float*)carve((size_t)B_ * 9216 * 4);
  float* gam2 = (float*)carve((size_t)B_ * 9216 * 4);
  float* bet2 = (float*)carve((size_t)B_ * 9216 * 4);
  float* gamN = (float*)carve((size_t)B_ * 768 * 4);
  float* betN = (float*)carve((size_t)B_ * 768 * 4);

  // canary: if guard returns, d_out stays 1e9 -> visible failure mode
  fill_k<<<1, 64, 0, stream>>>((float*)d_out, 1e9f, 1);
  if ((size_t)(p - (char*)d_ws) > ws_size) {
    fill_k<<<256, 256, 0, stream>>>((float*)d_out, 1e9f, out_size);
    return;
  }

  // modulation gammas/betas (fp32, exact)
  modk<<<dim3(12, 12), 256, 0, stream>>>(LAT, G1W, G1B, gam1, 9216);
  modk<<<dim3(12, 12), 256, 0, stream>>>(LAT, B1W, B1B, bet1, 9216);
  modk<<<dim3(12, 12), 256, 0, stream>>>(LAT, G2W, G2B, gam2, 9216);
  modk<<<dim3(12, 12), 256, 0, stream>>>(LAT, B2W, B2B, bet2, 9216);
  modk<<<dim3(12, 1),  256, 0, stream>>>(LAT, GNW, GNB, gamN, 768);
  modk<<<dim3(12, 1),  256, 0, stream>>>(LAT, BNW, BNB, betN, 768);

  // patch embed
  {
    int n4 = 768 * 768 / 4;
    cvt_bf16<<<(n4 + 255) / 256, 256, 0, stream>>>(CONVW, wconv, n4);
  }
  im2col_k<<<4096, 256, 0, stream>>>(X, patches);
  gemm_bt<EPI_PATCH><<<98 * 6, 256, 0, stream>>>(patches, 768, wconv, 768, 12544, 768, 6,
                                                 CONVB, nullptr, tf, nullptr, 768, POS);
  clspos_k<<<(B_ * DIM + 255) / 256, 256, 0, stream>>>(CLS, POS, tf);

  const int n4_qkv = 2304 * 768 / 4, n4_pro = 768 * 768 / 4, n4_fc = 3072 * 768 / 4;
  for (int l = 0; l < LAY; ++l) {
    cvt4_k<<<4096, 256, 0, stream>>>(QKVW + (size_t)l * 2304 * 768, PROJW + (size_t)l * 768 * 768,
                                     FC1W + (size_t)l * 3072 * 768, FC2W + (size_t)l * 768 * 3072,
                                     wqkv_l, wproj_l, wfc1_l, wfc2_l,
                                     n4_qkv, n4_pro, n4_fc, n4_fc);
    smln_k<<<MROWS, 256, 0, stream>>>(tf, gam1 + l * 768, bet1 + l * 768, 9216, xnf, xnb);
    gemm8<EPI_BF16><<<50 * 9, 512, 0, stream>>>(xnb, 768, wqkv_l, 768, MROWS, 768, 9,
                                                nullptr, qkvb, 2304);
    attn_k<<<B_ * NH, 256, 0, stream>>>(qkvb, aob);
    gemm_bt<EPI_PROJ><<<99 * 6, 256, 0, stream>>>(aob, 768, wproj_l, 768, MROWS, 768, 6,
                                                  PROJB + l * 768, xnf, tf, nullptr, 768, nullptr);
    smln_k<<<MROWS, 256, 0, stream>>>(tf, gam2 + l * 768, bet2 + l * 768, 9216, xnf, xnb);
    gemm8<EPI_GELU><<<50 * 12, 512, 0, stream>>>(xnb, 768, wfc1_l, 768, MROWS, 768, 12,
                                                 FC1B + l * 3072, hb, 3072);
    gemm_bt<EPI_FC2><<<99 * 6, 256, 0, stream>>>(hb, 3072, wfc2_l, 3072, MROWS, 3072, 6,
                                                 FC2B + l * 768, xnf, tf, nullptr, 768, nullptr);
  }
  smln_k<<<MROWS, 256, 0, stream>>>(tf, gamN, betN, 768, (float*)d_out, nullptr);
}

// Round 10
// 7062.685 us; speedup vs baseline: 1.0835x; 1.0835x over previous
//
#include <hip/hip_runtime.h>

typedef unsigned short u16;
typedef __bf16 bf16x8 __attribute__((ext_vector_type(8)));
typedef unsigned short u16x8 __attribute__((ext_vector_type(8)));
typedef float f32x4 __attribute__((ext_vector_type(4)));

#define B_    64
#define NTOK  197
#define DIM   768
#define NH    12
#define LAY   12
#define HID_  3072
#define MROWS (B_*NTOK)   // 12608

#define EPI_BF16  0
#define EPI_PROJ  2
#define EPI_GELU  3
#define EPI_FC2   4
#define EPI_PATCH 5

__device__ __forceinline__ u16 f2bf(float f) {
  unsigned u = __float_as_uint(f);
  u += 0x7FFFu + ((u >> 16) & 1u);          // RNE
  return (u16)(u >> 16);
}
__device__ __forceinline__ float bf2f(u16 h) {
  return __uint_as_float(((unsigned)h) << 16);
}

__device__ __forceinline__ void gld_lds16(const void* g, void* l) {
  __builtin_amdgcn_global_load_lds(
      (const __attribute__((address_space(1))) void*)g,
      (__attribute__((address_space(3))) void*)l, 16, 0, 0);
}

// ---------------- diagnostic fill ----------------
__global__ void fill_k(float* __restrict__ o, float v, int n) {
  int i = blockIdx.x * blockDim.x + threadIdx.x;
  const int st = gridDim.x * blockDim.x;
  for (; i < n; i += st) o[i] = v;
}

// ---------------- f32 -> bf16 convert ----------------
__global__ void cvt_bf16(const float* __restrict__ in, u16* __restrict__ out, int n4) {
  int i = blockIdx.x * blockDim.x + threadIdx.x;
  const int st = gridDim.x * blockDim.x;
  for (; i < n4; i += st) {
    float4 v = ((const float4*)in)[i];
    ushort4 o;
    o.x = f2bf(v.x); o.y = f2bf(v.y); o.z = f2bf(v.z); o.w = f2bf(v.w);
    ((ushort4*)out)[i] = o;
  }
}

// ---------------- fused 4-way f32 -> bf16 convert ----------------
__global__ void cvt4_k(const float* __restrict__ s0, const float* __restrict__ s1,
                       const float* __restrict__ s2, const float* __restrict__ s3,
                       u16* __restrict__ d0, u16* __restrict__ d1,
                       u16* __restrict__ d2, u16* __restrict__ d3,
                       int n0, int n1, int n2, int n3)   // float4 counts
{
  int i = blockIdx.x * blockDim.x + threadIdx.x;
  const int st = gridDim.x * blockDim.x;
  const int total = n0 + n1 + n2 + n3;
  for (; i < total; i += st) {
    const float* s; u16* d; int j = i;
    if (j < n0) { s = s0; d = d0; }
    else { j -= n0;
      if (j < n1) { s = s1; d = d1; }
      else { j -= n1;
        if (j < n2) { s = s2; d = d2; }
        else { j -= n2; s = s3; d = d3; } } }
    float4 v = ((const float4*)s)[j];
    ushort4 o;
    o.x = f2bf(v.x); o.y = f2bf(v.y); o.z = f2bf(v.z); o.w = f2bf(v.w);
    ((ushort4*)d)[j] = o;
  }
}

// ---------------- im2col for patch conv ----------------
__global__ void im2col_k(const float* __restrict__ x, u16* __restrict__ out) {
  int i = blockIdx.x * blockDim.x + threadIdx.x;
  const int st = gridDim.x * blockDim.x;
  const int total = 12544 * 768;
  for (; i < total; i += st) {
    int row = i / 768, col = i - row * 768;
    int b = row / 196, pr = row - b * 196;
    int py = pr / 14, px = pr - py * 14;
    int cin = col >> 8, rr = col & 255;
    int ky = rr >> 4, kx = rr & 15;
    out[i] = f2bf(x[((b * 3 + cin) * 224 + py * 16 + ky) * 224 + px * 16 + kx]);
  }
}

// ---------------- cls token + pos embed row 0 ----------------
__global__ void clspos_k(const float* __restrict__ cls, const float* __restrict__ pos,
                         float* __restrict__ t) {
  int i = blockIdx.x * blockDim.x + threadIdx.x;
  if (i >= B_ * DIM) return;
  int b = i / DIM, d = i - b * DIM;
  t[(size_t)b * NTOK * DIM + d] = cls[d] + pos[d];
}

// ---------------- modulation (fp32, exact) ----------------
__global__ __launch_bounds__(256)
void modk(const float* __restrict__ lat, const float* __restrict__ w,
          const float* __restrict__ bias, float* __restrict__ out, int ldb)
{
  __shared__ float ls[32][65];
  __shared__ float wsm[64][33];
  const int tid = threadIdx.x;
  const int mat = blockIdx.y;
  const int n0 = blockIdx.x * 64;
  const int nl = tid & 63;
  const int bg = tid >> 6;
  float acc[16];
  #pragma unroll
  for (int j = 0; j < 16; ++j) acc[j] = 0.f;
  for (int k0 = 0; k0 < 768; k0 += 32) {
    __syncthreads();
    #pragma unroll
    for (int i = 0; i < 8; ++i) {
      int idx = tid + i * 256;
      int rr = idx >> 5, kk = idx & 31;
      ls[kk][rr]  = lat[rr * 768 + k0 + kk];
      wsm[rr][kk] = w[((size_t)mat * 768 + n0 + rr) * 768 + k0 + kk];
    }
    __syncthreads();
    #pragma unroll 4
    for (int kk = 0; kk < 32; ++kk) {
      float wv = wsm[nl][kk];
      #pragma unroll
      for (int j = 0; j < 16; ++j)
        acc[j] += ls[kk][bg * 16 + j] * wv;
    }
  }
  const float EQS = 0.036084391824351615f;    // 1/sqrt(768)
  const float* bs = bias + (size_t)mat * 768 + n0;
  #pragma unroll
  for (int j = 0; j < 16; ++j) {
    int b = bg * 16 + j;
    out[(size_t)b * ldb + mat * 768 + n0 + nl] = acc[j] * EQS + bs[nl];
  }
}

// ---------------- SelfModulatedLayerNorm apply (oF optional) ----------------
__global__ __launch_bounds__(256)
void smln_k(const float* __restrict__ x,
            const float* __restrict__ gamma, const float* __restrict__ beta, int ldg,
            float* __restrict__ oF, u16* __restrict__ oB)
{
  const int row = blockIdx.x;
  const int tid = threadIdx.x;
  const float* xr = x + (size_t)row * DIM;
  float v0 = xr[tid], v1 = xr[tid + 256], v2 = xr[tid + 512];
  float s1 = v0 + v1 + v2;
  float s2 = v0 * v0 + v1 * v1 + v2 * v2;
  #pragma unroll
  for (int o = 32; o; o >>= 1) { s1 += __shfl_xor(s1, o); s2 += __shfl_xor(s2, o); }
  __shared__ float rs[8];
  const int lane = tid & 63, wv = tid >> 6;
  if (lane == 0) { rs[wv] = s1; rs[4 + wv] = s2; }
  __syncthreads();
  s1 = rs[0] + rs[1] + rs[2] + rs[3];
  s2 = rs[4] + rs[5] + rs[6] + rs[7];
  const float mean = s1 * (1.f / 768.f);
  const float var  = s2 * (1.f / 768.f) - mean * mean;
  const float rstd = rsqrtf(var + 1e-3f);
  const int b = row / NTOK;
  const float* g  = gamma + (size_t)b * ldg;
  const float* be = beta  + (size_t)b * ldg;
  const size_t base = (size_t)row * DIM;
  float vv[3] = {v0, v1, v2};
  #pragma unroll
  for (int j = 0; j < 3; ++j) {
    int d = tid + j * 256;
    float y = (vv[j] - mean) * rstd;
    y = y * (1.f + g[d]) + be[d];
    if (oF) oF[base + d] = y;
    if (oB) oB[base + d] = f2bf(y);
  }
}

// ---------------- MFMA attention: one block per (b,h) ----------------
__global__ __launch_bounds__(256)
void attn_k(const u16* __restrict__ qkv, u16* __restrict__ ao)
{
  __shared__ u16 Ks[208 * 68];
  __shared__ u16 Vt[64 * 226];
  __shared__ u16 Ps[4][16 * 228];
  const int bh = blockIdx.x;
  const int b = bh / NH, h = bh - (bh / NH) * NH;
  const int tid = threadIdx.x;
  const int lane = tid & 63, wv = tid >> 6;
  const int lr = lane & 15, kg = lane >> 4;
  const size_t tb = (size_t)(b * NTOK) * 2304 + h * 64;

  for (int t = tid; t < 1576; t += 256) {
    int n = t >> 3, c = t & 7;
    *(u16x8*)&Ks[n * 68 + c * 8] =
        *(const u16x8*)&qkv[tb + (size_t)n * 2304 + 768 + c * 8];
  }
  for (int t = tid; t < 1576; t += 256) {
    int n = t >> 3, dc = t & 7;
    u16x8 v = *(const u16x8*)&qkv[tb + (size_t)n * 2304 + 1536 + dc * 8];
    #pragma unroll
    for (int j = 0; j < 8; ++j) Vt[(dc * 8 + j) * 226 + n] = v[j];
  }
  for (int i = tid; i < 11 * 68; i += 256) Ks[197 * 68 + i] = 0;
  for (int i = tid; i < 64 * 29; i += 256) {
    int d = i / 29, c = i - d * 29;
    Vt[d * 226 + 197 + c] = 0;
  }
  for (int i = tid; i < 4 * 16 * 20; i += 256) {
    int w = i / 320, rm = i - w * 320, r = rm / 20, c = rm - r * 20;
    Ps[w][r * 228 + 208 + c] = 0;
  }
  __syncthreads();

  const f32x4 z4 = {0.f, 0.f, 0.f, 0.f};
  u16* pw = Ps[wv];

  for (int qt = wv; qt < 13; qt += 4) {
    const int q0 = qt * 16;
    const int qrow = min(q0 + lr, 196);
    const bf16x8 aq0 = *(const bf16x8*)&qkv[tb + (size_t)qrow * 2304 + kg * 8];
    const bf16x8 aq1 = *(const bf16x8*)&qkv[tb + (size_t)qrow * 2304 + 32 + kg * 8];

    f32x4 acc[13];
    #pragma unroll
    for (int ct = 0; ct < 13; ++ct) acc[ct] = z4;
    #pragma unroll
    for (int ct = 0; ct < 13; ++ct) {
      const bf16x8 bk0 = *(const bf16x8*)&Ks[(ct * 16 + lr) * 68 + kg * 8];
      const bf16x8 bk1 = *(const bf16x8*)&Ks[(ct * 16 + lr) * 68 + 32 + kg * 8];
      acc[ct] = __builtin_amdgcn_mfma_f32_16x16x32_bf16(aq0, bk0, acc[ct], 0, 0, 0);
      acc[ct] = __builtin_amdgcn_mfma_f32_16x16x32_bf16(aq1, bk1, acc[ct], 0, 0, 0);
    }

    float mx[4], sm[4], inv[4];
    #pragma unroll
    for (int r = 0; r < 4; ++r) mx[r] = -1e30f;
    #pragma unroll
    for (int ct = 0; ct < 13; ++ct)
      #pragma unroll
      for (int r = 0; r < 4; ++r) {
        float s = acc[ct][r] * 0.125f;
        if (ct * 16 + lr >= 197) s = -1e30f;
        acc[ct][r] = s;
        mx[r] = fmaxf(mx[r], s);
      }
    #pragma unroll
    for (int o = 1; o < 16; o <<= 1)
      #pragma unroll
      for (int r = 0; r < 4; ++r) mx[r] = fmaxf(mx[r], __shfl_xor(mx[r], o));
    #pragma unroll
    for (int r = 0; r < 4; ++r) sm[r] = 0.f;
    #pragma unroll
    for (int ct = 0; ct < 13; ++ct)
      #pragma unroll
      for (int r = 0; r < 4; ++r) {
        float p = __expf(acc[ct][r] - mx[r]);
        acc[ct][r] = p;
        sm[r] += p;
      }
    #pragma unroll
    for (int o = 1; o < 16; o <<= 1)
      #pragma unroll
      for (int r = 0; r < 4; ++r) sm[r] += __shfl_xor(sm[r], o);
    #pragma unroll
    for (int r = 0; r < 4; ++r) inv[r] = 1.f / sm[r];

    #pragma unroll
    for (int ct = 0; ct < 13; ++ct)
      #pragma unroll
      for (int r = 0; r < 4; ++r)
        pw[(kg * 4 + r) * 228 + ct * 16 + lr] = f2bf(acc[ct][r]);
    asm volatile("s_waitcnt lgkmcnt(0)" ::: "memory");
    __builtin_amdgcn_sched_barrier(0);

    f32x4 accO[4];
    #pragma unroll
    for (int dt = 0; dt < 4; ++dt) accO[dt] = z4;
    #pragma unroll
    for (int kt = 0; kt < 7; ++kt) {
      const bf16x8 ap = *(const bf16x8*)&pw[lr * 228 + kt * 32 + kg * 8];
      #pragma unroll
      for (int dt = 0; dt < 4; ++dt) {
        const bf16x8 bv = *(const bf16x8*)&Vt[(dt * 16 + lr) * 226 + kt * 32 + kg * 8];
        accO[dt] = __builtin_amdgcn_mfma_f32_16x16x32_bf16(ap, bv, accO[dt], 0, 0, 0);
      }
    }

    #pragma unroll
    for (int r = 0; r < 4; ++r) {
      const int q = q0 + kg * 4 + r;
      if (q < NTOK) {
        const size_t base = ((size_t)(b * NTOK + q)) * DIM + h * 64;
        #pragma unroll
        for (int dt = 0; dt < 4; ++dt)
          ao[base + dt * 16 + lr] = f2bf(accO[dt][r] * inv[r]);
      }
    }
  }
}

// ---------------- ring gemm: BM=BN=128, DEPTH-buffer, counted vmcnt ----------------
// DEPTH=3: 48KB LDS, 3 blocks/CU, 1-step prefetch lead (for grids <= 768 blocks).
// DEPTH=4: 64KB LDS, 2 blocks/CU, 3-step lead (~1000cyc >= HBM latency) for big grids.
// res (PROJ/FC2) is bf16.
template<int EPI, int DEPTH>
__global__ __launch_bounds__(256)
void gemm_bt(const u16* __restrict__ A, int lda,
             const u16* __restrict__ Bw, int ldb,
             int M, int K, int gn,
             const float* __restrict__ bias,
             const u16* __restrict__ res,
             float* __restrict__ outF, u16* __restrict__ outB, int ldo,
             const float* __restrict__ aux)
{
  __shared__ u16 SA[DEPTH][4096];   // [128 rows][32 k]
  __shared__ u16 SB[DEPTH][4096];
  const int tid = threadIdx.x;
  const int lane = tid & 63, wv = tid >> 6;
  const int lr = lane & 15, kg = lane >> 4;
  const int wm = wv >> 1, wn = wv & 1;

  const int nwg = gridDim.x;
  const int qq = nwg >> 3, rr2 = nwg & 7;
  const int xcd = blockIdx.x & 7, loc = blockIdx.x >> 3;
  const int v = (xcd < rr2 ? xcd * (qq + 1) : rr2 * (qq + 1) + (xcd - rr2) * qq) + loc;
  const int tm = v / gn, tn = v - tm * gn;

  const int c0 = tid, c1 = tid + 256;
  const int r0 = c0 >> 2, q0 = (c0 & 3) ^ (r0 & 3) ^ ((r0 >> 2) & 3);
  const int r1 = c1 >> 2, q1 = (c1 & 3) ^ (r1 & 3) ^ ((r1 >> 2) & 3);
  int am0 = tm * 128 + r0; if (am0 >= M) am0 = M - 1;
  int am1 = tm * 128 + r1; if (am1 >= M) am1 = M - 1;
  const u16* aS0 = A  + (size_t)am0 * lda + q0 * 8;
  const u16* aS1 = A  + (size_t)am1 * lda + q1 * 8;
  const u16* bS0 = Bw + (size_t)(tn * 128 + r0) * ldb + q0 * 8;
  const u16* bS1 = Bw + (size_t)(tn * 128 + r1) * ldb + q1 * 8;

  f32x4 acc[4][4];
  const f32x4 z = {0.f, 0.f, 0.f, 0.f};
  #pragma unroll
  for (int m = 0; m < 4; ++m)
    #pragma unroll
    for (int n = 0; n < 4; ++n) acc[m][n] = z;

#define STG(buf, ko) do { \
    u16* aD = &SA[buf][wv * 512]; u16* bD = &SB[buf][wv * 512]; \
    gld_lds16(aS0 + (ko), aD);        gld_lds16(aS1 + (ko), aD + 2048); \
    gld_lds16(bS0 + (ko), bD);        gld_lds16(bS1 + (ko), bD + 2048); \
  } while (0)

  const int KT = K >> 5;   // 24 or 96; divisible by DEPTH (3 or 4)
  #pragma unroll
  for (int d = 0; d < DEPTH - 1; ++d) STG(d, d * 32);
  if constexpr (DEPTH == 4) { asm volatile("s_waitcnt vmcnt(8)" ::: "memory"); }
  else                      { asm volatile("s_waitcnt vmcnt(4)" ::: "memory"); }
  __builtin_amdgcn_s_barrier();
  __builtin_amdgcn_sched_barrier(0);

  #pragma unroll 1
  for (int t0 = 0; t0 < KT; t0 += DEPTH) {
    #pragma unroll
    for (int u = 0; u < DEPTH; ++u) {          // buf = u (compile-time)
      const int t = t0 + u;
      if (t) {
        asm volatile("s_waitcnt lgkmcnt(0)" ::: "memory");
        __builtin_amdgcn_sched_barrier(0);
        if (t + DEPTH - 2 < KT) {
          if constexpr (DEPTH == 4) { asm volatile("s_waitcnt vmcnt(8)" ::: "memory"); }
          else                      { asm volatile("s_waitcnt vmcnt(4)" ::: "memory"); }
        } else if (t + 1 < KT) {
          asm volatile("s_waitcnt vmcnt(4)" ::: "memory");
        } else {
          asm volatile("s_waitcnt vmcnt(0)" ::: "memory");
        }
        __builtin_amdgcn_s_barrier();
        __builtin_amdgcn_sched_barrier(0);
      }
      if (t + DEPTH - 1 < KT) STG((u + DEPTH - 1) % DEPTH, (t + DEPTH - 1) * 32);
      bf16x8 af[4], bfr[4];
      #pragma unroll
      for (int m = 0; m < 4; ++m) {
        int row = wm * 64 + m * 16 + lr;
        af[m] = *(const bf16x8*)&SA[u][row * 32 + (((kg ^ row ^ (row >> 2)) & 3) << 3)];
      }
      #pragma unroll
      for (int n = 0; n < 4; ++n) {
        int row = wn * 64 + n * 16 + lr;
        bfr[n] = *(const bf16x8*)&SB[u][row * 32 + (((kg ^ row ^ (row >> 2)) & 3) << 3)];
      }
      #pragma unroll
      for (int m = 0; m < 4; ++m)
        #pragma unroll
        for (int n = 0; n < 4; ++n)
          acc[m][n] = __builtin_amdgcn_mfma_f32_16x16x32_bf16(af[m], bfr[n], acc[m][n], 0, 0, 0);
    }
  }
#undef STG
  __syncthreads();

  // ---- epilogue: LDS transpose -> full-line vector stores ----
  const int gr0 = tm * 128 + wm * 64;
  const int gc0 = tn * 128 + wn * 64;
  if constexpr (EPI == EPI_BF16 || EPI == EPI_GELU) {
    u16* T = (u16*)SA + wv * 1152;            // [16][72] per wave
    #pragma unroll
    for (int m = 0; m < 4; ++m) {
      #pragma unroll
      for (int n = 0; n < 4; ++n) {
        #pragma unroll
        for (int r = 0; r < 4; ++r) {
          float val = acc[m][n][r];
          if constexpr (EPI == EPI_GELU) {
            float u = val + bias[gc0 + n * 16 + lr];
            val = 0.5f * u * (1.f + erff(u * 0.70710678118654752f));
          }
          T[(kg * 4 + r) * 72 + n * 16 + lr] = f2bf(val);
        }
      }
      asm volatile("s_waitcnt lgkmcnt(0)" ::: "memory");
      __builtin_amdgcn_sched_barrier(0);
      #pragma unroll
      for (int half = 0; half < 2; ++half) {
        int row = (lane >> 3) + half * 8;
        int c8 = lane & 7;
        u16x8 vv = *(const u16x8*)&T[row * 72 + c8 * 8];
        int gr = gr0 + m * 16 + row;
        if (gr < M) *(u16x8*)&outB[(size_t)gr * ldo + gc0 + c8 * 8] = vv;
      }
      asm volatile("s_waitcnt lgkmcnt(0)" ::: "memory");   // reads done before T reuse
      __builtin_amdgcn_sched_barrier(0);
    }
  } else {
    float* T = (float*)SA + wv * 1088;        // [16][68] per wave
    #pragma unroll
    for (int m = 0; m < 4; ++m) {
      #pragma unroll
      for (int n = 0; n < 4; ++n)
        #pragma unroll
        for (int r = 0; r < 4; ++r)
          T[(kg * 4 + r) * 68 + n * 16 + lr] = acc[m][n][r];
      asm volatile("s_waitcnt lgkmcnt(0)" ::: "memory");
      __builtin_amdgcn_sched_barrier(0);
      #pragma unroll
      for (int qu = 0; qu < 4; ++qu) {
        int row = (lane >> 4) + qu * 4;
        int c4 = lane & 15;
        f32x4 vv = *(const f32x4*)&T[row * 68 + c4 * 4];
        int gr = gr0 + m * 16 + row;
        int gc = gc0 + c4 * 4;
        if (gr < M) {
          f32x4 bv = *(const f32x4*)&bias[gc];
          if constexpr (EPI == EPI_PROJ) {
            size_t o = (size_t)gr * ldo + gc;
            ushort4 rv = *(const ushort4*)&res[o];        // bf16 residual (xn)
            f32x4 ov;
            ov[0] = vv[0] + bv[0] + 2.f * bf2f(rv.x);
            ov[1] = vv[1] + bv[1] + 2.f * bf2f(rv.y);
            ov[2] = vv[2] + bv[2] + 2.f * bf2f(rv.z);
            ov[3] = vv[3] + bv[3] + 2.f * bf2f(rv.w);
            *(f32x4*)&outF[o] = ov;
          } else if constexpr (EPI == EPI_FC2) {
            size_t o = (size_t)gr * ldo + gc;
            ushort4 rv = *(const ushort4*)&res[o];        // bf16 residual (t2)
            f32x4 ov;
            ov[0] = vv[0] + bv[0] + bf2f(rv.x);
            ov[1] = vv[1] + bv[1] + bf2f(rv.y);
            ov[2] = vv[2] + bv[2] + bf2f(rv.z);
            ov[3] = vv[3] + bv[3] + bf2f(rv.w);
            *(f32x4*)&outF[o] = ov;
          } else {  // EPI_PATCH
            int pb = gr / 196, pp = gr - pb * 196;
            size_t o = ((size_t)pb * NTOK + 1 + pp) * DIM + gc;
            f32x4 av = *(const f32x4*)&aux[(size_t)(1 + pp) * DIM + gc];
            f32x4 ov;
            #pragma unroll
            for (int j = 0; j < 4; ++j) ov[j] = sinf(vv[j] + bv[j]) + av[j];
            *(f32x4*)&outF[o] = ov;
          }
        }
      }
      asm volatile("s_waitcnt lgkmcnt(0)" ::: "memory");
      __builtin_amdgcn_sched_barrier(0);
    }
  }
}

// ---------------- host ----------------
extern "C" void kernel_launch(void* const* d_in, const int* in_sizes, int n_in,
                              void* d_out, int out_size, void* d_ws, size_t ws_size,
                              hipStream_t stream)
{
  (void)in_sizes; (void)n_in;
  const float* X     = (const float*)d_in[0];
  const float* LAT   = (const float*)d_in[1];
  const float* CONVW = (const float*)d_in[2];
  const float* CONVB = (const float*)d_in[3];
  const float* CLS   = (const float*)d_in[4];
  const float* POS   = (const float*)d_in[5];
  const float* G1W   = (const float*)d_in[6];
  const float* G1B   = (const float*)d_in[7];
  const float* B1W   = (const float*)d_in[8];
  const float* B1B   = (const float*)d_in[9];
  const float* QKVW  = (const float*)d_in[10];
  const float* PROJW = (const float*)d_in[11];
  const float* PROJB = (const float*)d_in[12];
  const float* G2W   = (const float*)d_in[13];
  const float* G2B   = (const float*)d_in[14];
  const float* B2W   = (const float*)d_in[15];
  const float* B2B   = (const float*)d_in[16];
  const float* FC1W  = (const float*)d_in[17];
  const float* FC1B  = (const float*)d_in[18];
  const float* FC2W  = (const float*)d_in[19];
  const float* FC2B  = (const float*)d_in[20];
  const float* GNW   = (const float*)d_in[21];
  const float* GNB   = (const float*)d_in[22];
  const float* BNW   = (const float*)d_in[23];
  const float* BNB   = (const float*)d_in[24];

  char* p = (char*)d_ws;
  auto carve = [&](size_t bytes) { char* r = p; p += (bytes + 255) & ~(size_t)255; return r; };

  // union buffer: patches (pre-loop) / qkvb (qkv->attn) / hb (fc1->fc2)
  char* Ubuf  = carve((size_t)MROWS * HID_ * 2);            // 77.5 MB
  u16* patches = (u16*)Ubuf;
  u16* qkvb    = (u16*)Ubuf;
  u16* hb      = (u16*)Ubuf;
  u16* wconv  = (u16*)carve((size_t)768 * 768 * 2);
  u16* wqkv_l = (u16*)carve((size_t)2304 * 768 * 2);
  u16* wproj_l= (u16*)carve((size_t)768 * 768 * 2);
  u16* wfc1_l = (u16*)carve((size_t)3072 * 768 * 2);
  u16* wfc2_l = (u16*)carve((size_t)768 * 3072 * 2);
  float* tf   = (float*)carve((size_t)MROWS * 768 * 4);
  u16* xnb    = (u16*)carve((size_t)MROWS * 768 * 2);      // xn / t2, bf16 (also residual source)
  u16* aob    = (u16*)carve((size_t)MROWS * 768 * 2);
  float* gam1 = (float*)carve((size_t)B_ * 9216 * 4);
  float* bet1 = (float*)carve((size_t)B_ * 9216 * 4);
  float* gam2 = (float*)carve((size_t)B_ * 9216 * 4);
  float* bet2 = (float*)carve((size_t)B_ * 9216 * 4);
  float* gamN = (float*)carve((size_t)B_ * 768 * 4);
  float* betN = (float*)carve((size_t)B_ * 768 * 4);

  // canary: if guard returns, d_out stays 1e9 -> visible failure mode
  fill_k<<<1, 64, 0, stream>>>((float*)d_out, 1e9f, 1);
  if ((size_t)(p - (char*)d_ws) > ws_size) {
    fill_k<<<256, 256, 0, stream>>>((float*)d_out, 1e9f, out_size);
    return;
  }

  // modulation gammas/betas (fp32, exact)
  modk<<<dim3(12, 12), 256, 0, stream>>>(LAT, G1W, G1B, gam1, 9216);
  modk<<<dim3(12, 12), 256, 0, stream>>>(LAT, B1W, B1B, bet1, 9216);
  modk<<<dim3(12, 12), 256, 0, stream>>>(LAT, G2W, G2B, gam2, 9216);
  modk<<<dim3(12, 12), 256, 0, stream>>>(LAT, B2W, B2B, bet2, 9216);
  modk<<<dim3(12, 1),  256, 0, stream>>>(LAT, GNW, GNB, gamN, 768);
  modk<<<dim3(12, 1),  256, 0, stream>>>(LAT, BNW, BNB, betN, 768);

  // patch embed
  {
    int n4 = 768 * 768 / 4;
    cvt_bf16<<<(n4 + 255) / 256, 256, 0, stream>>>(CONVW, wconv, n4);
  }
  im2col_k<<<4096, 256, 0, stream>>>(X, patches);
  gemm_bt<EPI_PATCH, 3><<<98 * 6, 256, 0, stream>>>(patches, 768, wconv, 768, 12544, 768, 6,
                                                    CONVB, nullptr, tf, nullptr, 768, POS);
  clspos_k<<<(B_ * DIM + 255) / 256, 256, 0, stream>>>(CLS, POS, tf);

  const int n4_qkv = 2304 * 768 / 4, n4_pro = 768 * 768 / 4, n4_fc = 3072 * 768 / 4;
  for (int l = 0; l < LAY; ++l) {
    cvt4_k<<<4096, 256, 0, stream>>>(QKVW + (size_t)l * 2304 * 768, PROJW + (size_t)l * 768 * 768,
                                     FC1W + (size_t)l * 3072 * 768, FC2W + (size_t)l * 768 * 3072,
                                     wqkv_l, wproj_l, wfc1_l, wfc2_l,
                                     n4_qkv, n4_pro, n4_fc, n4_fc);
    smln_k<<<MROWS, 256, 0, stream>>>(tf, gam1 + l * 768, bet1 + l * 768, 9216, nullptr, xnb);
    gemm_bt<EPI_BF16, 4><<<99 * 18, 256, 0, stream>>>(xnb, 768, wqkv_l, 768, MROWS, 768, 18,
                                                      nullptr, nullptr, nullptr, qkvb, 2304, nullptr);
    attn_k<<<B_ * NH, 256, 0, stream>>>(qkvb, aob);
    gemm_bt<EPI_PROJ, 3><<<99 * 6, 256, 0, stream>>>(aob, 768, wproj_l, 768, MROWS, 768, 6,
                                                     PROJB + l * 768, xnb, tf, nullptr, 768, nullptr);
    smln_k<<<MROWS, 256, 0, stream>>>(tf, gam2 + l * 768, bet2 + l * 768, 9216, nullptr, xnb);
    gemm_bt<EPI_GELU, 4><<<99 * 24, 256, 0, stream>>>(xnb, 768, wfc1_l, 768, MROWS, 768, 24,
                                                      FC1B + l * 3072, nullptr, nullptr, hb, 3072, nullptr);
    gemm_bt<EPI_FC2, 3><<<99 * 6, 256, 0, stream>>>(hb, 3072, wfc2_l, 3072, MROWS, 3072, 6,
                                                    FC2B + l * 768, xnb, tf, nullptr, 768, nullptr);
  }
  smln_k<<<MROWS, 256, 0, stream>>>(tf, gamN, betN, 768, (float*)d_out, nullptr);
}

// Round 11
// 6746.236 us; speedup vs baseline: 1.1343x; 1.0469x over previous
//
#include <hip/hip_runtime.h>

typedef unsigned short u16;
typedef __bf16 bf16x8 __attribute__((ext_vector_type(8)));
typedef unsigned short u16x8 __attribute__((ext_vector_type(8)));
typedef float f32x4 __attribute__((ext_vector_type(4)));

#define B_    64
#define NTOK  197
#define DIM   768
#define NH    12
#define LAY   12
#define HID_  3072
#define MROWS (B_*NTOK)   // 12608

#define EPI_BF16  0
#define EPI_PROJ  2
#define EPI_GELU  3
#define EPI_FC2   4
#define EPI_PATCH 5

__device__ __forceinline__ u16 f2bf(float f) {
  unsigned u = __float_as_uint(f);
  u += 0x7FFFu + ((u >> 16) & 1u);          // RNE
  return (u16)(u >> 16);
}
__device__ __forceinline__ float bf2f(u16 h) {
  return __uint_as_float(((unsigned)h) << 16);
}

__device__ __forceinline__ void gld_lds16(const void* g, void* l) {
  __builtin_amdgcn_global_load_lds(
      (const __attribute__((address_space(1))) void*)g,
      (__attribute__((address_space(3))) void*)l, 16, 0, 0);
}

// ---------------- diagnostic fill ----------------
__global__ void fill_k(float* __restrict__ o, float v, int n) {
  int i = blockIdx.x * blockDim.x + threadIdx.x;
  const int st = gridDim.x * blockDim.x;
  for (; i < n; i += st) o[i] = v;
}

// ---------------- f32 -> bf16 convert ----------------
__global__ void cvt_bf16(const float* __restrict__ in, u16* __restrict__ out, int n4) {
  int i = blockIdx.x * blockDim.x + threadIdx.x;
  const int st = gridDim.x * blockDim.x;
  for (; i < n4; i += st) {
    float4 v = ((const float4*)in)[i];
    ushort4 o;
    o.x = f2bf(v.x); o.y = f2bf(v.y); o.z = f2bf(v.z); o.w = f2bf(v.w);
    ((ushort4*)out)[i] = o;
  }
}

// ---------------- fused 4-way f32 -> bf16 convert ----------------
__global__ void cvt4_k(const float* __restrict__ s0, const float* __restrict__ s1,
                       const float* __restrict__ s2, const float* __restrict__ s3,
                       u16* __restrict__ d0, u16* __restrict__ d1,
                       u16* __restrict__ d2, u16* __restrict__ d3,
                       int n0, int n1, int n2, int n3)   // float4 counts
{
  int i = blockIdx.x * blockDim.x + threadIdx.x;
  const int st = gridDim.x * blockDim.x;
  const int total = n0 + n1 + n2 + n3;
  for (; i < total; i += st) {
    const float* s; u16* d; int j = i;
    if (j < n0) { s = s0; d = d0; }
    else { j -= n0;
      if (j < n1) { s = s1; d = d1; }
      else { j -= n1;
        if (j < n2) { s = s2; d = d2; }
        else { j -= n2; s = s3; d = d3; } } }
    float4 v = ((const float4*)s)[j];
    ushort4 o;
    o.x = f2bf(v.x); o.y = f2bf(v.y); o.z = f2bf(v.z); o.w = f2bf(v.w);
    ((ushort4*)d)[j] = o;
  }
}

// ---------------- im2col for patch conv ----------------
__global__ void im2col_k(const float* __restrict__ x, u16* __restrict__ out) {
  int i = blockIdx.x * blockDim.x + threadIdx.x;
  const int st = gridDim.x * blockDim.x;
  const int total = 12544 * 768;
  for (; i < total; i += st) {
    int row = i / 768, col = i - row * 768;
    int b = row / 196, pr = row - b * 196;
    int py = pr / 14, px = pr - py * 14;
    int cin = col >> 8, rr = col & 255;
    int ky = rr >> 4, kx = rr & 15;
    out[i] = f2bf(x[((b * 3 + cin) * 224 + py * 16 + ky) * 224 + px * 16 + kx]);
  }
}

// ---------------- cls token + pos embed row 0 ----------------
__global__ void clspos_k(const float* __restrict__ cls, const float* __restrict__ pos,
                         float* __restrict__ t) {
  int i = blockIdx.x * blockDim.x + threadIdx.x;
  if (i >= B_ * DIM) return;
  int b = i / DIM, d = i - b * DIM;
  t[(size_t)b * NTOK * DIM + d] = cls[d] + pos[d];
}

// ---------------- modulation (fp32, exact) ----------------
__global__ __launch_bounds__(256)
void modk(const float* __restrict__ lat, const float* __restrict__ w,
          const float* __restrict__ bias, float* __restrict__ out, int ldb)
{
  __shared__ float ls[32][65];
  __shared__ float wsm[64][33];
  const int tid = threadIdx.x;
  const int mat = blockIdx.y;
  const int n0 = blockIdx.x * 64;
  const int nl = tid & 63;
  const int bg = tid >> 6;
  float acc[16];
  #pragma unroll
  for (int j = 0; j < 16; ++j) acc[j] = 0.f;
  for (int k0 = 0; k0 < 768; k0 += 32) {
    __syncthreads();
    #pragma unroll
    for (int i = 0; i < 8; ++i) {
      int idx = tid + i * 256;
      int rr = idx >> 5, kk = idx & 31;
      ls[kk][rr]  = lat[rr * 768 + k0 + kk];
      wsm[rr][kk] = w[((size_t)mat * 768 + n0 + rr) * 768 + k0 + kk];
    }
    __syncthreads();
    #pragma unroll 4
    for (int kk = 0; kk < 32; ++kk) {
      float wv = wsm[nl][kk];
      #pragma unroll
      for (int j = 0; j < 16; ++j)
        acc[j] += ls[kk][bg * 16 + j] * wv;
    }
  }
  const float EQS = 0.036084391824351615f;    // 1/sqrt(768)
  const float* bs = bias + (size_t)mat * 768 + n0;
  #pragma unroll
  for (int j = 0; j < 16; ++j) {
    int b = bg * 16 + j;
    out[(size_t)b * ldb + mat * 768 + n0 + nl] = acc[j] * EQS + bs[nl];
  }
}

// ---------------- SelfModulatedLayerNorm apply (oF optional) ----------------
__global__ __launch_bounds__(256)
void smln_k(const float* __restrict__ x,
            const float* __restrict__ gamma, const float* __restrict__ beta, int ldg,
            float* __restrict__ oF, u16* __restrict__ oB)
{
  const int row = blockIdx.x;
  const int tid = threadIdx.x;
  const float* xr = x + (size_t)row * DIM;
  float v0 = xr[tid], v1 = xr[tid + 256], v2 = xr[tid + 512];
  float s1 = v0 + v1 + v2;
  float s2 = v0 * v0 + v1 * v1 + v2 * v2;
  #pragma unroll
  for (int o = 32; o; o >>= 1) { s1 += __shfl_xor(s1, o); s2 += __shfl_xor(s2, o); }
  __shared__ float rs[8];
  const int lane = tid & 63, wv = tid >> 6;
  if (lane == 0) { rs[wv] = s1; rs[4 + wv] = s2; }
  __syncthreads();
  s1 = rs[0] + rs[1] + rs[2] + rs[3];
  s2 = rs[4] + rs[5] + rs[6] + rs[7];
  const float mean = s1 * (1.f / 768.f);
  const float var  = s2 * (1.f / 768.f) - mean * mean;
  const float rstd = rsqrtf(var + 1e-3f);
  const int b = row / NTOK;
  const float* g  = gamma + (size_t)b * ldg;
  const float* be = beta  + (size_t)b * ldg;
  const size_t base = (size_t)row * DIM;
  float vv[3] = {v0, v1, v2};
  #pragma unroll
  for (int j = 0; j < 3; ++j) {
    int d = tid + j * 256;
    float y = (vv[j] - mean) * rstd;
    y = y * (1.f + g[d]) + be[d];
    if (oF) oF[base + d] = y;
    if (oB) oB[base + d] = f2bf(y);
  }
}

// ---------------- MFMA attention: one block per (b,h) ----------------
__global__ __launch_bounds__(256)
void attn_k(const u16* __restrict__ qkv, u16* __restrict__ ao)
{
  __shared__ u16 Ks[208 * 68];
  __shared__ u16 Vt[64 * 226];
  __shared__ u16 Ps[4][16 * 228];
  const int bh = blockIdx.x;
  const int b = bh / NH, h = bh - (bh / NH) * NH;
  const int tid = threadIdx.x;
  const int lane = tid & 63, wv = tid >> 6;
  const int lr = lane & 15, kg = lane >> 4;
  const size_t tb = (size_t)(b * NTOK) * 2304 + h * 64;

  for (int t = tid; t < 1576; t += 256) {
    int n = t >> 3, c = t & 7;
    *(u16x8*)&Ks[n * 68 + c * 8] =
        *(const u16x8*)&qkv[tb + (size_t)n * 2304 + 768 + c * 8];
  }
  for (int t = tid; t < 1576; t += 256) {
    int n = t >> 3, dc = t & 7;
    u16x8 v = *(const u16x8*)&qkv[tb + (size_t)n * 2304 + 1536 + dc * 8];
    #pragma unroll
    for (int j = 0; j < 8; ++j) Vt[(dc * 8 + j) * 226 + n] = v[j];
  }
  for (int i = tid; i < 11 * 68; i += 256) Ks[197 * 68 + i] = 0;
  for (int i = tid; i < 64 * 29; i += 256) {
    int d = i / 29, c = i - d * 29;
    Vt[d * 226 + 197 + c] = 0;
  }
  for (int i = tid; i < 4 * 16 * 20; i += 256) {
    int w = i / 320, rm = i - w * 320, r = rm / 20, c = rm - r * 20;
    Ps[w][r * 228 + 208 + c] = 0;
  }
  __syncthreads();

  const f32x4 z4 = {0.f, 0.f, 0.f, 0.f};
  u16* pw = Ps[wv];

  for (int qt = wv; qt < 13; qt += 4) {
    const int q0 = qt * 16;
    const int qrow = min(q0 + lr, 196);
    const bf16x8 aq0 = *(const bf16x8*)&qkv[tb + (size_t)qrow * 2304 + kg * 8];
    const bf16x8 aq1 = *(const bf16x8*)&qkv[tb + (size_t)qrow * 2304 + 32 + kg * 8];

    f32x4 acc[13];
    #pragma unroll
    for (int ct = 0; ct < 13; ++ct) acc[ct] = z4;
    #pragma unroll
    for (int ct = 0; ct < 13; ++ct) {
      const bf16x8 bk0 = *(const bf16x8*)&Ks[(ct * 16 + lr) * 68 + kg * 8];
      const bf16x8 bk1 = *(const bf16x8*)&Ks[(ct * 16 + lr) * 68 + 32 + kg * 8];
      acc[ct] = __builtin_amdgcn_mfma_f32_16x16x32_bf16(aq0, bk0, acc[ct], 0, 0, 0);
      acc[ct] = __builtin_amdgcn_mfma_f32_16x16x32_bf16(aq1, bk1, acc[ct], 0, 0, 0);
    }

    float mx[4], sm[4], inv[4];
    #pragma unroll
    for (int r = 0; r < 4; ++r) mx[r] = -1e30f;
    #pragma unroll
    for (int ct = 0; ct < 13; ++ct)
      #pragma unroll
      for (int r = 0; r < 4; ++r) {
        float s = acc[ct][r] * 0.125f;
        if (ct * 16 + lr >= 197) s = -1e30f;
        acc[ct][r] = s;
        mx[r] = fmaxf(mx[r], s);
      }
    #pragma unroll
    for (int o = 1; o < 16; o <<= 1)
      #pragma unroll
      for (int r = 0; r < 4; ++r) mx[r] = fmaxf(mx[r], __shfl_xor(mx[r], o));
    #pragma unroll
    for (int r = 0; r < 4; ++r) sm[r] = 0.f;
    #pragma unroll
    for (int ct = 0; ct < 13; ++ct)
      #pragma unroll
      for (int r = 0; r < 4; ++r) {
        float p = __expf(acc[ct][r] - mx[r]);
        acc[ct][r] = p;
        sm[r] += p;
      }
    #pragma unroll
    for (int o = 1; o < 16; o <<= 1)
      #pragma unroll
      for (int r = 0; r < 4; ++r) sm[r] += __shfl_xor(sm[r], o);
    #pragma unroll
    for (int r = 0; r < 4; ++r) inv[r] = 1.f / sm[r];

    #pragma unroll
    for (int ct = 0; ct < 13; ++ct)
      #pragma unroll
      for (int r = 0; r < 4; ++r)
        pw[(kg * 4 + r) * 228 + ct * 16 + lr] = f2bf(acc[ct][r]);
    asm volatile("s_waitcnt lgkmcnt(0)" ::: "memory");
    __builtin_amdgcn_sched_barrier(0);

    f32x4 accO[4];
    #pragma unroll
    for (int dt = 0; dt < 4; ++dt) accO[dt] = z4;
    #pragma unroll
    for (int kt = 0; kt < 7; ++kt) {
      const bf16x8 ap = *(const bf16x8*)&pw[lr * 228 + kt * 32 + kg * 8];
      #pragma unroll
      for (int dt = 0; dt < 4; ++dt) {
        const bf16x8 bv = *(const bf16x8*)&Vt[(dt * 16 + lr) * 226 + kt * 32 + kg * 8];
        accO[dt] = __builtin_amdgcn_mfma_f32_16x16x32_bf16(ap, bv, accO[dt], 0, 0, 0);
      }
    }

    #pragma unroll
    for (int r = 0; r < 4; ++r) {
      const int q = q0 + kg * 4 + r;
      if (q < NTOK) {
        const size_t base = ((size_t)(b * NTOK + q)) * DIM + h * 64;
        #pragma unroll
        for (int dt = 0; dt < 4; ++dt)
          ao[base + dt * 16 + lr] = f2bf(accO[dt][r] * inv[r]);
      }
    }
  }
}

// ---------------- ring gemm: BM=BN=128, 3-buffer, counted vmcnt ----------------
// K-loop waits use asm-with-memory-clobber only (correct ordering of memory ops);
// NO sched_barrier(0) in the loop -> compiler free to interleave ds_read/MFMA
// across phase boundaries with counted lgkmcnt (m97-style). res is bf16.
template<int EPI>
__global__ __launch_bounds__(256)
void gemm_bt(const u16* __restrict__ A, int lda,
             const u16* __restrict__ Bw, int ldb,
             int M, int K, int gn,
             const float* __restrict__ bias,
             const u16* __restrict__ res,
             float* __restrict__ outF, u16* __restrict__ outB, int ldo,
             const float* __restrict__ aux)
{
  __shared__ u16 SA[3][4096];   // [128 rows][32 k] x3 ring
  __shared__ u16 SB[3][4096];
  const int tid = threadIdx.x;
  const int lane = tid & 63, wv = tid >> 6;
  const int lr = lane & 15, kg = lane >> 4;
  const int wm = wv >> 1, wn = wv & 1;

  const int nwg = gridDim.x;
  const int qq = nwg >> 3, rr2 = nwg & 7;
  const int xcd = blockIdx.x & 7, loc = blockIdx.x >> 3;
  const int v = (xcd < rr2 ? xcd * (qq + 1) : rr2 * (qq + 1) + (xcd - rr2) * qq) + loc;
  const int tm = v / gn, tn = v - tm * gn;

  const int c0 = tid, c1 = tid + 256;
  const int r0 = c0 >> 2, q0 = (c0 & 3) ^ (r0 & 3) ^ ((r0 >> 2) & 3);
  const int r1 = c1 >> 2, q1 = (c1 & 3) ^ (r1 & 3) ^ ((r1 >> 2) & 3);
  int am0 = tm * 128 + r0; if (am0 >= M) am0 = M - 1;
  int am1 = tm * 128 + r1; if (am1 >= M) am1 = M - 1;
  const u16* aS0 = A  + (size_t)am0 * lda + q0 * 8;
  const u16* aS1 = A  + (size_t)am1 * lda + q1 * 8;
  const u16* bS0 = Bw + (size_t)(tn * 128 + r0) * ldb + q0 * 8;
  const u16* bS1 = Bw + (size_t)(tn * 128 + r1) * ldb + q1 * 8;

  f32x4 acc[4][4];
  const f32x4 z = {0.f, 0.f, 0.f, 0.f};
  #pragma unroll
  for (int m = 0; m < 4; ++m)
    #pragma unroll
    for (int n = 0; n < 4; ++n) acc[m][n] = z;

#define STG(buf, ko) do { \
    u16* aD = &SA[buf][wv * 512]; u16* bD = &SB[buf][wv * 512]; \
    gld_lds16(aS0 + (ko), aD);        gld_lds16(aS1 + (ko), aD + 2048); \
    gld_lds16(bS0 + (ko), bD);        gld_lds16(bS1 + (ko), bD + 2048); \
  } while (0)

  const int KT = K >> 5;   // 24 or 96 (divisible by 3)
  STG(0, 0);
  STG(1, 32);
  asm volatile("s_waitcnt vmcnt(4)" ::: "memory");
  __builtin_amdgcn_s_barrier();

  #pragma unroll 1
  for (int t0 = 0; t0 < KT; t0 += 3) {
    #pragma unroll
    for (int u = 0; u < 3; ++u) {          // buf = u (compile-time)
      const int t = t0 + u;
      if (t) {
        asm volatile("s_waitcnt lgkmcnt(0)" ::: "memory");   // my reads of old buf done
        if (t + 1 < KT) asm volatile("s_waitcnt vmcnt(4)" ::: "memory");
        else            asm volatile("s_waitcnt vmcnt(0)" ::: "memory");
        __builtin_amdgcn_s_barrier();
      }
      if (t + 2 < KT) STG((u + 2) % 3, (t + 2) * 32);
      bf16x8 af[4], bfr[4];
      #pragma unroll
      for (int m = 0; m < 4; ++m) {
        int row = wm * 64 + m * 16 + lr;
        af[m] = *(const bf16x8*)&SA[u][row * 32 + (((kg ^ row ^ (row >> 2)) & 3) << 3)];
      }
      #pragma unroll
      for (int n = 0; n < 4; ++n) {
        int row = wn * 64 + n * 16 + lr;
        bfr[n] = *(const bf16x8*)&SB[u][row * 32 + (((kg ^ row ^ (row >> 2)) & 3) << 3)];
      }
      #pragma unroll
      for (int m = 0; m < 4; ++m)
        #pragma unroll
        for (int n = 0; n < 4; ++n)
          acc[m][n] = __builtin_amdgcn_mfma_f32_16x16x32_bf16(af[m], bfr[n], acc[m][n], 0, 0, 0);
    }
  }
#undef STG
  __syncthreads();   // all waves done with LDS before epilogue reuse

  // ---- epilogue: LDS transpose -> full-line vector stores ----
  const int gr0 = tm * 128 + wm * 64;
  const int gc0 = tn * 128 + wn * 64;
  if constexpr (EPI == EPI_BF16 || EPI == EPI_GELU) {
    u16* T = (u16*)SA + wv * 1152;            // [16][72] per wave
    #pragma unroll
    for (int m = 0; m < 4; ++m) {
      #pragma unroll
      for (int n = 0; n < 4; ++n) {
        #pragma unroll
        for (int r = 0; r < 4; ++r) {
          float val = acc[m][n][r];
          if constexpr (EPI == EPI_GELU) {
            float u = val + bias[gc0 + n * 16 + lr];
            val = 0.5f * u * (1.f + erff(u * 0.70710678118654752f));
          }
          T[(kg * 4 + r) * 72 + n * 16 + lr] = f2bf(val);
        }
      }
      asm volatile("s_waitcnt lgkmcnt(0)" ::: "memory");
      __builtin_amdgcn_sched_barrier(0);
      #pragma unroll
      for (int half = 0; half < 2; ++half) {
        int row = (lane >> 3) + half * 8;
        int c8 = lane & 7;
        u16x8 vv = *(const u16x8*)&T[row * 72 + c8 * 8];
        int gr = gr0 + m * 16 + row;
        if (gr < M) *(u16x8*)&outB[(size_t)gr * ldo + gc0 + c8 * 8] = vv;
      }
      asm volatile("s_waitcnt lgkmcnt(0)" ::: "memory");   // reads done before T reuse
      __builtin_amdgcn_sched_barrier(0);
    }
  } else {
    float* T = (float*)SA + wv * 1088;        // [16][68] per wave
    #pragma unroll
    for (int m = 0; m < 4; ++m) {
      #pragma unroll
      for (int n = 0; n < 4; ++n)
        #pragma unroll
        for (int r = 0; r < 4; ++r)
          T[(kg * 4 + r) * 68 + n * 16 + lr] = acc[m][n][r];
      asm volatile("s_waitcnt lgkmcnt(0)" ::: "memory");
      __builtin_amdgcn_sched_barrier(0);
      #pragma unroll
      for (int qu = 0; qu < 4; ++qu) {
        int row = (lane >> 4) + qu * 4;
        int c4 = lane & 15;
        f32x4 vv = *(const f32x4*)&T[row * 68 + c4 * 4];
        int gr = gr0 + m * 16 + row;
        int gc = gc0 + c4 * 4;
        if (gr < M) {
          f32x4 bv = *(const f32x4*)&bias[gc];
          if constexpr (EPI == EPI_PROJ) {
            size_t o = (size_t)gr * ldo + gc;
            ushort4 rv = *(const ushort4*)&res[o];        // bf16 residual (xn)
            f32x4 ov;
            ov[0] = vv[0] + bv[0] + 2.f * bf2f(rv.x);
            ov[1] = vv[1] + bv[1] + 2.f * bf2f(rv.y);
            ov[2] = vv[2] + bv[2] + 2.f * bf2f(rv.z);
            ov[3] = vv[3] + bv[3] + 2.f * bf2f(rv.w);
            *(f32x4*)&outF[o] = ov;
          } else if constexpr (EPI == EPI_FC2) {
            size_t o = (size_t)gr * ldo + gc;
            ushort4 rv = *(const ushort4*)&res[o];        // bf16 residual (t2)
            f32x4 ov;
            ov[0] = vv[0] + bv[0] + bf2f(rv.x);
            ov[1] = vv[1] + bv[1] + bf2f(rv.y);
            ov[2] = vv[2] + bv[2] + bf2f(rv.z);
            ov[3] = vv[3] + bv[3] + bf2f(rv.w);
            *(f32x4*)&outF[o] = ov;
          } else {  // EPI_PATCH
            int pb = gr / 196, pp = gr - pb * 196;
            size_t o = ((size_t)pb * NTOK + 1 + pp) * DIM + gc;
            f32x4 av = *(const f32x4*)&aux[(size_t)(1 + pp) * DIM + gc];
            f32x4 ov;
            #pragma unroll
            for (int j = 0; j < 4; ++j) ov[j] = sinf(vv[j] + bv[j]) + av[j];
            *(f32x4*)&outF[o] = ov;
          }
        }
      }
      asm volatile("s_waitcnt lgkmcnt(0)" ::: "memory");
      __builtin_amdgcn_sched_barrier(0);
    }
  }
}

// ---------------- host ----------------
extern "C" void kernel_launch(void* const* d_in, const int* in_sizes, int n_in,
                              void* d_out, int out_size, void* d_ws, size_t ws_size,
                              hipStream_t stream)
{
  (void)in_sizes; (void)n_in;
  const float* X     = (const float*)d_in[0];
  const float* LAT   = (const float*)d_in[1];
  const float* CONVW = (const float*)d_in[2];
  const float* CONVB = (const float*)d_in[3];
  const float* CLS   = (const float*)d_in[4];
  const float* POS   = (const float*)d_in[5];
  const float* G1W   = (const float*)d_in[6];
  const float* G1B   = (const float*)d_in[7];
  const float* B1W   = (const float*)d_in[8];
  const float* B1B   = (const float*)d_in[9];
  const float* QKVW  = (const float*)d_in[10];
  const float* PROJW = (const float*)d_in[11];
  const float* PROJB = (const float*)d_in[12];
  const float* G2W   = (const float*)d_in[13];
  const float* G2B   = (const float*)d_in[14];
  const float* B2W   = (const float*)d_in[15];
  const float* B2B   = (const float*)d_in[16];
  const float* FC1W  = (const float*)d_in[17];
  const float* FC1B  = (const float*)d_in[18];
  const float* FC2W  = (const float*)d_in[19];
  const float* FC2B  = (const float*)d_in[20];
  const float* GNW   = (const float*)d_in[21];
  const float* GNB   = (const float*)d_in[22];
  const float* BNW   = (const float*)d_in[23];
  const float* BNB   = (const float*)d_in[24];

  char* p = (char*)d_ws;
  auto carve = [&](size_t bytes) { char* r = p; p += (bytes + 255) & ~(size_t)255; return r; };

  // union buffer: patches (pre-loop) / qkvb (qkv->attn) / hb (fc1->fc2)
  char* Ubuf  = carve((size_t)MROWS * HID_ * 2);            // 77.5 MB
  u16* patches = (u16*)Ubuf;
  u16* qkvb    = (u16*)Ubuf;
  u16* hb      = (u16*)Ubuf;
  u16* wconv  = (u16*)carve((size_t)768 * 768 * 2);
  u16* wqkv_l = (u16*)carve((size_t)2304 * 768 * 2);
  u16* wproj_l= (u16*)carve((size_t)768 * 768 * 2);
  u16* wfc1_l = (u16*)carve((size_t)3072 * 768 * 2);
  u16* wfc2_l = (u16*)carve((size_t)768 * 3072 * 2);
  float* tf   = (float*)carve((size_t)MROWS * 768 * 4);
  u16* xnb    = (u16*)carve((size_t)MROWS * 768 * 2);      // xn / t2, bf16 (also residual source)
  u16* aob    = (u16*)carve((size_t)MROWS * 768 * 2);
  float* gam1 = (float*)carve((size_t)B_ * 9216 * 4);
  float* bet1 = (float*)carve((size_t)B_ * 9216 * 4);
  float* gam2 = (float*)carve((size_t)B_ * 9216 * 4);
  float* bet2 = (float*)carve((size_t)B_ * 9216 * 4);
  float* gamN = (float*)carve((size_t)B_ * 768 * 4);
  float* betN = (float*)carve((size_t)B_ * 768 * 4);

  // canary: if guard returns, d_out stays 1e9 -> visible failure mode
  fill_k<<<1, 64, 0, stream>>>((float*)d_out, 1e9f, 1);
  if ((size_t)(p - (char*)d_ws) > ws_size) {
    fill_k<<<256, 256, 0, stream>>>((float*)d_out, 1e9f, out_size);
    return;
  }

  // modulation gammas/betas (fp32, exact)
  modk<<<dim3(12, 12), 256, 0, stream>>>(LAT, G1W, G1B, gam1, 9216);
  modk<<<dim3(12, 12), 256, 0, stream>>>(LAT, B1W, B1B, bet1, 9216);
  modk<<<dim3(12, 12), 256, 0, stream>>>(LAT, G2W, G2B, gam2, 9216);
  modk<<<dim3(12, 12), 256, 0, stream>>>(LAT, B2W, B2B, bet2, 9216);
  modk<<<dim3(12, 1),  256, 0, stream>>>(LAT, GNW, GNB, gamN, 768);
  modk<<<dim3(12, 1),  256, 0, stream>>>(LAT, BNW, BNB, betN, 768);

  // patch embed
  {
    int n4 = 768 * 768 / 4;
    cvt_bf16<<<(n4 + 255) / 256, 256, 0, stream>>>(CONVW, wconv, n4);
  }
  im2col_k<<<4096, 256, 0, stream>>>(X, patches);
  gemm_bt<EPI_PATCH><<<98 * 6, 256, 0, stream>>>(patches, 768, wconv, 768, 12544, 768, 6,
                                                 CONVB, nullptr, tf, nullptr, 768, POS);
  clspos_k<<<(B_ * DIM + 255) / 256, 256, 0, stream>>>(CLS, POS, tf);

  const int n4_qkv = 2304 * 768 / 4, n4_pro = 768 * 768 / 4, n4_fc = 3072 * 768 / 4;
  for (int l = 0; l < LAY; ++l) {
    cvt4_k<<<4096, 256, 0, stream>>>(QKVW + (size_t)l * 2304 * 768, PROJW + (size_t)l * 768 * 768,
                                     FC1W + (size_t)l * 3072 * 768, FC2W + (size_t)l * 768 * 3072,
                                     wqkv_l, wproj_l, wfc1_l, wfc2_l,
                                     n4_qkv, n4_pro, n4_fc, n4_fc);
    smln_k<<<MROWS, 256, 0, stream>>>(tf, gam1 + l * 768, bet1 + l * 768, 9216, nullptr, xnb);
    gemm_bt<EPI_BF16><<<99 * 18, 256, 0, stream>>>(xnb, 768, wqkv_l, 768, MROWS, 768, 18,
                                                   nullptr, nullptr, nullptr, qkvb, 2304, nullptr);
    attn_k<<<B_ * NH, 256, 0, stream>>>(qkvb, aob);
    gemm_bt<EPI_PROJ><<<99 * 6, 256, 0, stream>>>(aob, 768, wproj_l, 768, MROWS, 768, 6,
                                                  PROJB + l * 768, xnb, tf, nullptr, 768, nullptr);
    smln_k<<<MROWS, 256, 0, stream>>>(tf, gam2 + l * 768, bet2 + l * 768, 9216, nullptr, xnb);
    gemm_bt<EPI_GELU><<<99 * 24, 256, 0, stream>>>(xnb, 768, wfc1_l, 768, MROWS, 768, 24,
                                                   FC1B + l * 3072, nullptr, nullptr, hb, 3072, nullptr);
    gemm_bt<EPI_FC2><<<99 * 6, 256, 0, stream>>>(hb, 3072, wfc2_l, 3072, MROWS, 3072, 6,
                                                 FC2B + l * 768, xnb, tf, nullptr, 768, nullptr);
  }
  smln_k<<<MROWS, 256, 0, stream>>>(tf, gamN, betN, 768, (float*)d_out, nullptr);
}

// Round 12
// 6684.522 us; speedup vs baseline: 1.1448x; 1.0092x over previous
//
#include <hip/hip_runtime.h>

typedef unsigned short u16;
typedef __bf16 bf16x8 __attribute__((ext_vector_type(8)));
typedef unsigned short u16x8 __attribute__((ext_vector_type(8)));
typedef float f32x4 __attribute__((ext_vector_type(4)));

#define B_    64
#define NTOK  197
#define DIM   768
#define NH    12
#define LAY   12
#define HID_  3072
#define MROWS (B_*NTOK)   // 12608

#define EPI_BF16  0
#define EPI_PROJ  2
#define EPI_GELU  3
#define EPI_FC2   4
#define EPI_PATCH 5

__device__ __forceinline__ u16 f2bf(float f) {
  unsigned u = __float_as_uint(f);
  u += 0x7FFFu + ((u >> 16) & 1u);          // RNE
  return (u16)(u >> 16);
}
__device__ __forceinline__ float bf2f(u16 h) {
  return __uint_as_float(((unsigned)h) << 16);
}

__device__ __forceinline__ void gld_lds16(const void* g, void* l) {
  __builtin_amdgcn_global_load_lds(
      (const __attribute__((address_space(1))) void*)g,
      (__attribute__((address_space(3))) void*)l, 16, 0, 0);
}

// ---------------- diagnostic fill ----------------
__global__ void fill_k(float* __restrict__ o, float v, int n) {
  int i = blockIdx.x * blockDim.x + threadIdx.x;
  const int st = gridDim.x * blockDim.x;
  for (; i < n; i += st) o[i] = v;
}

// ---------------- f32 -> bf16 convert ----------------
__global__ void cvt_bf16(const float* __restrict__ in, u16* __restrict__ out, int n4) {
  int i = blockIdx.x * blockDim.x + threadIdx.x;
  const int st = gridDim.x * blockDim.x;
  for (; i < n4; i += st) {
    float4 v = ((const float4*)in)[i];
    ushort4 o;
    o.x = f2bf(v.x); o.y = f2bf(v.y); o.z = f2bf(v.z); o.w = f2bf(v.w);
    ((ushort4*)out)[i] = o;
  }
}

// ---------------- fused 4-way f32 -> bf16 convert ----------------
__global__ void cvt4_k(const float* __restrict__ s0, const float* __restrict__ s1,
                       const float* __restrict__ s2, const float* __restrict__ s3,
                       u16* __restrict__ d0, u16* __restrict__ d1,
                       u16* __restrict__ d2, u16* __restrict__ d3,
                       int n0, int n1, int n2, int n3)   // float4 counts
{
  int i = blockIdx.x * blockDim.x + threadIdx.x;
  const int st = gridDim.x * blockDim.x;
  const int total = n0 + n1 + n2 + n3;
  for (; i < total; i += st) {
    const float* s; u16* d; int j = i;
    if (j < n0) { s = s0; d = d0; }
    else { j -= n0;
      if (j < n1) { s = s1; d = d1; }
      else { j -= n1;
        if (j < n2) { s = s2; d = d2; }
        else { j -= n2; s = s3; d = d3; } } }
    float4 v = ((const float4*)s)[j];
    ushort4 o;
    o.x = f2bf(v.x); o.y = f2bf(v.y); o.z = f2bf(v.z); o.w = f2bf(v.w);
    ((ushort4*)d)[j] = o;
  }
}

// ---------------- im2col for patch conv ----------------
__global__ void im2col_k(const float* __restrict__ x, u16* __restrict__ out) {
  int i = blockIdx.x * blockDim.x + threadIdx.x;
  const int st = gridDim.x * blockDim.x;
  const int total = 12544 * 768;
  for (; i < total; i += st) {
    int row = i / 768, col = i - row * 768;
    int b = row / 196, pr = row - b * 196;
    int py = pr / 14, px = pr - py * 14;
    int cin = col >> 8, rr = col & 255;
    int ky = rr >> 4, kx = rr & 15;
    out[i] = f2bf(x[((b * 3 + cin) * 224 + py * 16 + ky) * 224 + px * 16 + kx]);
  }
}

// ---------------- cls token + pos embed row 0 ----------------
__global__ void clspos_k(const float* __restrict__ cls, const float* __restrict__ pos,
                         float* __restrict__ t) {
  int i = blockIdx.x * blockDim.x + threadIdx.x;
  if (i >= B_ * DIM) return;
  int b = i / DIM, d = i - b * DIM;
  t[(size_t)b * NTOK * DIM + d] = cls[d] + pos[d];
}

// ---------------- modulation (fp32, exact) ----------------
__global__ __launch_bounds__(256)
void modk(const float* __restrict__ lat, const float* __restrict__ w,
          const float* __restrict__ bias, float* __restrict__ out, int ldb)
{
  __shared__ float ls[32][65];
  __shared__ float wsm[64][33];
  const int tid = threadIdx.x;
  const int mat = blockIdx.y;
  const int n0 = blockIdx.x * 64;
  const int nl = tid & 63;
  const int bg = tid >> 6;
  float acc[16];
  #pragma unroll
  for (int j = 0; j < 16; ++j) acc[j] = 0.f;
  for (int k0 = 0; k0 < 768; k0 += 32) {
    __syncthreads();
    #pragma unroll
    for (int i = 0; i < 8; ++i) {
      int idx = tid + i * 256;
      int rr = idx >> 5, kk = idx & 31;
      ls[kk][rr]  = lat[rr * 768 + k0 + kk];
      wsm[rr][kk] = w[((size_t)mat * 768 + n0 + rr) * 768 + k0 + kk];
    }
    __syncthreads();
    #pragma unroll 4
    for (int kk = 0; kk < 32; ++kk) {
      float wv = wsm[nl][kk];
      #pragma unroll
      for (int j = 0; j < 16; ++j)
        acc[j] += ls[kk][bg * 16 + j] * wv;
    }
  }
  const float EQS = 0.036084391824351615f;    // 1/sqrt(768)
  const float* bs = bias + (size_t)mat * 768 + n0;
  #pragma unroll
  for (int j = 0; j < 16; ++j) {
    int b = bg * 16 + j;
    out[(size_t)b * ldb + mat * 768 + n0 + nl] = acc[j] * EQS + bs[nl];
  }
}

// ---------------- SelfModulatedLayerNorm apply (oF optional) ----------------
__global__ __launch_bounds__(256)
void smln_k(const float* __restrict__ x,
            const float* __restrict__ gamma, const float* __restrict__ beta, int ldg,
            float* __restrict__ oF, u16* __restrict__ oB)
{
  const int row = blockIdx.x;
  const int tid = threadIdx.x;
  const float* xr = x + (size_t)row * DIM;
  float v0 = xr[tid], v1 = xr[tid + 256], v2 = xr[tid + 512];
  float s1 = v0 + v1 + v2;
  float s2 = v0 * v0 + v1 * v1 + v2 * v2;
  #pragma unroll
  for (int o = 32; o; o >>= 1) { s1 += __shfl_xor(s1, o); s2 += __shfl_xor(s2, o); }
  __shared__ float rs[8];
  const int lane = tid & 63, wv = tid >> 6;
  if (lane == 0) { rs[wv] = s1; rs[4 + wv] = s2; }
  __syncthreads();
  s1 = rs[0] + rs[1] + rs[2] + rs[3];
  s2 = rs[4] + rs[5] + rs[6] + rs[7];
  const float mean = s1 * (1.f / 768.f);
  const float var  = s2 * (1.f / 768.f) - mean * mean;
  const float rstd = rsqrtf(var + 1e-3f);
  const int b = row / NTOK;
  const float* g  = gamma + (size_t)b * ldg;
  const float* be = beta  + (size_t)b * ldg;
  const size_t base = (size_t)row * DIM;
  float vv[3] = {v0, v1, v2};
  #pragma unroll
  for (int j = 0; j < 3; ++j) {
    int d = tid + j * 256;
    float y = (vv[j] - mean) * rstd;
    y = y * (1.f + g[d]) + be[d];
    if (oF) oF[base + d] = y;
    if (oB) oB[base + d] = f2bf(y);
  }
}

// ---------------- MFMA attention: one block per (b,h) ----------------
__global__ __launch_bounds__(256)
void attn_k(const u16* __restrict__ qkv, u16* __restrict__ ao)
{
  __shared__ u16 Ks[208 * 68];
  __shared__ u16 Vt[64 * 226];
  __shared__ u16 Ps[4][16 * 228];
  const int bh = blockIdx.x;
  const int b = bh / NH, h = bh - (bh / NH) * NH;
  const int tid = threadIdx.x;
  const int lane = tid & 63, wv = tid >> 6;
  const int lr = lane & 15, kg = lane >> 4;
  const size_t tb = (size_t)(b * NTOK) * 2304 + h * 64;

  for (int t = tid; t < 1576; t += 256) {
    int n = t >> 3, c = t & 7;
    *(u16x8*)&Ks[n * 68 + c * 8] =
        *(const u16x8*)&qkv[tb + (size_t)n * 2304 + 768 + c * 8];
  }
  for (int t = tid; t < 1576; t += 256) {
    int n = t >> 3, dc = t & 7;
    u16x8 v = *(const u16x8*)&qkv[tb + (size_t)n * 2304 + 1536 + dc * 8];
    #pragma unroll
    for (int j = 0; j < 8; ++j) Vt[(dc * 8 + j) * 226 + n] = v[j];
  }
  for (int i = tid; i < 11 * 68; i += 256) Ks[197 * 68 + i] = 0;
  for (int i = tid; i < 64 * 29; i += 256) {
    int d = i / 29, c = i - d * 29;
    Vt[d * 226 + 197 + c] = 0;
  }
  for (int i = tid; i < 4 * 16 * 20; i += 256) {
    int w = i / 320, rm = i - w * 320, r = rm / 20, c = rm - r * 20;
    Ps[w][r * 228 + 208 + c] = 0;
  }
  __syncthreads();

  const f32x4 z4 = {0.f, 0.f, 0.f, 0.f};
  u16* pw = Ps[wv];

  for (int qt = wv; qt < 13; qt += 4) {
    const int q0 = qt * 16;
    const int qrow = min(q0 + lr, 196);
    const bf16x8 aq0 = *(const bf16x8*)&qkv[tb + (size_t)qrow * 2304 + kg * 8];
    const bf16x8 aq1 = *(const bf16x8*)&qkv[tb + (size_t)qrow * 2304 + 32 + kg * 8];

    f32x4 acc[13];
    #pragma unroll
    for (int ct = 0; ct < 13; ++ct) acc[ct] = z4;
    #pragma unroll
    for (int ct = 0; ct < 13; ++ct) {
      const bf16x8 bk0 = *(const bf16x8*)&Ks[(ct * 16 + lr) * 68 + kg * 8];
      const bf16x8 bk1 = *(const bf16x8*)&Ks[(ct * 16 + lr) * 68 + 32 + kg * 8];
      acc[ct] = __builtin_amdgcn_mfma_f32_16x16x32_bf16(aq0, bk0, acc[ct], 0, 0, 0);
      acc[ct] = __builtin_amdgcn_mfma_f32_16x16x32_bf16(aq1, bk1, acc[ct], 0, 0, 0);
    }

    float mx[4], sm[4], inv[4];
    #pragma unroll
    for (int r = 0; r < 4; ++r) mx[r] = -1e30f;
    #pragma unroll
    for (int ct = 0; ct < 13; ++ct)
      #pragma unroll
      for (int r = 0; r < 4; ++r) {
        float s = acc[ct][r] * 0.125f;
        if (ct * 16 + lr >= 197) s = -1e30f;
        acc[ct][r] = s;
        mx[r] = fmaxf(mx[r], s);
      }
    #pragma unroll
    for (int o = 1; o < 16; o <<= 1)
      #pragma unroll
      for (int r = 0; r < 4; ++r) mx[r] = fmaxf(mx[r], __shfl_xor(mx[r], o));
    #pragma unroll
    for (int r = 0; r < 4; ++r) sm[r] = 0.f;
    #pragma unroll
    for (int ct = 0; ct < 13; ++ct)
      #pragma unroll
      for (int r = 0; r < 4; ++r) {
        float p = __expf(acc[ct][r] - mx[r]);
        acc[ct][r] = p;
        sm[r] += p;
      }
    #pragma unroll
    for (int o = 1; o < 16; o <<= 1)
      #pragma unroll
      for (int r = 0; r < 4; ++r) sm[r] += __shfl_xor(sm[r], o);
    #pragma unroll
    for (int r = 0; r < 4; ++r) inv[r] = 1.f / sm[r];

    #pragma unroll
    for (int ct = 0; ct < 13; ++ct)
      #pragma unroll
      for (int r = 0; r < 4; ++r)
        pw[(kg * 4 + r) * 228 + ct * 16 + lr] = f2bf(acc[ct][r]);
    asm volatile("s_waitcnt lgkmcnt(0)" ::: "memory");
    __builtin_amdgcn_sched_barrier(0);

    f32x4 accO[4];
    #pragma unroll
    for (int dt = 0; dt < 4; ++dt) accO[dt] = z4;
    #pragma unroll
    for (int kt = 0; kt < 7; ++kt) {
      const bf16x8 ap = *(const bf16x8*)&pw[lr * 228 + kt * 32 + kg * 8];
      #pragma unroll
      for (int dt = 0; dt < 4; ++dt) {
        const bf16x8 bv = *(const bf16x8*)&Vt[(dt * 16 + lr) * 226 + kt * 32 + kg * 8];
        accO[dt] = __builtin_amdgcn_mfma_f32_16x16x32_bf16(ap, bv, accO[dt], 0, 0, 0);
      }
    }

    #pragma unroll
    for (int r = 0; r < 4; ++r) {
      const int q = q0 + kg * 4 + r;
      if (q < NTOK) {
        const size_t base = ((size_t)(b * NTOK + q)) * DIM + h * 64;
        #pragma unroll
        for (int dt = 0; dt < 4; ++dt)
          ao[base + dt * 16 + lr] = f2bf(accO[dt][r] * inv[r]);
      }
    }
  }
}

// ---------------- ring gemm: BM=BN=128, 3-buffer, counted vmcnt ----------------
// L2-fitting hierarchical block order: grid = 8 * mpx * gn; each XCD owns mpx
// contiguous tm rows; within XCD iterate (tn-chunk of TC, tm, tn-in-chunk) so the
// XCD's A-chunk (~2.5MB) and the TC B-col-panels (<=1.6MB) are L2-co-resident ->
// A fetched once total, B fetched once per XCD. Dead blocks (tm >= gm) exit early.
template<int EPI>
__global__ __launch_bounds__(256)
void gemm_bt(const u16* __restrict__ A, int lda,
             const u16* __restrict__ Bw, int ldb,
             int M, int K, int gm, int gn, int TC, int mpx,
             const float* __restrict__ bias,
             const u16* __restrict__ res,
             float* __restrict__ outF, u16* __restrict__ outB, int ldo,
             const float* __restrict__ aux)
{
  __shared__ u16 SA[3][4096];   // [128 rows][32 k] x3 ring
  __shared__ u16 SB[3][4096];
  const int tid = threadIdx.x;
  const int lane = tid & 63, wv = tid >> 6;
  const int lr = lane & 15, kg = lane >> 4;
  const int wm = wv >> 1, wn = wv & 1;

  // hierarchical decode (gn % TC == 0 guaranteed by host)
  const int xcd = blockIdx.x & 7, loc = blockIdx.x >> 3;
  const int c    = loc / (mpx * TC);
  const int rem  = loc - c * (mpx * TC);
  const int mloc = rem / TC;
  const int tm   = xcd * mpx + mloc;
  const int tn   = c * TC + (rem - mloc * TC);
  if (tm >= gm) return;                 // pad block: exits before any barrier

  const int c0 = tid, c1 = tid + 256;
  const int r0 = c0 >> 2, q0 = (c0 & 3) ^ (r0 & 3) ^ ((r0 >> 2) & 3);
  const int r1 = c1 >> 2, q1 = (c1 & 3) ^ (r1 & 3) ^ ((r1 >> 2) & 3);
  int am0 = tm * 128 + r0; if (am0 >= M) am0 = M - 1;
  int am1 = tm * 128 + r1; if (am1 >= M) am1 = M - 1;
  const u16* aS0 = A  + (size_t)am0 * lda + q0 * 8;
  const u16* aS1 = A  + (size_t)am1 * lda + q1 * 8;
  const u16* bS0 = Bw + (size_t)(tn * 128 + r0) * ldb + q0 * 8;
  const u16* bS1 = Bw + (size_t)(tn * 128 + r1) * ldb + q1 * 8;

  f32x4 acc[4][4];
  const f32x4 z = {0.f, 0.f, 0.f, 0.f};
  #pragma unroll
  for (int m = 0; m < 4; ++m)
    #pragma unroll
    for (int n = 0; n < 4; ++n) acc[m][n] = z;

#define STG(buf, ko) do { \
    u16* aD = &SA[buf][wv * 512]; u16* bD = &SB[buf][wv * 512]; \
    gld_lds16(aS0 + (ko), aD);        gld_lds16(aS1 + (ko), aD + 2048); \
    gld_lds16(bS0 + (ko), bD);        gld_lds16(bS1 + (ko), bD + 2048); \
  } while (0)

  const int KT = K >> 5;   // 24 or 96 (divisible by 3)
  STG(0, 0);
  STG(1, 32);
  asm volatile("s_waitcnt vmcnt(4)" ::: "memory");
  __builtin_amdgcn_s_barrier();

  #pragma unroll 1
  for (int t0 = 0; t0 < KT; t0 += 3) {
    #pragma unroll
    for (int u = 0; u < 3; ++u) {          // buf = u (compile-time)
      const int t = t0 + u;
      if (t) {
        asm volatile("s_waitcnt lgkmcnt(0)" ::: "memory");   // my reads of old buf done
        if (t + 1 < KT) asm volatile("s_waitcnt vmcnt(4)" ::: "memory");
        else            asm volatile("s_waitcnt vmcnt(0)" ::: "memory");
        __builtin_amdgcn_s_barrier();
      }
      if (t + 2 < KT) STG((u + 2) % 3, (t + 2) * 32);
      bf16x8 af[4], bfr[4];
      #pragma unroll
      for (int m = 0; m < 4; ++m) {
        int row = wm * 64 + m * 16 + lr;
        af[m] = *(const bf16x8*)&SA[u][row * 32 + (((kg ^ row ^ (row >> 2)) & 3) << 3)];
      }
      #pragma unroll
      for (int n = 0; n < 4; ++n) {
        int row = wn * 64 + n * 16 + lr;
        bfr[n] = *(const bf16x8*)&SB[u][row * 32 + (((kg ^ row ^ (row >> 2)) & 3) << 3)];
      }
      #pragma unroll
      for (int m = 0; m < 4; ++m)
        #pragma unroll
        for (int n = 0; n < 4; ++n)
          acc[m][n] = __builtin_amdgcn_mfma_f32_16x16x32_bf16(af[m], bfr[n], acc[m][n], 0, 0, 0);
    }
  }
#undef STG
  __syncthreads();   // all waves done with LDS before epilogue reuse

  // ---- epilogue: LDS transpose -> full-line vector stores ----
  const int gr0 = tm * 128 + wm * 64;
  const int gc0 = tn * 128 + wn * 64;
  if constexpr (EPI == EPI_BF16 || EPI == EPI_GELU) {
    u16* T = (u16*)SA + wv * 1152;            // [16][72] per wave
    #pragma unroll
    for (int m = 0; m < 4; ++m) {
      #pragma unroll
      for (int n = 0; n < 4; ++n) {
        #pragma unroll
        for (int r = 0; r < 4; ++r) {
          float val = acc[m][n][r];
          if constexpr (EPI == EPI_GELU) {
            float u = val + bias[gc0 + n * 16 + lr];
            val = 0.5f * u * (1.f + erff(u * 0.70710678118654752f));
          }
          T[(kg * 4 + r) * 72 + n * 16 + lr] = f2bf(val);
        }
      }
      asm volatile("s_waitcnt lgkmcnt(0)" ::: "memory");
      __builtin_amdgcn_sched_barrier(0);
      #pragma unroll
      for (int half = 0; half < 2; ++half) {
        int row = (lane >> 3) + half * 8;
        int c8 = lane & 7;
        u16x8 vv = *(const u16x8*)&T[row * 72 + c8 * 8];
        int gr = gr0 + m * 16 + row;
        if (gr < M) *(u16x8*)&outB[(size_t)gr * ldo + gc0 + c8 * 8] = vv;
      }
      asm volatile("s_waitcnt lgkmcnt(0)" ::: "memory");   // reads done before T reuse
      __builtin_amdgcn_sched_barrier(0);
    }
  } else {
    float* T = (float*)SA + wv * 1088;        // [16][68] per wave
    #pragma unroll
    for (int m = 0; m < 4; ++m) {
      #pragma unroll
      for (int n = 0; n < 4; ++n)
        #pragma unroll
        for (int r = 0; r < 4; ++r)
          T[(kg * 4 + r) * 68 + n * 16 + lr] = acc[m][n][r];
      asm volatile("s_waitcnt lgkmcnt(0)" ::: "memory");
      __builtin_amdgcn_sched_barrier(0);
      #pragma unroll
      for (int qu = 0; qu < 4; ++qu) {
        int row = (lane >> 4) + qu * 4;
        int c4 = lane & 15;
        f32x4 vv = *(const f32x4*)&T[row * 68 + c4 * 4];
        int gr = gr0 + m * 16 + row;
        int gc = gc0 + c4 * 4;
        if (gr < M) {
          f32x4 bv = *(const f32x4*)&bias[gc];
          if constexpr (EPI == EPI_PROJ) {
            size_t o = (size_t)gr * ldo + gc;
            ushort4 rv = *(const ushort4*)&res[o];        // bf16 residual (xn)
            f32x4 ov;
            ov[0] = vv[0] + bv[0] + 2.f * bf2f(rv.x);
            ov[1] = vv[1] + bv[1] + 2.f * bf2f(rv.y);
            ov[2] = vv[2] + bv[2] + 2.f * bf2f(rv.z);
            ov[3] = vv[3] + bv[3] + 2.f * bf2f(rv.w);
            *(f32x4*)&outF[o] = ov;
          } else if constexpr (EPI == EPI_FC2) {
            size_t o = (size_t)gr * ldo + gc;
            ushort4 rv = *(const ushort4*)&res[o];        // bf16 residual (t2)
            f32x4 ov;
            ov[0] = vv[0] + bv[0] + bf2f(rv.x);
            ov[1] = vv[1] + bv[1] + bf2f(rv.y);
            ov[2] = vv[2] + bv[2] + bf2f(rv.z);
            ov[3] = vv[3] + bv[3] + bf2f(rv.w);
            *(f32x4*)&outF[o] = ov;
          } else {  // EPI_PATCH
            int pb = gr / 196, pp = gr - pb * 196;
            size_t o = ((size_t)pb * NTOK + 1 + pp) * DIM + gc;
            f32x4 av = *(const f32x4*)&aux[(size_t)(1 + pp) * DIM + gc];
            f32x4 ov;
            #pragma unroll
            for (int j = 0; j < 4; ++j) ov[j] = sinf(vv[j] + bv[j]) + av[j];
            *(f32x4*)&outF[o] = ov;
          }
        }
      }
      asm volatile("s_waitcnt lgkmcnt(0)" ::: "memory");
      __builtin_amdgcn_sched_barrier(0);
    }
  }
}

// ---------------- host ----------------
extern "C" void kernel_launch(void* const* d_in, const int* in_sizes, int n_in,
                              void* d_out, int out_size, void* d_ws, size_t ws_size,
                              hipStream_t stream)
{
  (void)in_sizes; (void)n_in;
  const float* X     = (const float*)d_in[0];
  const float* LAT   = (const float*)d_in[1];
  const float* CONVW = (const float*)d_in[2];
  const float* CONVB = (const float*)d_in[3];
  const float* CLS   = (const float*)d_in[4];
  const float* POS   = (const float*)d_in[5];
  const float* G1W   = (const float*)d_in[6];
  const float* G1B   = (const float*)d_in[7];
  const float* B1W   = (const float*)d_in[8];
  const float* B1B   = (const float*)d_in[9];
  const float* QKVW  = (const float*)d_in[10];
  const float* PROJW = (const float*)d_in[11];
  const float* PROJB = (const float*)d_in[12];
  const float* G2W   = (const float*)d_in[13];
  const float* G2B   = (const float*)d_in[14];
  const float* B2W   = (const float*)d_in[15];
  const float* B2B   = (const float*)d_in[16];
  const float* FC1W  = (const float*)d_in[17];
  const float* FC1B  = (const float*)d_in[18];
  const float* FC2W  = (const float*)d_in[19];
  const float* FC2B  = (const float*)d_in[20];
  const float* GNW   = (const float*)d_in[21];
  const float* GNB   = (const float*)d_in[22];
  const float* BNW   = (const float*)d_in[23];
  const float* BNB   = (const float*)d_in[24];

  char* p = (char*)d_ws;
  auto carve = [&](size_t bytes) { char* r = p; p += (bytes + 255) & ~(size_t)255; return r; };

  // union buffer: patches (pre-loop) / qkvb (qkv->attn) / hb (fc1->fc2)
  char* Ubuf  = carve((size_t)MROWS * HID_ * 2);            // 77.5 MB
  u16* patches = (u16*)Ubuf;
  u16* qkvb    = (u16*)Ubuf;
  u16* hb      = (u16*)Ubuf;
  u16* wconv  = (u16*)carve((size_t)768 * 768 * 2);
  u16* wqkv_l = (u16*)carve((size_t)2304 * 768 * 2);
  u16* wproj_l= (u16*)carve((size_t)768 * 768 * 2);
  u16* wfc1_l = (u16*)carve((size_t)3072 * 768 * 2);
  u16* wfc2_l = (u16*)carve((size_t)768 * 3072 * 2);
  float* tf   = (float*)carve((size_t)MROWS * 768 * 4);
  u16* xnb    = (u16*)carve((size_t)MROWS * 768 * 2);      // xn / t2, bf16 (also residual source)
  u16* aob    = (u16*)carve((size_t)MROWS * 768 * 2);
  float* gam1 = (float*)carve((size_t)B_ * 9216 * 4);
  float* bet1 = (float*)carve((size_t)B_ * 9216 * 4);
  float* gam2 = (float*)carve((size_t)B_ * 9216 * 4);
  float* bet2 = (float*)carve((size_t)B_ * 9216 * 4);
  float* gamN = (float*)carve((size_t)B_ * 768 * 4);
  float* betN = (float*)carve((size_t)B_ * 768 * 4);

  // canary: if guard returns, d_out stays 1e9 -> visible failure mode
  fill_k<<<1, 64, 0, stream>>>((float*)d_out, 1e9f, 1);
  if ((size_t)(p - (char*)d_ws) > ws_size) {
    fill_k<<<256, 256, 0, stream>>>((float*)d_out, 1e9f, out_size);
    return;
  }

  // modulation gammas/betas (fp32, exact)
  modk<<<dim3(12, 12), 256, 0, stream>>>(LAT, G1W, G1B, gam1, 9216);
  modk<<<dim3(12, 12), 256, 0, stream>>>(LAT, B1W, B1B, bet1, 9216);
  modk<<<dim3(12, 12), 256, 0, stream>>>(LAT, G2W, G2B, gam2, 9216);
  modk<<<dim3(12, 12), 256, 0, stream>>>(LAT, B2W, B2B, bet2, 9216);
  modk<<<dim3(12, 1),  256, 0, stream>>>(LAT, GNW, GNB, gamN, 768);
  modk<<<dim3(12, 1),  256, 0, stream>>>(LAT, BNW, BNB, betN, 768);

  // patch embed
  {
    int n4 = 768 * 768 / 4;
    cvt_bf16<<<(n4 + 255) / 256, 256, 0, stream>>>(CONVW, wconv, n4);
  }
  im2col_k<<<4096, 256, 0, stream>>>(X, patches);
  // gm=98, gn=6, TC=6, mpx=13 -> grid 8*13*6 = 624
  gemm_bt<EPI_PATCH><<<624, 256, 0, stream>>>(patches, 768, wconv, 768, 12544, 768, 98, 6, 6, 13,
                                              CONVB, nullptr, tf, nullptr, 768, POS);
  clspos_k<<<(B_ * DIM + 255) / 256, 256, 0, stream>>>(CLS, POS, tf);

  const int n4_qkv = 2304 * 768 / 4, n4_pro = 768 * 768 / 4, n4_fc = 3072 * 768 / 4;
  for (int l = 0; l < LAY; ++l) {
    cvt4_k<<<4096, 256, 0, stream>>>(QKVW + (size_t)l * 2304 * 768, PROJW + (size_t)l * 768 * 768,
                                     FC1W + (size_t)l * 3072 * 768, FC2W + (size_t)l * 768 * 3072,
                                     wqkv_l, wproj_l, wfc1_l, wfc2_l,
                                     n4_qkv, n4_pro, n4_fc, n4_fc);
    smln_k<<<MROWS, 256, 0, stream>>>(tf, gam1 + l * 768, bet1 + l * 768, 9216, nullptr, xnb);
    // qkv: gm=99, gn=18, TC=6 (B-chunk 1.18MB + A-chunk 2.5MB < 4MB), mpx=13 -> 1872
    gemm_bt<EPI_BF16><<<1872, 256, 0, stream>>>(xnb, 768, wqkv_l, 768, MROWS, 768, 99, 18, 6, 13,
                                                nullptr, nullptr, nullptr, qkvb, 2304, nullptr);
    attn_k<<<B_ * NH, 256, 0, stream>>>(qkvb, aob);
    // proj: gm=99, gn=6, TC=6, mpx=13 -> 624
    gemm_bt<EPI_PROJ><<<624, 256, 0, stream>>>(aob, 768, wproj_l, 768, MROWS, 768, 99, 6, 6, 13,
                                               PROJB + l * 768, xnb, tf, nullptr, 768, nullptr);
    smln_k<<<MROWS, 256, 0, stream>>>(tf, gam2 + l * 768, bet2 + l * 768, 9216, nullptr, xnb);
    // fc1: gm=99, gn=24, TC=8 (B-chunk 1.57MB + A-chunk 2.5MB ~ 4MB), mpx=13 -> 2496
    gemm_bt<EPI_GELU><<<2496, 256, 0, stream>>>(xnb, 768, wfc1_l, 768, MROWS, 768, 99, 24, 8, 13,
                                                FC1B + l * 3072, nullptr, nullptr, hb, 3072, nullptr);
    // fc2: gm=99, gn=6, TC=6, mpx=13 -> 624
    gemm_bt<EPI_FC2><<<624, 256, 0, stream>>>(hb, 3072, wfc2_l, 3072, MROWS, 3072, 99, 6, 6, 13,
                                              FC2B + l * 768, xnb, tf, nullptr, 768, nullptr);
  }
  smln_k<<<MROWS, 256, 0, stream>>>(tf, gamN, betN, 768, (float*)d_out, nullptr);
}

// Round 13
// 6621.651 us; speedup vs baseline: 1.1556x; 1.0095x over previous
//
#include <hip/hip_runtime.h>

typedef unsigned short u16;
typedef __bf16 bf16x8 __attribute__((ext_vector_type(8)));
typedef unsigned short u16x8 __attribute__((ext_vector_type(8)));
typedef float f32x4 __attribute__((ext_vector_type(4)));

#define B_    64
#define NTOK  197
#define DIM   768
#define NH    12
#define LAY   12
#define HID_  3072
#define MROWS (B_*NTOK)   // 12608

#define EPI_BF16  0
#define EPI_PROJ  2
#define EPI_GELU  3
#define EPI_FC2   4
#define EPI_PATCH 5

__device__ __forceinline__ u16 f2bf(float f) {
  unsigned u = __float_as_uint(f);
  u += 0x7FFFu + ((u >> 16) & 1u);          // RNE
  return (u16)(u >> 16);
}
__device__ __forceinline__ float bf2f(u16 h) {
  return __uint_as_float(((unsigned)h) << 16);
}

__device__ __forceinline__ void gld_lds16(const void* g, void* l) {
  __builtin_amdgcn_global_load_lds(
      (const __attribute__((address_space(1))) void*)g,
      (__attribute__((address_space(3))) void*)l, 16, 0, 0);
}

// ---------------- diagnostic fill ----------------
__global__ void fill_k(float* __restrict__ o, float v, int n) {
  int i = blockIdx.x * blockDim.x + threadIdx.x;
  const int st = gridDim.x * blockDim.x;
  for (; i < n; i += st) o[i] = v;
}

// ---------------- f32 -> bf16 convert ----------------
__global__ void cvt_bf16(const float* __restrict__ in, u16* __restrict__ out, int n4) {
  int i = blockIdx.x * blockDim.x + threadIdx.x;
  const int st = gridDim.x * blockDim.x;
  for (; i < n4; i += st) {
    float4 v = ((const float4*)in)[i];
    ushort4 o;
    o.x = f2bf(v.x); o.y = f2bf(v.y); o.z = f2bf(v.z); o.w = f2bf(v.w);
    ((ushort4*)out)[i] = o;
  }
}

// ---------------- fused 4-way f32 -> bf16 convert ----------------
__global__ void cvt4_k(const float* __restrict__ s0, const float* __restrict__ s1,
                       const float* __restrict__ s2, const float* __restrict__ s3,
                       u16* __restrict__ d0, u16* __restrict__ d1,
                       u16* __restrict__ d2, u16* __restrict__ d3,
                       int n0, int n1, int n2, int n3)   // float4 counts
{
  int i = blockIdx.x * blockDim.x + threadIdx.x;
  const int st = gridDim.x * blockDim.x;
  const int total = n0 + n1 + n2 + n3;
  for (; i < total; i += st) {
    const float* s; u16* d; int j = i;
    if (j < n0) { s = s0; d = d0; }
    else { j -= n0;
      if (j < n1) { s = s1; d = d1; }
      else { j -= n1;
        if (j < n2) { s = s2; d = d2; }
        else { j -= n2; s = s3; d = d3; } } }
    float4 v = ((const float4*)s)[j];
    ushort4 o;
    o.x = f2bf(v.x); o.y = f2bf(v.y); o.z = f2bf(v.z); o.w = f2bf(v.w);
    ((ushort4*)d)[j] = o;
  }
}

// ---------------- im2col for patch conv ----------------
__global__ void im2col_k(const float* __restrict__ x, u16* __restrict__ out) {
  int i = blockIdx.x * blockDim.x + threadIdx.x;
  const int st = gridDim.x * blockDim.x;
  const int total = 12544 * 768;
  for (; i < total; i += st) {
    int row = i / 768, col = i - row * 768;
    int b = row / 196, pr = row - b * 196;
    int py = pr / 14, px = pr - py * 14;
    int cin = col >> 8, rr = col & 255;
    int ky = rr >> 4, kx = rr & 15;
    out[i] = f2bf(x[((b * 3 + cin) * 224 + py * 16 + ky) * 224 + px * 16 + kx]);
  }
}

// ---------------- cls token + pos embed row 0 ----------------
__global__ void clspos_k(const float* __restrict__ cls, const float* __restrict__ pos,
                         float* __restrict__ t) {
  int i = blockIdx.x * blockDim.x + threadIdx.x;
  if (i >= B_ * DIM) return;
  int b = i / DIM, d = i - b * DIM;
  t[(size_t)b * NTOK * DIM + d] = cls[d] + pos[d];
}

// ---------------- modulation (fp32, exact) ----------------
__global__ __launch_bounds__(256)
void modk(const float* __restrict__ lat, const float* __restrict__ w,
          const float* __restrict__ bias, float* __restrict__ out, int ldb)
{
  __shared__ float ls[32][65];
  __shared__ float wsm[64][33];
  const int tid = threadIdx.x;
  const int mat = blockIdx.y;
  const int n0 = blockIdx.x * 64;
  const int nl = tid & 63;
  const int bg = tid >> 6;
  float acc[16];
  #pragma unroll
  for (int j = 0; j < 16; ++j) acc[j] = 0.f;
  for (int k0 = 0; k0 < 768; k0 += 32) {
    __syncthreads();
    #pragma unroll
    for (int i = 0; i < 8; ++i) {
      int idx = tid + i * 256;
      int rr = idx >> 5, kk = idx & 31;
      ls[kk][rr]  = lat[rr * 768 + k0 + kk];
      wsm[rr][kk] = w[((size_t)mat * 768 + n0 + rr) * 768 + k0 + kk];
    }
    __syncthreads();
    #pragma unroll 4
    for (int kk = 0; kk < 32; ++kk) {
      float wv = wsm[nl][kk];
      #pragma unroll
      for (int j = 0; j < 16; ++j)
        acc[j] += ls[kk][bg * 16 + j] * wv;
    }
  }
  const float EQS = 0.036084391824351615f;    // 1/sqrt(768)
  const float* bs = bias + (size_t)mat * 768 + n0;
  #pragma unroll
  for (int j = 0; j < 16; ++j) {
    int b = bg * 16 + j;
    out[(size_t)b * ldb + mat * 768 + n0 + nl] = acc[j] * EQS + bs[nl];
  }
}

// ---------------- SelfModulatedLayerNorm apply (oF optional) ----------------
__global__ __launch_bounds__(256)
void smln_k(const float* __restrict__ x,
            const float* __restrict__ gamma, const float* __restrict__ beta, int ldg,
            float* __restrict__ oF, u16* __restrict__ oB)
{
  const int row = blockIdx.x;
  const int tid = threadIdx.x;
  const float* xr = x + (size_t)row * DIM;
  float v0 = xr[tid], v1 = xr[tid + 256], v2 = xr[tid + 512];
  float s1 = v0 + v1 + v2;
  float s2 = v0 * v0 + v1 * v1 + v2 * v2;
  #pragma unroll
  for (int o = 32; o; o >>= 1) { s1 += __shfl_xor(s1, o); s2 += __shfl_xor(s2, o); }
  __shared__ float rs[8];
  const int lane = tid & 63, wv = tid >> 6;
  if (lane == 0) { rs[wv] = s1; rs[4 + wv] = s2; }
  __syncthreads();
  s1 = rs[0] + rs[1] + rs[2] + rs[3];
  s2 = rs[4] + rs[5] + rs[6] + rs[7];
  const float mean = s1 * (1.f / 768.f);
  const float var  = s2 * (1.f / 768.f) - mean * mean;
  const float rstd = rsqrtf(var + 1e-3f);
  const int b = row / NTOK;
  const float* g  = gamma + (size_t)b * ldg;
  const float* be = beta  + (size_t)b * ldg;
  const size_t base = (size_t)row * DIM;
  float vv[3] = {v0, v1, v2};
  #pragma unroll
  for (int j = 0; j < 3; ++j) {
    int d = tid + j * 256;
    float y = (vv[j] - mean) * rstd;
    y = y * (1.f + g[d]) + be[d];
    if (oF) oF[base + d] = y;
    if (oB) oB[base + d] = f2bf(y);
  }
}

// ---------------- MFMA attention: one block per (b,h) ----------------
__global__ __launch_bounds__(256)
void attn_k(const u16* __restrict__ qkv, u16* __restrict__ ao)
{
  __shared__ u16 Ks[208 * 68];
  __shared__ u16 Vt[64 * 226];
  __shared__ u16 Ps[4][16 * 228];
  const int bh = blockIdx.x;
  const int b = bh / NH, h = bh - (bh / NH) * NH;
  const int tid = threadIdx.x;
  const int lane = tid & 63, wv = tid >> 6;
  const int lr = lane & 15, kg = lane >> 4;
  const size_t tb = (size_t)(b * NTOK) * 2304 + h * 64;

  for (int t = tid; t < 1576; t += 256) {
    int n = t >> 3, c = t & 7;
    *(u16x8*)&Ks[n * 68 + c * 8] =
        *(const u16x8*)&qkv[tb + (size_t)n * 2304 + 768 + c * 8];
  }
  for (int t = tid; t < 1576; t += 256) {
    int n = t >> 3, dc = t & 7;
    u16x8 v = *(const u16x8*)&qkv[tb + (size_t)n * 2304 + 1536 + dc * 8];
    #pragma unroll
    for (int j = 0; j < 8; ++j) Vt[(dc * 8 + j) * 226 + n] = v[j];
  }
  for (int i = tid; i < 11 * 68; i += 256) Ks[197 * 68 + i] = 0;
  for (int i = tid; i < 64 * 29; i += 256) {
    int d = i / 29, c = i - d * 29;
    Vt[d * 226 + 197 + c] = 0;
  }
  for (int i = tid; i < 4 * 16 * 20; i += 256) {
    int w = i / 320, rm = i - w * 320, r = rm / 20, c = rm - r * 20;
    Ps[w][r * 228 + 208 + c] = 0;
  }
  __syncthreads();

  const f32x4 z4 = {0.f, 0.f, 0.f, 0.f};
  u16* pw = Ps[wv];

  for (int qt = wv; qt < 13; qt += 4) {
    const int q0 = qt * 16;
    const int qrow = min(q0 + lr, 196);
    const bf16x8 aq0 = *(const bf16x8*)&qkv[tb + (size_t)qrow * 2304 + kg * 8];
    const bf16x8 aq1 = *(const bf16x8*)&qkv[tb + (size_t)qrow * 2304 + 32 + kg * 8];

    f32x4 acc[13];
    #pragma unroll
    for (int ct = 0; ct < 13; ++ct) acc[ct] = z4;
    #pragma unroll
    for (int ct = 0; ct < 13; ++ct) {
      const bf16x8 bk0 = *(const bf16x8*)&Ks[(ct * 16 + lr) * 68 + kg * 8];
      const bf16x8 bk1 = *(const bf16x8*)&Ks[(ct * 16 + lr) * 68 + 32 + kg * 8];
      acc[ct] = __builtin_amdgcn_mfma_f32_16x16x32_bf16(aq0, bk0, acc[ct], 0, 0, 0);
      acc[ct] = __builtin_amdgcn_mfma_f32_16x16x32_bf16(aq1, bk1, acc[ct], 0, 0, 0);
    }

    float mx[4], sm[4], inv[4];
    #pragma unroll
    for (int r = 0; r < 4; ++r) mx[r] = -1e30f;
    #pragma unroll
    for (int ct = 0; ct < 13; ++ct)
      #pragma unroll
      for (int r = 0; r < 4; ++r) {
        float s = acc[ct][r] * 0.125f;
        if (ct * 16 + lr >= 197) s = -1e30f;
        acc[ct][r] = s;
        mx[r] = fmaxf(mx[r], s);
      }
    #pragma unroll
    for (int o = 1; o < 16; o <<= 1)
      #pragma unroll
      for (int r = 0; r < 4; ++r) mx[r] = fmaxf(mx[r], __shfl_xor(mx[r], o));
    #pragma unroll
    for (int r = 0; r < 4; ++r) sm[r] = 0.f;
    #pragma unroll
    for (int ct = 0; ct < 13; ++ct)
      #pragma unroll
      for (int r = 0; r < 4; ++r) {
        float p = __expf(acc[ct][r] - mx[r]);
        acc[ct][r] = p;
        sm[r] += p;
      }
    #pragma unroll
    for (int o = 1; o < 16; o <<= 1)
      #pragma unroll
      for (int r = 0; r < 4; ++r) sm[r] += __shfl_xor(sm[r], o);
    #pragma unroll
    for (int r = 0; r < 4; ++r) inv[r] = 1.f / sm[r];

    #pragma unroll
    for (int ct = 0; ct < 13; ++ct)
      #pragma unroll
      for (int r = 0; r < 4; ++r)
        pw[(kg * 4 + r) * 228 + ct * 16 + lr] = f2bf(acc[ct][r]);
    asm volatile("s_waitcnt lgkmcnt(0)" ::: "memory");
    __builtin_amdgcn_sched_barrier(0);

    f32x4 accO[4];
    #pragma unroll
    for (int dt = 0; dt < 4; ++dt) accO[dt] = z4;
    #pragma unroll
    for (int kt = 0; kt < 7; ++kt) {
      const bf16x8 ap = *(const bf16x8*)&pw[lr * 228 + kt * 32 + kg * 8];
      #pragma unroll
      for (int dt = 0; dt < 4; ++dt) {
        const bf16x8 bv = *(const bf16x8*)&Vt[(dt * 16 + lr) * 226 + kt * 32 + kg * 8];
        accO[dt] = __builtin_amdgcn_mfma_f32_16x16x32_bf16(ap, bv, accO[dt], 0, 0, 0);
      }
    }

    #pragma unroll
    for (int r = 0; r < 4; ++r) {
      const int q = q0 + kg * 4 + r;
      if (q < NTOK) {
        const size_t base = ((size_t)(b * NTOK + q)) * DIM + h * 64;
        #pragma unroll
        for (int dt = 0; dt < 4; ++dt)
          ao[base + dt * 16 + lr] = f2bf(accO[dt][r] * inv[r]);
      }
    }
  }
}

// ---------------- gemm256: 256x256 8-wave 8-phase bf16 GEMM, counted vmcnt ----------------
// BK=64, 512 thr (2M x 4N waves, each 128x64 out), 2x64KB LDS dbuf, swizzle
// slot=(c&7)^(row&7). Per K-tile: 4 phases {ds_read || 2 gld next-tile -> barrier
// -> lgkm(0) -> setprio(1) 16 MFMA -> [counted vmcnt] -> barrier}. Staging order
// B0,B1|B2,B3|A0,A2|A1,A3 with waits vmcnt(4)@p1 / vmcnt(2)@p3 -> every ds_read
// covered by a wait on loads >=1 phase old; never drains a fresh load.
template<int EPI>
__global__ __launch_bounds__(512, 2)
void gemm256(const u16* __restrict__ A, int lda,
             const u16* __restrict__ Bw, int ldb,
             int M, int K, int gn,
             const float* __restrict__ bias,
             const u16* __restrict__ res,
             float* __restrict__ outF, u16* __restrict__ outB, int ldo,
             const float* __restrict__ aux)
{
  __shared__ u16 SA[2][16384];   // [256 rows][64 k] per buf
  __shared__ u16 SB[2][16384];
  const int tid = threadIdx.x;
  const int lane = tid & 63, wv = tid >> 6;
  const int lr = lane & 15, kg = lane >> 4;
  const int wm = wv >> 2, wn = wv & 3;

  // bijective XCD swizzle (m204), tn-inner
  const int nwg = gridDim.x;
  const int qq = nwg >> 3, rr2 = nwg & 7;
  const int xcd = blockIdx.x & 7, loc = blockIdx.x >> 3;
  const int v = (xcd < rr2 ? xcd * (qq + 1) : rr2 * (qq + 1) + (xcd - rr2) * qq) + loc;
  const int tm = v / gn, tn = v - tm * gn;

  // staging sources: chunk c = tid + j*512 (j=0..3 covers rows j*64..j*64+63);
  // row = c>>3, phys slot holds k-chunk q = (c&7)^(row&7)
  const u16* aSrc[4];
  const u16* bSrc[4];
  #pragma unroll
  for (int j = 0; j < 4; ++j) {
    int c = tid + j * 512;
    int r = c >> 3, q = (c & 7) ^ (r & 7);
    int am = tm * 256 + r; if (am >= M) am = M - 1;
    aSrc[j] = A  + (size_t)am * lda + q * 8;
    bSrc[j] = Bw + (size_t)(tn * 256 + r) * ldb + q * 8;
  }

#define SGA(BUF, J, KO) gld_lds16(aSrc[J] + (KO), &SA[BUF][((J) * 512 + wv * 64) * 8])
#define SGB(BUF, J, KO) gld_lds16(bSrc[J] + (KO), &SB[BUF][((J) * 512 + wv * 64) * 8])

  f32x4 acc[8][4];
  const f32x4 z = {0.f, 0.f, 0.f, 0.f};
  #pragma unroll
  for (int m = 0; m < 8; ++m)
    #pragma unroll
    for (int n = 0; n < 4; ++n) acc[m][n] = z;

  const int KT = K >> 6;   // 12 or 48 (even)

  // prologue: stage tile 0, order B0..B3, A0, A2, A1, A3; cover B+A0+A2
  SGB(0, 0, 0); SGB(0, 1, 0); SGB(0, 2, 0); SGB(0, 3, 0);
  SGA(0, 0, 0); SGA(0, 2, 0); SGA(0, 1, 0); SGA(0, 3, 0);
  asm volatile("s_waitcnt vmcnt(2)" ::: "memory");
  __builtin_amdgcn_s_barrier();

#define RDA(BUF, P) \
    _Pragma("unroll") \
    for (int ks = 0; ks < 2; ++ks) \
      _Pragma("unroll") \
      for (int mm = 0; mm < 2; ++mm) { \
        int rrow = wm * 128 + ((P) * 2 + mm) * 16 + lr; \
        af[ks][mm] = *(const bf16x8*)&SA[BUF][rrow * 64 + ((((ks * 4 + kg) ^ (rrow & 7))) << 3)]; \
      }

#define MM(P) \
    _Pragma("unroll") \
    for (int ks = 0; ks < 2; ++ks) \
      _Pragma("unroll") \
      for (int mm = 0; mm < 2; ++mm) \
        _Pragma("unroll") \
        for (int n = 0; n < 4; ++n) \
          acc[(P) * 2 + mm][n] = __builtin_amdgcn_mfma_f32_16x16x32_bf16( \
              af[ks][mm], bfr[ks][n], acc[(P) * 2 + mm][n], 0, 0, 0);

#define TILE(BUF) do { \
    const int ko = (kt + 1) * 64; \
    const bool pf = (kt + 1 < KT); \
    bf16x8 bfr[2][4]; \
    bf16x8 af[2][2]; \
    /* p0: read B (whole tile) + A m0,m1; stage B0',B1' */ \
    _Pragma("unroll") \
    for (int ks = 0; ks < 2; ++ks) \
      _Pragma("unroll") \
      for (int n = 0; n < 4; ++n) { \
        int rrow = wn * 64 + n * 16 + lr; \
        bfr[ks][n] = *(const bf16x8*)&SB[BUF][rrow * 64 + ((((ks * 4 + kg) ^ (rrow & 7))) << 3)]; \
      } \
    RDA(BUF, 0); \
    if (pf) { SGB(BUF ^ 1, 0, ko); SGB(BUF ^ 1, 1, ko); } \
    __builtin_amdgcn_s_barrier(); \
    asm volatile("s_waitcnt lgkmcnt(0)" ::: "memory"); \
    __builtin_amdgcn_s_setprio(1); MM(0); __builtin_amdgcn_s_setprio(0); \
    __builtin_amdgcn_s_barrier(); \
    /* p1: read A m2,m3; stage B2',B3'; cover A1,A3 for p2/p3 */ \
    RDA(BUF, 1); \
    if (pf) { SGB(BUF ^ 1, 2, ko); SGB(BUF ^ 1, 3, ko); } \
    __builtin_amdgcn_s_barrier(); \
    asm volatile("s_waitcnt lgkmcnt(0)" ::: "memory"); \
    __builtin_amdgcn_s_setprio(1); MM(1); __builtin_amdgcn_s_setprio(0); \
    if (pf) { asm volatile("s_waitcnt vmcnt(4)" ::: "memory"); } \
    else    { asm volatile("s_waitcnt vmcnt(0)" ::: "memory"); } \
    __builtin_amdgcn_s_barrier(); \
    /* p2: read A m4,m5; stage A0',A2' */ \
    RDA(BUF, 2); \
    if (pf) { SGA(BUF ^ 1, 0, ko); SGA(BUF ^ 1, 2, ko); } \
    __builtin_amdgcn_s_barrier(); \
    asm volatile("s_waitcnt lgkmcnt(0)" ::: "memory"); \
    __builtin_amdgcn_s_setprio(1); MM(2); __builtin_amdgcn_s_setprio(0); \
    __builtin_amdgcn_s_barrier(); \
    /* p3: read A m6,m7; stage A1',A3'; boundary cover B'+A0'+A2' */ \
    RDA(BUF, 3); \
    if (pf) { SGA(BUF ^ 1, 1, ko); SGA(BUF ^ 1, 3, ko); } \
    __builtin_amdgcn_s_barrier(); \
    asm volatile("s_waitcnt lgkmcnt(0)" ::: "memory"); \
    __builtin_amdgcn_s_setprio(1); MM(3); __builtin_amdgcn_s_setprio(0); \
    if (pf) { asm volatile("s_waitcnt vmcnt(2)" ::: "memory"); } \
    else    { asm volatile("s_waitcnt vmcnt(0)" ::: "memory"); } \
    __builtin_amdgcn_s_barrier(); \
  } while (0)

  for (int kt0 = 0; kt0 < KT; kt0 += 2) {
    { const int kt = kt0;     TILE(0); }
    { const int kt = kt0 + 1; TILE(1); }
  }
#undef TILE
#undef MM
#undef RDA
#undef SGA
#undef SGB
  __syncthreads();   // LDS free for epilogue reuse

  // ---- epilogue: per-wave LDS transpose -> full-line vector stores ----
  const int gr0 = tm * 256 + wm * 128;
  const int gc0 = tn * 256 + wn * 64;
  if constexpr (EPI == EPI_BF16 || EPI == EPI_GELU) {
    u16* T = (u16*)SA + wv * 1152;            // [16][72] per wave (18KB total)
    #pragma unroll
    for (int m = 0; m < 8; ++m) {
      #pragma unroll
      for (int n = 0; n < 4; ++n) {
        #pragma unroll
        for (int r = 0; r < 4; ++r) {
          float val = acc[m][n][r];
          if constexpr (EPI == EPI_GELU) {
            float u = val + bias[gc0 + n * 16 + lr];
            val = 0.5f * u * (1.f + erff(u * 0.70710678118654752f));
          }
          T[(kg * 4 + r) * 72 + n * 16 + lr] = f2bf(val);
        }
      }
      asm volatile("s_waitcnt lgkmcnt(0)" ::: "memory");
      __builtin_amdgcn_sched_barrier(0);
      #pragma unroll
      for (int half = 0; half < 2; ++half) {
        int row = (lane >> 3) + half * 8;
        int c8 = lane & 7;
        u16x8 vv = *(const u16x8*)&T[row * 72 + c8 * 8];
        int gr = gr0 + m * 16 + row;
        if (gr < M) *(u16x8*)&outB[(size_t)gr * ldo + gc0 + c8 * 8] = vv;
      }
      asm volatile("s_waitcnt lgkmcnt(0)" ::: "memory");
      __builtin_amdgcn_sched_barrier(0);
    }
  } else {
    float* T = (float*)SA + wv * 1088;        // [16][68] f32 per wave (34.8KB total)
    #pragma unroll
    for (int m = 0; m < 8; ++m) {
      #pragma unroll
      for (int n = 0; n < 4; ++n)
        #pragma unroll
        for (int r = 0; r < 4; ++r)
          T[(kg * 4 + r) * 68 + n * 16 + lr] = acc[m][n][r];
      asm volatile("s_waitcnt lgkmcnt(0)" ::: "memory");
      __builtin_amdgcn_sched_barrier(0);
      #pragma unroll
      for (int qu = 0; qu < 4; ++qu) {
        int row = (lane >> 4) + qu * 4;
        int c4 = lane & 15;
        f32x4 vv = *(const f32x4*)&T[row * 68 + c4 * 4];
        int gr = gr0 + m * 16 + row;
        int gc = gc0 + c4 * 4;
        if (gr < M) {
          f32x4 bv = *(const f32x4*)&bias[gc];
          if constexpr (EPI == EPI_PROJ) {
            size_t o = (size_t)gr * ldo + gc;
            ushort4 rv = *(const ushort4*)&res[o];        // bf16 residual (xn)
            f32x4 ov;
            ov[0] = vv[0] + bv[0] + 2.f * bf2f(rv.x);
            ov[1] = vv[1] + bv[1] + 2.f * bf2f(rv.y);
            ov[2] = vv[2] + bv[2] + 2.f * bf2f(rv.z);
            ov[3] = vv[3] + bv[3] + 2.f * bf2f(rv.w);
            *(f32x4*)&outF[o] = ov;
          } else if constexpr (EPI == EPI_FC2) {
            size_t o = (size_t)gr * ldo + gc;
            ushort4 rv = *(const ushort4*)&res[o];        // bf16 residual (t2)
            f32x4 ov;
            ov[0] = vv[0] + bv[0] + bf2f(rv.x);
            ov[1] = vv[1] + bv[1] + bf2f(rv.y);
            ov[2] = vv[2] + bv[2] + bf2f(rv.z);
            ov[3] = vv[3] + bv[3] + bf2f(rv.w);
            *(f32x4*)&outF[o] = ov;
          } else {  // EPI_PATCH
            int pb = gr / 196, pp = gr - pb * 196;
            size_t o = ((size_t)pb * NTOK + 1 + pp) * DIM + gc;
            f32x4 av = *(const f32x4*)&aux[(size_t)(1 + pp) * DIM + gc];
            f32x4 ov;
            #pragma unroll
            for (int j = 0; j < 4; ++j) ov[j] = sinf(vv[j] + bv[j]) + av[j];
            *(f32x4*)&outF[o] = ov;
          }
        }
      }
      asm volatile("s_waitcnt lgkmcnt(0)" ::: "memory");
      __builtin_amdgcn_sched_barrier(0);
    }
  }
}

// ---------------- host ----------------
extern "C" void kernel_launch(void* const* d_in, const int* in_sizes, int n_in,
                              void* d_out, int out_size, void* d_ws, size_t ws_size,
                              hipStream_t stream)
{
  (void)in_sizes; (void)n_in;
  const float* X     = (const float*)d_in[0];
  const float* LAT   = (const float*)d_in[1];
  const float* CONVW = (const float*)d_in[2];
  const float* CONVB = (const float*)d_in[3];
  const float* CLS   = (const float*)d_in[4];
  const float* POS   = (const float*)d_in[5];
  const float* G1W   = (const float*)d_in[6];
  const float* G1B   = (const float*)d_in[7];
  const float* B1W   = (const float*)d_in[8];
  const float* B1B   = (const float*)d_in[9];
  const float* QKVW  = (const float*)d_in[10];
  const float* PROJW = (const float*)d_in[11];
  const float* PROJB = (const float*)d_in[12];
  const float* G2W   = (const float*)d_in[13];
  const float* G2B   = (const float*)d_in[14];
  const float* B2W   = (const float*)d_in[15];
  const float* B2B   = (const float*)d_in[16];
  const float* FC1W  = (const float*)d_in[17];
  const float* FC1B  = (const float*)d_in[18];
  const float* FC2W  = (const float*)d_in[19];
  const float* FC2B  = (const float*)d_in[20];
  const float* GNW   = (const float*)d_in[21];
  const float* GNB   = (const float*)d_in[22];
  const float* BNW   = (const float*)d_in[23];
  const float* BNB   = (const float*)d_in[24];

  char* p = (char*)d_ws;
  auto carve = [&](size_t bytes) { char* r = p; p += (bytes + 255) & ~(size_t)255; return r; };

  // union buffer: patches (pre-loop) / qkvb (qkv->attn) / hb (fc1->fc2)
  char* Ubuf  = carve((size_t)MROWS * HID_ * 2);            // 77.5 MB
  u16* patches = (u16*)Ubuf;
  u16* qkvb    = (u16*)Ubuf;
  u16* hb      = (u16*)Ubuf;
  u16* wconv  = (u16*)carve((size_t)768 * 768 * 2);
  u16* wqkv_l = (u16*)carve((size_t)2304 * 768 * 2);
  u16* wproj_l= (u16*)carve((size_t)768 * 768 * 2);
  u16* wfc1_l = (u16*)carve((size_t)3072 * 768 * 2);
  u16* wfc2_l = (u16*)carve((size_t)768 * 3072 * 2);
  float* tf   = (float*)carve((size_t)MROWS * 768 * 4);
  u16* xnb    = (u16*)carve((size_t)MROWS * 768 * 2);      // xn / t2, bf16 (residual source)
  u16* aob    = (u16*)carve((size_t)MROWS * 768 * 2);
  float* gam1 = (float*)carve((size_t)B_ * 9216 * 4);
  float* bet1 = (float*)carve((size_t)B_ * 9216 * 4);
  float* gam2 = (float*)carve((size_t)B_ * 9216 * 4);
  float* bet2 = (float*)carve((size_t)B_ * 9216 * 4);
  float* gamN = (float*)carve((size_t)B_ * 768 * 4);
  float* betN = (float*)carve((size_t)B_ * 768 * 4);

  // canary: if guard returns, d_out stays 1e9 -> visible failure mode
  fill_k<<<1, 64, 0, stream>>>((float*)d_out, 1e9f, 1);
  if ((size_t)(p - (char*)d_ws) > ws_size) {
    fill_k<<<256, 256, 0, stream>>>((float*)d_out, 1e9f, out_size);
    return;
  }

  // modulation gammas/betas (fp32, exact)
  modk<<<dim3(12, 12), 256, 0, stream>>>(LAT, G1W, G1B, gam1, 9216);
  modk<<<dim3(12, 12), 256, 0, stream>>>(LAT, B1W, B1B, bet1, 9216);
  modk<<<dim3(12, 12), 256, 0, stream>>>(LAT, G2W, G2B, gam2, 9216);
  modk<<<dim3(12, 12), 256, 0, stream>>>(LAT, B2W, B2B, bet2, 9216);
  modk<<<dim3(12, 1),  256, 0, stream>>>(LAT, GNW, GNB, gamN, 768);
  modk<<<dim3(12, 1),  256, 0, stream>>>(LAT, BNW, BNB, betN, 768);

  // patch embed
  {
    int n4 = 768 * 768 / 4;
    cvt_bf16<<<(n4 + 255) / 256, 256, 0, stream>>>(CONVW, wconv, n4);
  }
  im2col_k<<<4096, 256, 0, stream>>>(X, patches);
  // patch: gm=49 (12544/256), gn=3 -> 147 blocks
  gemm256<EPI_PATCH><<<147, 512, 0, stream>>>(patches, 768, wconv, 768, 12544, 768, 3,
                                              CONVB, nullptr, tf, nullptr, 768, POS);
  clspos_k<<<(B_ * DIM + 255) / 256, 256, 0, stream>>>(CLS, POS, tf);

  const int n4_qkv = 2304 * 768 / 4, n4_pro = 768 * 768 / 4, n4_fc = 3072 * 768 / 4;
  for (int l = 0; l < LAY; ++l) {
    cvt4_k<<<4096, 256, 0, stream>>>(QKVW + (size_t)l * 2304 * 768, PROJW + (size_t)l * 768 * 768,
                                     FC1W + (size_t)l * 3072 * 768, FC2W + (size_t)l * 768 * 3072,
                                     wqkv_l, wproj_l, wfc1_l, wfc2_l,
                                     n4_qkv, n4_pro, n4_fc, n4_fc);
    smln_k<<<MROWS, 256, 0, stream>>>(tf, gam1 + l * 768, bet1 + l * 768, 9216, nullptr, xnb);
    // qkv: gm=50, gn=9 -> 450 blocks
    gemm256<EPI_BF16><<<450, 512, 0, stream>>>(xnb, 768, wqkv_l, 768, MROWS, 768, 9,
                                               nullptr, nullptr, nullptr, qkvb, 2304, nullptr);
    attn_k<<<B_ * NH, 256, 0, stream>>>(qkvb, aob);
    // proj: gm=50, gn=3 -> 150 blocks
    gemm256<EPI_PROJ><<<150, 512, 0, stream>>>(aob, 768, wproj_l, 768, MROWS, 768, 3,
                                               PROJB + l * 768, xnb, tf, nullptr, 768, nullptr);
    smln_k<<<MROWS, 256, 0, stream>>>(tf, gam2 + l * 768, bet2 + l * 768, 9216, nullptr, xnb);
    // fc1: gm=50, gn=12 -> 600 blocks
    gemm256<EPI_GELU><<<600, 512, 0, stream>>>(xnb, 768, wfc1_l, 768, MROWS, 768, 12,
                                               FC1B + l * 3072, nullptr, nullptr, hb, 3072, nullptr);
    // fc2: K=3072 (KT=48), gm=50, gn=3 -> 150 blocks
    gemm256<EPI_FC2><<<150, 512, 0, stream>>>(hb, 3072, wfc2_l, 3072, MROWS, 3072, 3,
                                              FC2B + l * 768, xnb, tf, nullptr, 768, nullptr);
  }
  smln_k<<<MROWS, 256, 0, stream>>>(tf, gamN, betN, 768, (float*)d_out, nullptr);
}

// Round 14
// 6043.282 us; speedup vs baseline: 1.2662x; 1.0957x over previous
//
#include <hip/hip_runtime.h>

typedef unsigned short u16;
typedef __bf16 bf16x8 __attribute__((ext_vector_type(8)));
typedef unsigned short u16x8 __attribute__((ext_vector_type(8)));
typedef float f32x4 __attribute__((ext_vector_type(4)));

#define B_    64
#define NTOK  197
#define DIM   768
#define NH    12
#define LAY   12
#define HID_  3072
#define MROWS (B_*NTOK)   // 12608

#define EPI_BF16  0
#define EPI_PROJ  2
#define EPI_GELU  3
#define EPI_FC2   4
#define EPI_PATCH 5

__device__ __forceinline__ u16 f2bf(float f) {
  unsigned u = __float_as_uint(f);
  u += 0x7FFFu + ((u >> 16) & 1u);          // RNE
  return (u16)(u >> 16);
}
__device__ __forceinline__ float bf2f(u16 h) {
  return __uint_as_float(((unsigned)h) << 16);
}

__device__ __forceinline__ void gld_lds16(const void* g, void* l) {
  __builtin_amdgcn_global_load_lds(
      (const __attribute__((address_space(1))) void*)g,
      (__attribute__((address_space(3))) void*)l, 16, 0, 0);
}

// ---------------- diagnostic fill ----------------
__global__ void fill_k(float* __restrict__ o, float v, int n) {
  int i = blockIdx.x * blockDim.x + threadIdx.x;
  const int st = gridDim.x * blockDim.x;
  for (; i < n; i += st) o[i] = v;
}

// ---------------- f32 -> bf16 convert ----------------
__global__ void cvt_bf16(const float* __restrict__ in, u16* __restrict__ out, int n4) {
  int i = blockIdx.x * blockDim.x + threadIdx.x;
  const int st = gridDim.x * blockDim.x;
  for (; i < n4; i += st) {
    float4 v = ((const float4*)in)[i];
    ushort4 o;
    o.x = f2bf(v.x); o.y = f2bf(v.y); o.z = f2bf(v.z); o.w = f2bf(v.w);
    ((ushort4*)out)[i] = o;
  }
}

// ---------------- fused 4-way f32 -> bf16 convert ----------------
__global__ void cvt4_k(const float* __restrict__ s0, const float* __restrict__ s1,
                       const float* __restrict__ s2, const float* __restrict__ s3,
                       u16* __restrict__ d0, u16* __restrict__ d1,
                       u16* __restrict__ d2, u16* __restrict__ d3,
                       int n0, int n1, int n2, int n3)   // float4 counts
{
  int i = blockIdx.x * blockDim.x + threadIdx.x;
  const int st = gridDim.x * blockDim.x;
  const int total = n0 + n1 + n2 + n3;
  for (; i < total; i += st) {
    const float* s; u16* d; int j = i;
    if (j < n0) { s = s0; d = d0; }
    else { j -= n0;
      if (j < n1) { s = s1; d = d1; }
      else { j -= n1;
        if (j < n2) { s = s2; d = d2; }
        else { j -= n2; s = s3; d = d3; } } }
    float4 v = ((const float4*)s)[j];
    ushort4 o;
    o.x = f2bf(v.x); o.y = f2bf(v.y); o.z = f2bf(v.z); o.w = f2bf(v.w);
    ((ushort4*)d)[j] = o;
  }
}

// ---------------- im2col for patch conv ----------------
__global__ void im2col_k(const float* __restrict__ x, u16* __restrict__ out) {
  int i = blockIdx.x * blockDim.x + threadIdx.x;
  const int st = gridDim.x * blockDim.x;
  const int total = 12544 * 768;
  for (; i < total; i += st) {
    int row = i / 768, col = i - row * 768;
    int b = row / 196, pr = row - b * 196;
    int py = pr / 14, px = pr - py * 14;
    int cin = col >> 8, rr = col & 255;
    int ky = rr >> 4, kx = rr & 15;
    out[i] = f2bf(x[((b * 3 + cin) * 224 + py * 16 + ky) * 224 + px * 16 + kx]);
  }
}

// ---------------- cls token + pos embed row 0 ----------------
__global__ void clspos_k(const float* __restrict__ cls, const float* __restrict__ pos,
                         float* __restrict__ t) {
  int i = blockIdx.x * blockDim.x + threadIdx.x;
  if (i >= B_ * DIM) return;
  int b = i / DIM, d = i - b * DIM;
  t[(size_t)b * NTOK * DIM + d] = cls[d] + pos[d];
}

// ---------------- modulation (fp32, exact) ----------------
__global__ __launch_bounds__(256)
void modk(const float* __restrict__ lat, const float* __restrict__ w,
          const float* __restrict__ bias, float* __restrict__ out, int ldb)
{
  __shared__ float ls[32][65];
  __shared__ float wsm[64][33];
  const int tid = threadIdx.x;
  const int mat = blockIdx.y;
  const int n0 = blockIdx.x * 64;
  const int nl = tid & 63;
  const int bg = tid >> 6;
  float acc[16];
  #pragma unroll
  for (int j = 0; j < 16; ++j) acc[j] = 0.f;
  for (int k0 = 0; k0 < 768; k0 += 32) {
    __syncthreads();
    #pragma unroll
    for (int i = 0; i < 8; ++i) {
      int idx = tid + i * 256;
      int rr = idx >> 5, kk = idx & 31;
      ls[kk][rr]  = lat[rr * 768 + k0 + kk];
      wsm[rr][kk] = w[((size_t)mat * 768 + n0 + rr) * 768 + k0 + kk];
    }
    __syncthreads();
    #pragma unroll 4
    for (int kk = 0; kk < 32; ++kk) {
      float wv = wsm[nl][kk];
      #pragma unroll
      for (int j = 0; j < 16; ++j)
        acc[j] += ls[kk][bg * 16 + j] * wv;
    }
  }
  const float EQS = 0.036084391824351615f;    // 1/sqrt(768)
  const float* bs = bias + (size_t)mat * 768 + n0;
  #pragma unroll
  for (int j = 0; j < 16; ++j) {
    int b = bg * 16 + j;
    out[(size_t)b * ldb + mat * 768 + n0 + nl] = acc[j] * EQS + bs[nl];
  }
}

// ---------------- SelfModulatedLayerNorm apply ----------------
__global__ __launch_bounds__(256)
void smln_k(const float* __restrict__ x,
            const float* __restrict__ gamma, const float* __restrict__ beta, int ldg,
            float* __restrict__ oF, u16* __restrict__ oB)
{
  const int row = blockIdx.x;
  const int tid = threadIdx.x;
  const float* xr = x + (size_t)row * DIM;
  float v0 = xr[tid], v1 = xr[tid + 256], v2 = xr[tid + 512];
  float s1 = v0 + v1 + v2;
  float s2 = v0 * v0 + v1 * v1 + v2 * v2;
  #pragma unroll
  for (int o = 32; o; o >>= 1) { s1 += __shfl_xor(s1, o); s2 += __shfl_xor(s2, o); }
  __shared__ float rs[8];
  const int lane = tid & 63, wv = tid >> 6;
  if (lane == 0) { rs[wv] = s1; rs[4 + wv] = s2; }
  __syncthreads();
  s1 = rs[0] + rs[1] + rs[2] + rs[3];
  s2 = rs[4] + rs[5] + rs[6] + rs[7];
  const float mean = s1 * (1.f / 768.f);
  const float var  = s2 * (1.f / 768.f) - mean * mean;
  const float rstd = rsqrtf(var + 1e-3f);
  const int b = row / NTOK;
  const float* g  = gamma + (size_t)b * ldg;
  const float* be = beta  + (size_t)b * ldg;
  const size_t base = (size_t)row * DIM;
  float vv[3] = {v0, v1, v2};
  #pragma unroll
  for (int j = 0; j < 3; ++j) {
    int d = tid + j * 256;
    float y = (vv[j] - mean) * rstd;
    y = y * (1.f + g[d]) + be[d];
    oF[base + d] = y;
    if (oB) oB[base + d] = f2bf(y);
  }
}

// ---------------- MFMA attention: one block per (b,h) ----------------
__global__ __launch_bounds__(256)
void attn_k(const u16* __restrict__ qkv, u16* __restrict__ ao)
{
  __shared__ u16 Ks[208 * 68];
  __shared__ u16 Vt[64 * 226];
  __shared__ u16 Ps[4][16 * 228];
  const int bh = blockIdx.x;
  const int b = bh / NH, h = bh - (bh / NH) * NH;
  const int tid = threadIdx.x;
  const int lane = tid & 63, wv = tid >> 6;
  const int lr = lane & 15, kg = lane >> 4;
  const size_t tb = (size_t)(b * NTOK) * 2304 + h * 64;

  for (int t = tid; t < 1576; t += 256) {
    int n = t >> 3, c = t & 7;
    *(u16x8*)&Ks[n * 68 + c * 8] =
        *(const u16x8*)&qkv[tb + (size_t)n * 2304 + 768 + c * 8];
  }
  for (int t = tid; t < 1576; t += 256) {
    int n = t >> 3, dc = t & 7;
    u16x8 v = *(const u16x8*)&qkv[tb + (size_t)n * 2304 + 1536 + dc * 8];
    #pragma unroll
    for (int j = 0; j < 8; ++j) Vt[(dc * 8 + j) * 226 + n] = v[j];
  }
  for (int i = tid; i < 11 * 68; i += 256) Ks[197 * 68 + i] = 0;
  for (int i = tid; i < 64 * 29; i += 256) {
    int d = i / 29, c = i - d * 29;
    Vt[d * 226 + 197 + c] = 0;
  }
  for (int i = tid; i < 4 * 16 * 20; i += 256) {
    int w = i / 320, rm = i - w * 320, r = rm / 20, c = rm - r * 20;
    Ps[w][r * 228 + 208 + c] = 0;
  }
  __syncthreads();

  const f32x4 z4 = {0.f, 0.f, 0.f, 0.f};
  u16* pw = Ps[wv];

  for (int qt = wv; qt < 13; qt += 4) {
    const int q0 = qt * 16;
    const int qrow = min(q0 + lr, 196);
    const bf16x8 aq0 = *(const bf16x8*)&qkv[tb + (size_t)qrow * 2304 + kg * 8];
    const bf16x8 aq1 = *(const bf16x8*)&qkv[tb + (size_t)qrow * 2304 + 32 + kg * 8];

    f32x4 acc[13];
    #pragma unroll
    for (int ct = 0; ct < 13; ++ct) acc[ct] = z4;
    #pragma unroll
    for (int ct = 0; ct < 13; ++ct) {
      const bf16x8 bk0 = *(const bf16x8*)&Ks[(ct * 16 + lr) * 68 + kg * 8];
      const bf16x8 bk1 = *(const bf16x8*)&Ks[(ct * 16 + lr) * 68 + 32 + kg * 8];
      acc[ct] = __builtin_amdgcn_mfma_f32_16x16x32_bf16(aq0, bk0, acc[ct], 0, 0, 0);
      acc[ct] = __builtin_amdgcn_mfma_f32_16x16x32_bf16(aq1, bk1, acc[ct], 0, 0, 0);
    }

    float mx[4], sm[4], inv[4];
    #pragma unroll
    for (int r = 0; r < 4; ++r) mx[r] = -1e30f;
    #pragma unroll
    for (int ct = 0; ct < 13; ++ct)
      #pragma unroll
      for (int r = 0; r < 4; ++r) {
        float s = acc[ct][r] * 0.125f;
        if (ct * 16 + lr >= 197) s = -1e30f;
        acc[ct][r] = s;
        mx[r] = fmaxf(mx[r], s);
      }
    #pragma unroll
    for (int o = 1; o < 16; o <<= 1)
      #pragma unroll
      for (int r = 0; r < 4; ++r) mx[r] = fmaxf(mx[r], __shfl_xor(mx[r], o));
    #pragma unroll
    for (int r = 0; r < 4; ++r) sm[r] = 0.f;
    #pragma unroll
    for (int ct = 0; ct < 13; ++ct)
      #pragma unroll
      for (int r = 0; r < 4; ++r) {
        float p = __expf(acc[ct][r] - mx[r]);
        acc[ct][r] = p;
        sm[r] += p;
      }
    #pragma unroll
    for (int o = 1; o < 16; o <<= 1)
      #pragma unroll
      for (int r = 0; r < 4; ++r) sm[r] += __shfl_xor(sm[r], o);
    #pragma unroll
    for (int r = 0; r < 4; ++r) inv[r] = 1.f / sm[r];

    #pragma unroll
    for (int ct = 0; ct < 13; ++ct)
      #pragma unroll
      for (int r = 0; r < 4; ++r)
        pw[(kg * 4 + r) * 228 + ct * 16 + lr] = f2bf(acc[ct][r]);
    asm volatile("s_waitcnt lgkmcnt(0)" ::: "memory");
    __builtin_amdgcn_sched_barrier(0);

    f32x4 accO[4];
    #pragma unroll
    for (int dt = 0; dt < 4; ++dt) accO[dt] = z4;
    #pragma unroll
    for (int kt = 0; kt < 7; ++kt) {
      const bf16x8 ap = *(const bf16x8*)&pw[lr * 228 + kt * 32 + kg * 8];
      #pragma unroll
      for (int dt = 0; dt < 4; ++dt) {
        const bf16x8 bv = *(const bf16x8*)&Vt[(dt * 16 + lr) * 226 + kt * 32 + kg * 8];
        accO[dt] = __builtin_amdgcn_mfma_f32_16x16x32_bf16(ap, bv, accO[dt], 0, 0, 0);
      }
    }

    #pragma unroll
    for (int r = 0; r < 4; ++r) {
      const int q = q0 + kg * 4 + r;
      if (q < NTOK) {
        const size_t base = ((size_t)(b * NTOK + q)) * DIM + h * 64;
        #pragma unroll
        for (int dt = 0; dt < 4; ++dt)
          ao[base + dt * 16 + lr] = f2bf(accO[dt][r] * inv[r]);
      }
    }
  }
}

// ---------------- ring gemm (r8-exact): BM=BN=128, 3-buffer, counted vmcnt ----------------
// TC>0 selects the L2-chunked hierarchical block order (r12): each XCD owns mpx
// tm rows; iterate (tn-chunk of TC, tm, tn-in-chunk) -> A-chunk + TC B-panels
// L2-co-resident. TC==0 = r8's plain bijective XCD swizzle (tn-inner).
template<int EPI>
__global__ __launch_bounds__(256)
void gemm_bt(const u16* __restrict__ A, int lda,
             const u16* __restrict__ Bw, int ldb,
             int M, int K, int gm, int gn, int TC, int mpx,
             const float* __restrict__ bias,
             const float* __restrict__ res,
             float* __restrict__ outF, u16* __restrict__ outB, int ldo,
             const float* __restrict__ aux)
{
  __shared__ u16 SA[3][4096];   // [128 rows][32 k] x3 ring
  __shared__ u16 SB[3][4096];
  const int tid = threadIdx.x;
  const int lane = tid & 63, wv = tid >> 6;
  const int lr = lane & 15, kg = lane >> 4;
  const int wm = wv >> 1, wn = wv & 1;

  int tm, tn;
  if (TC > 0) {
    const int xcd = blockIdx.x & 7, loc = blockIdx.x >> 3;
    const int c    = loc / (mpx * TC);
    const int rem  = loc - c * (mpx * TC);
    const int mloc = rem / TC;
    tm = xcd * mpx + mloc;
    tn = c * TC + (rem - mloc * TC);
    if (tm >= gm) return;               // pad block: exits before any barrier
  } else {
    const int nwg = gridDim.x;
    const int qq = nwg >> 3, rr2 = nwg & 7;
    const int xcd = blockIdx.x & 7, loc = blockIdx.x >> 3;
    const int v = (xcd < rr2 ? xcd * (qq + 1) : rr2 * (qq + 1) + (xcd - rr2) * qq) + loc;
    tm = v / gn; tn = v - tm * gn;
  }

  const int c0 = tid, c1 = tid + 256;
  const int r0 = c0 >> 2, q0 = (c0 & 3) ^ (r0 & 3) ^ ((r0 >> 2) & 3);
  const int r1 = c1 >> 2, q1 = (c1 & 3) ^ (r1 & 3) ^ ((r1 >> 2) & 3);
  int am0 = tm * 128 + r0; if (am0 >= M) am0 = M - 1;
  int am1 = tm * 128 + r1; if (am1 >= M) am1 = M - 1;
  const u16* aS0 = A  + (size_t)am0 * lda + q0 * 8;
  const u16* aS1 = A  + (size_t)am1 * lda + q1 * 8;
  const u16* bS0 = Bw + (size_t)(tn * 128 + r0) * ldb + q0 * 8;
  const u16* bS1 = Bw + (size_t)(tn * 128 + r1) * ldb + q1 * 8;

  f32x4 acc[4][4];
  const f32x4 z = {0.f, 0.f, 0.f, 0.f};
  #pragma unroll
  for (int m = 0; m < 4; ++m)
    #pragma unroll
    for (int n = 0; n < 4; ++n) acc[m][n] = z;

#define STG(buf, ko) do { \
    u16* aD = &SA[buf][wv * 512]; u16* bD = &SB[buf][wv * 512]; \
    gld_lds16(aS0 + (ko), aD);        gld_lds16(aS1 + (ko), aD + 2048); \
    gld_lds16(bS0 + (ko), bD);        gld_lds16(bS1 + (ko), bD + 2048); \
  } while (0)

  const int KT = K >> 5;   // 24 or 96
  STG(0, 0);
  STG(1, 32);
  asm volatile("s_waitcnt vmcnt(4)" ::: "memory");
  __builtin_amdgcn_s_barrier();
  __builtin_amdgcn_sched_barrier(0);

  for (int t = 0; t < KT; ++t) {
    const int buf = t % 3;
    if (t) {
      asm volatile("s_waitcnt lgkmcnt(0)" ::: "memory");
      __builtin_amdgcn_sched_barrier(0);
      if (t + 1 < KT) asm volatile("s_waitcnt vmcnt(4)" ::: "memory");
      else            asm volatile("s_waitcnt vmcnt(0)" ::: "memory");
      __builtin_amdgcn_s_barrier();
      __builtin_amdgcn_sched_barrier(0);
    }
    if (t + 2 < KT) STG((t + 2) % 3, (t + 2) * 32);
    bf16x8 af[4], bfr[4];
    #pragma unroll
    for (int m = 0; m < 4; ++m) {
      int row = wm * 64 + m * 16 + lr;
      af[m] = *(const bf16x8*)&SA[buf][row * 32 + (((kg ^ row ^ (row >> 2)) & 3) << 3)];
    }
    #pragma unroll
    for (int n = 0; n < 4; ++n) {
      int row = wn * 64 + n * 16 + lr;
      bfr[n] = *(const bf16x8*)&SB[buf][row * 32 + (((kg ^ row ^ (row >> 2)) & 3) << 3)];
    }
    #pragma unroll
    for (int m = 0; m < 4; ++m)
      #pragma unroll
      for (int n = 0; n < 4; ++n)
        acc[m][n] = __builtin_amdgcn_mfma_f32_16x16x32_bf16(af[m], bfr[n], acc[m][n], 0, 0, 0);
  }
#undef STG
  __syncthreads();   // all waves done with LDS before epilogue reuse

  // ---- epilogue: LDS transpose -> full-line vector stores ----
  const int gr0 = tm * 128 + wm * 64;
  const int gc0 = tn * 128 + wn * 64;
  if constexpr (EPI == EPI_BF16 || EPI == EPI_GELU) {
    u16* T = (u16*)SA + wv * 1152;            // [16][72] per wave
    #pragma unroll
    for (int m = 0; m < 4; ++m) {
      #pragma unroll
      for (int n = 0; n < 4; ++n) {
        #pragma unroll
        for (int r = 0; r < 4; ++r) {
          float val = acc[m][n][r];
          if constexpr (EPI == EPI_GELU) {
            float u = val + bias[gc0 + n * 16 + lr];
            val = 0.5f * u * (1.f + erff(u * 0.70710678118654752f));
          }
          T[(kg * 4 + r) * 72 + n * 16 + lr] = f2bf(val);
        }
      }
      asm volatile("s_waitcnt lgkmcnt(0)" ::: "memory");
      __builtin_amdgcn_sched_barrier(0);
      #pragma unroll
      for (int half = 0; half < 2; ++half) {
        int row = (lane >> 3) + half * 8;
        int c8 = lane & 7;
        u16x8 vv = *(const u16x8*)&T[row * 72 + c8 * 8];
        int gr = gr0 + m * 16 + row;
        if (gr < M) *(u16x8*)&outB[(size_t)gr * ldo + gc0 + c8 * 8] = vv;
      }
      asm volatile("s_waitcnt lgkmcnt(0)" ::: "memory");   // reads done before T reuse
      __builtin_amdgcn_sched_barrier(0);
    }
  } else {
    float* T = (float*)SA + wv * 1088;        // [16][68] per wave
    #pragma unroll
    for (int m = 0; m < 4; ++m) {
      #pragma unroll
      for (int n = 0; n < 4; ++n)
        #pragma unroll
        for (int r = 0; r < 4; ++r)
          T[(kg * 4 + r) * 68 + n * 16 + lr] = acc[m][n][r];
      asm volatile("s_waitcnt lgkmcnt(0)" ::: "memory");
      __builtin_amdgcn_sched_barrier(0);
      #pragma unroll
      for (int qu = 0; qu < 4; ++qu) {
        int row = (lane >> 4) + qu * 4;
        int c4 = lane & 15;
        f32x4 vv = *(const f32x4*)&T[row * 68 + c4 * 4];
        int gr = gr0 + m * 16 + row;
        int gc = gc0 + c4 * 4;
        if (gr < M) {
          f32x4 bv = *(const f32x4*)&bias[gc];
          if constexpr (EPI == EPI_PROJ) {
            size_t o = (size_t)gr * ldo + gc;
            f32x4 rv = *(const f32x4*)&res[o];
            f32x4 ov = vv + bv + 2.f * rv;
            *(f32x4*)&outF[o] = ov;
          } else if constexpr (EPI == EPI_FC2) {
            size_t o = (size_t)gr * ldo + gc;
            f32x4 rv = *(const f32x4*)&res[o];
            f32x4 ov = vv + bv + rv;
            *(f32x4*)&outF[o] = ov;
          } else {  // EPI_PATCH
            int pb = gr / 196, pp = gr - pb * 196;
            size_t o = ((size_t)pb * NTOK + 1 + pp) * DIM + gc;
            f32x4 av = *(const f32x4*)&aux[(size_t)(1 + pp) * DIM + gc];
            f32x4 ov;
            #pragma unroll
            for (int j = 0; j < 4; ++j) ov[j] = sinf(vv[j] + bv[j]) + av[j];
            *(f32x4*)&outF[o] = ov;
          }
        }
      }
      asm volatile("s_waitcnt lgkmcnt(0)" ::: "memory");
      __builtin_amdgcn_sched_barrier(0);
    }
  }
}

// ---------------- host ----------------
extern "C" void kernel_launch(void* const* d_in, const int* in_sizes, int n_in,
                              void* d_out, int out_size, void* d_ws, size_t ws_size,
                              hipStream_t stream)
{
  (void)in_sizes; (void)n_in;
  const float* X     = (const float*)d_in[0];
  const float* LAT   = (const float*)d_in[1];
  const float* CONVW = (const float*)d_in[2];
  const float* CONVB = (const float*)d_in[3];
  const float* CLS   = (const float*)d_in[4];
  const float* POS   = (const float*)d_in[5];
  const float* G1W   = (const float*)d_in[6];
  const float* G1B   = (const float*)d_in[7];
  const float* B1W   = (const float*)d_in[8];
  const float* B1B   = (const float*)d_in[9];
  const float* QKVW  = (const float*)d_in[10];
  const float* PROJW = (const float*)d_in[11];
  const float* PROJB = (const float*)d_in[12];
  const float* G2W   = (const float*)d_in[13];
  const float* G2B   = (const float*)d_in[14];
  const float* B2W   = (const float*)d_in[15];
  const float* B2B   = (const float*)d_in[16];
  const float* FC1W  = (const float*)d_in[17];
  const float* FC1B  = (const float*)d_in[18];
  const float* FC2W  = (const float*)d_in[19];
  const float* FC2B  = (const float*)d_in[20];
  const float* GNW   = (const float*)d_in[21];
  const float* GNB   = (const float*)d_in[22];
  const float* BNW   = (const float*)d_in[23];
  const float* BNB   = (const float*)d_in[24];

  char* p = (char*)d_ws;
  auto carve = [&](size_t bytes) { char* r = p; p += (bytes + 255) & ~(size_t)255; return r; };

  // union buffer: patches (pre-loop) / qkvb (qkv->attn) / hb (fc1->fc2)
  char* Ubuf  = carve((size_t)MROWS * HID_ * 2);            // 77.5 MB
  u16* patches = (u16*)Ubuf;
  u16* qkvb    = (u16*)Ubuf;
  u16* hb      = (u16*)Ubuf;
  u16* wconv  = (u16*)carve((size_t)768 * 768 * 2);
  u16* wqkv_l = (u16*)carve((size_t)2304 * 768 * 2);
  u16* wproj_l= (u16*)carve((size_t)768 * 768 * 2);
  u16* wfc1_l = (u16*)carve((size_t)3072 * 768 * 2);
  u16* wfc2_l = (u16*)carve((size_t)768 * 3072 * 2);
  float* tf   = (float*)carve((size_t)MROWS * 768 * 4);
  float* xnf  = (float*)carve((size_t)MROWS * 768 * 4);
  u16* xnb    = (u16*)carve((size_t)MROWS * 768 * 2);
  u16* aob    = (u16*)carve((size_t)MROWS * 768 * 2);
  float* gam1 = (float*)carve((size_t)B_ * 9216 * 4);
  float* bet1 = (float*)carve((size_t)B_ * 9216 * 4);
  float* gam2 = (float*)carve((size_t)B_ * 9216 * 4);
  float* bet2 = (float*)carve((size_t)B_ * 9216 * 4);
  float* gamN = (float*)carve((size_t)B_ * 768 * 4);
  float* betN = (float*)carve((size_t)B_ * 768 * 4);

  // canary: if guard returns, d_out stays 1e9 -> visible failure mode
  fill_k<<<1, 64, 0, stream>>>((float*)d_out, 1e9f, 1);
  if ((size_t)(p - (char*)d_ws) > ws_size) {
    fill_k<<<256, 256, 0, stream>>>((float*)d_out, 1e9f, out_size);
    return;
  }

  // modulation gammas/betas (fp32, exact)
  modk<<<dim3(12, 12), 256, 0, stream>>>(LAT, G1W, G1B, gam1, 9216);
  modk<<<dim3(12, 12), 256, 0, stream>>>(LAT, B1W, B1B, bet1, 9216);
  modk<<<dim3(12, 12), 256, 0, stream>>>(LAT, G2W, G2B, gam2, 9216);
  modk<<<dim3(12, 12), 256, 0, stream>>>(LAT, B2W, B2B, bet2, 9216);
  modk<<<dim3(12, 1),  256, 0, stream>>>(LAT, GNW, GNB, gamN, 768);
  modk<<<dim3(12, 1),  256, 0, stream>>>(LAT, BNW, BNB, betN, 768);

  // patch embed
  {
    int n4 = 768 * 768 / 4;
    cvt_bf16<<<(n4 + 255) / 256, 256, 0, stream>>>(CONVW, wconv, n4);
  }
  im2col_k<<<4096, 256, 0, stream>>>(X, patches);
  gemm_bt<EPI_PATCH><<<98 * 6, 256, 0, stream>>>(patches, 768, wconv, 768, 12544, 768, 98, 6, 0, 0,
                                                 CONVB, nullptr, tf, nullptr, 768, POS);
  clspos_k<<<(B_ * DIM + 255) / 256, 256, 0, stream>>>(CLS, POS, tf);

  const int n4_qkv = 2304 * 768 / 4, n4_pro = 768 * 768 / 4, n4_fc = 3072 * 768 / 4;
  for (int l = 0; l < LAY; ++l) {
    cvt4_k<<<4096, 256, 0, stream>>>(QKVW + (size_t)l * 2304 * 768, PROJW + (size_t)l * 768 * 768,
                                     FC1W + (size_t)l * 3072 * 768, FC2W + (size_t)l * 768 * 3072,
                                     wqkv_l, wproj_l, wfc1_l, wfc2_l,
                                     n4_qkv, n4_pro, n4_fc, n4_fc);
    smln_k<<<MROWS, 256, 0, stream>>>(tf, gam1 + l * 768, bet1 + l * 768, 9216, xnf, xnb);
    // qkv: L2-chunked (gm=99, gn=18, TC=6, mpx=13 -> 8*13*18 = 1872 blocks)
    gemm_bt<EPI_BF16><<<1872, 256, 0, stream>>>(xnb, 768, wqkv_l, 768, MROWS, 768, 99, 18, 6, 13,
                                                nullptr, nullptr, nullptr, qkvb, 2304, nullptr);
    attn_k<<<B_ * NH, 256, 0, stream>>>(qkvb, aob);
    gemm_bt<EPI_PROJ><<<99 * 6, 256, 0, stream>>>(aob, 768, wproj_l, 768, MROWS, 768, 99, 6, 0, 0,
                                                  PROJB + l * 768, xnf, tf, nullptr, 768, nullptr);
    smln_k<<<MROWS, 256, 0, stream>>>(tf, gam2 + l * 768, bet2 + l * 768, 9216, xnf, xnb);
    // fc1: L2-chunked (gm=99, gn=24, TC=8, mpx=13 -> 8*13*24 = 2496 blocks)
    gemm_bt<EPI_GELU><<<2496, 256, 0, stream>>>(xnb, 768, wfc1_l, 768, MROWS, 768, 99, 24, 8, 13,
                                                FC1B + l * 3072, nullptr, nullptr, hb, 3072, nullptr);
    gemm_bt<EPI_FC2><<<99 * 6, 256, 0, stream>>>(hb, 3072, wfc2_l, 3072, MROWS, 3072, 99, 6, 0, 0,
                                                 FC2B + l * 768, xnf, tf, nullptr, 768, nullptr);
  }
  smln_k<<<MROWS, 256, 0, stream>>>(tf, gamN, betN, 768, (float*)d_out, nullptr);
}

// Round 15
// 5867.667 us; speedup vs baseline: 1.3041x; 1.0299x over previous
//
#include <hip/hip_runtime.h>

typedef unsigned short u16;
typedef __bf16 bf16x8 __attribute__((ext_vector_type(8)));
typedef unsigned short u16x8 __attribute__((ext_vector_type(8)));
typedef float f32x4 __attribute__((ext_vector_type(4)));

#define B_    64
#define NTOK  197
#define DIM   768
#define NH    12
#define LAY   12
#define HID_  3072
#define MROWS (B_*NTOK)   // 12608

#define EPI_BF16  0
#define EPI_PROJ  2
#define EPI_GELU  3
#define EPI_FC2   4
#define EPI_PATCH 5

__device__ __forceinline__ u16 f2bf(float f) {
  unsigned u = __float_as_uint(f);
  u += 0x7FFFu + ((u >> 16) & 1u);          // RNE
  return (u16)(u >> 16);
}
__device__ __forceinline__ float bf2f(u16 h) {
  return __uint_as_float(((unsigned)h) << 16);
}

__device__ __forceinline__ void gld_lds16(const void* g, void* l) {
  __builtin_amdgcn_global_load_lds(
      (const __attribute__((address_space(1))) void*)g,
      (__attribute__((address_space(3))) void*)l, 16, 0, 0);
}

// ---------------- diagnostic fill ----------------
__global__ void fill_k(float* __restrict__ o, float v, int n) {
  int i = blockIdx.x * blockDim.x + threadIdx.x;
  const int st = gridDim.x * blockDim.x;
  for (; i < n; i += st) o[i] = v;
}

// ---------------- f32 -> bf16 convert ----------------
__global__ void cvt_bf16(const float* __restrict__ in, u16* __restrict__ out, int n4) {
  int i = blockIdx.x * blockDim.x + threadIdx.x;
  const int st = gridDim.x * blockDim.x;
  for (; i < n4; i += st) {
    float4 v = ((const float4*)in)[i];
    ushort4 o;
    o.x = f2bf(v.x); o.y = f2bf(v.y); o.z = f2bf(v.z); o.w = f2bf(v.w);
    ((ushort4*)out)[i] = o;
  }
}

// ---------------- fused 4-way f32 -> bf16 convert ----------------
__global__ void cvt4_k(const float* __restrict__ s0, const float* __restrict__ s1,
                       const float* __restrict__ s2, const float* __restrict__ s3,
                       u16* __restrict__ d0, u16* __restrict__ d1,
                       u16* __restrict__ d2, u16* __restrict__ d3,
                       int n0, int n1, int n2, int n3)   // float4 counts
{
  int i = blockIdx.x * blockDim.x + threadIdx.x;
  const int st = gridDim.x * blockDim.x;
  const int total = n0 + n1 + n2 + n3;
  for (; i < total; i += st) {
    const float* s; u16* d; int j = i;
    if (j < n0) { s = s0; d = d0; }
    else { j -= n0;
      if (j < n1) { s = s1; d = d1; }
      else { j -= n1;
        if (j < n2) { s = s2; d = d2; }
        else { j -= n2; s = s3; d = d3; } } }
    float4 v = ((const float4*)s)[j];
    ushort4 o;
    o.x = f2bf(v.x); o.y = f2bf(v.y); o.z = f2bf(v.z); o.w = f2bf(v.w);
    ((ushort4*)d)[j] = o;
  }
}

// ---------------- im2col for patch conv ----------------
__global__ void im2col_k(const float* __restrict__ x, u16* __restrict__ out) {
  int i = blockIdx.x * blockDim.x + threadIdx.x;
  const int st = gridDim.x * blockDim.x;
  const int total = 12544 * 768;
  for (; i < total; i += st) {
    int row = i / 768, col = i - row * 768;
    int b = row / 196, pr = row - b * 196;
    int py = pr / 14, px = pr - py * 14;
    int cin = col >> 8, rr = col & 255;
    int ky = rr >> 4, kx = rr & 15;
    out[i] = f2bf(x[((b * 3 + cin) * 224 + py * 16 + ky) * 224 + px * 16 + kx]);
  }
}

// ---------------- cls token + pos embed row 0 ----------------
__global__ void clspos_k(const float* __restrict__ cls, const float* __restrict__ pos,
                         float* __restrict__ t) {
  int i = blockIdx.x * blockDim.x + threadIdx.x;
  if (i >= B_ * DIM) return;
  int b = i / DIM, d = i - b * DIM;
  t[(size_t)b * NTOK * DIM + d] = cls[d] + pos[d];
}

// ---------------- modulation (fp32, exact) ----------------
__global__ __launch_bounds__(256)
void modk(const float* __restrict__ lat, const float* __restrict__ w,
          const float* __restrict__ bias, float* __restrict__ out, int ldb)
{
  __shared__ float ls[32][65];
  __shared__ float wsm[64][33];
  const int tid = threadIdx.x;
  const int mat = blockIdx.y;
  const int n0 = blockIdx.x * 64;
  const int nl = tid & 63;
  const int bg = tid >> 6;
  float acc[16];
  #pragma unroll
  for (int j = 0; j < 16; ++j) acc[j] = 0.f;
  for (int k0 = 0; k0 < 768; k0 += 32) {
    __syncthreads();
    #pragma unroll
    for (int i = 0; i < 8; ++i) {
      int idx = tid + i * 256;
      int rr = idx >> 5, kk = idx & 31;
      ls[kk][rr]  = lat[rr * 768 + k0 + kk];
      wsm[rr][kk] = w[((size_t)mat * 768 + n0 + rr) * 768 + k0 + kk];
    }
    __syncthreads();
    #pragma unroll 4
    for (int kk = 0; kk < 32; ++kk) {
      float wv = wsm[nl][kk];
      #pragma unroll
      for (int j = 0; j < 16; ++j)
        acc[j] += ls[kk][bg * 16 + j] * wv;
    }
  }
  const float EQS = 0.036084391824351615f;    // 1/sqrt(768)
  const float* bs = bias + (size_t)mat * 768 + n0;
  #pragma unroll
  for (int j = 0; j < 16; ++j) {
    int b = bg * 16 + j;
    out[(size_t)b * ldb + mat * 768 + n0 + nl] = acc[j] * EQS + bs[nl];
  }
}

// ---------------- SelfModulatedLayerNorm apply (oF optional) ----------------
__global__ __launch_bounds__(256)
void smln_k(const float* __restrict__ x,
            const float* __restrict__ gamma, const float* __restrict__ beta, int ldg,
            float* __restrict__ oF, u16* __restrict__ oB)
{
  const int row = blockIdx.x;
  const int tid = threadIdx.x;
  const float* xr = x + (size_t)row * DIM;
  float v0 = xr[tid], v1 = xr[tid + 256], v2 = xr[tid + 512];
  float s1 = v0 + v1 + v2;
  float s2 = v0 * v0 + v1 * v1 + v2 * v2;
  #pragma unroll
  for (int o = 32; o; o >>= 1) { s1 += __shfl_xor(s1, o); s2 += __shfl_xor(s2, o); }
  __shared__ float rs[8];
  const int lane = tid & 63, wv = tid >> 6;
  if (lane == 0) { rs[wv] = s1; rs[4 + wv] = s2; }
  __syncthreads();
  s1 = rs[0] + rs[1] + rs[2] + rs[3];
  s2 = rs[4] + rs[5] + rs[6] + rs[7];
  const float mean = s1 * (1.f / 768.f);
  const float var  = s2 * (1.f / 768.f) - mean * mean;
  const float rstd = rsqrtf(var + 1e-3f);
  const int b = row / NTOK;
  const float* g  = gamma + (size_t)b * ldg;
  const float* be = beta  + (size_t)b * ldg;
  const size_t base = (size_t)row * DIM;
  float vv[3] = {v0, v1, v2};
  #pragma unroll
  for (int j = 0; j < 3; ++j) {
    int d = tid + j * 256;
    float y = (vv[j] - mean) * rstd;
    y = y * (1.f + g[d]) + be[d];
    if (oF) oF[base + d] = y;
    if (oB) oB[base + d] = f2bf(y);
  }
}

// ---------------- MFMA attention: one block per (b,h) ----------------
__global__ __launch_bounds__(256)
void attn_k(const u16* __restrict__ qkv, u16* __restrict__ ao)
{
  __shared__ u16 Ks[208 * 68];
  __shared__ u16 Vt[64 * 226];
  __shared__ u16 Ps[4][16 * 228];
  const int bh = blockIdx.x;
  const int b = bh / NH, h = bh - (bh / NH) * NH;
  const int tid = threadIdx.x;
  const int lane = tid & 63, wv = tid >> 6;
  const int lr = lane & 15, kg = lane >> 4;
  const size_t tb = (size_t)(b * NTOK) * 2304 + h * 64;

  for (int t = tid; t < 1576; t += 256) {
    int n = t >> 3, c = t & 7;
    *(u16x8*)&Ks[n * 68 + c * 8] =
        *(const u16x8*)&qkv[tb + (size_t)n * 2304 + 768 + c * 8];
  }
  for (int t = tid; t < 1576; t += 256) {
    int n = t >> 3, dc = t & 7;
    u16x8 v = *(const u16x8*)&qkv[tb + (size_t)n * 2304 + 1536 + dc * 8];
    #pragma unroll
    for (int j = 0; j < 8; ++j) Vt[(dc * 8 + j) * 226 + n] = v[j];
  }
  for (int i = tid; i < 11 * 68; i += 256) Ks[197 * 68 + i] = 0;
  for (int i = tid; i < 64 * 29; i += 256) {
    int d = i / 29, c = i - d * 29;
    Vt[d * 226 + 197 + c] = 0;
  }
  for (int i = tid; i < 4 * 16 * 20; i += 256) {
    int w = i / 320, rm = i - w * 320, r = rm / 20, c = rm - r * 20;
    Ps[w][r * 228 + 208 + c] = 0;
  }
  __syncthreads();

  const f32x4 z4 = {0.f, 0.f, 0.f, 0.f};
  u16* pw = Ps[wv];

  for (int qt = wv; qt < 13; qt += 4) {
    const int q0 = qt * 16;
    const int qrow = min(q0 + lr, 196);
    const bf16x8 aq0 = *(const bf16x8*)&qkv[tb + (size_t)qrow * 2304 + kg * 8];
    const bf16x8 aq1 = *(const bf16x8*)&qkv[tb + (size_t)qrow * 2304 + 32 + kg * 8];

    f32x4 acc[13];
    #pragma unroll
    for (int ct = 0; ct < 13; ++ct) acc[ct] = z4;
    #pragma unroll
    for (int ct = 0; ct < 13; ++ct) {
      const bf16x8 bk0 = *(const bf16x8*)&Ks[(ct * 16 + lr) * 68 + kg * 8];
      const bf16x8 bk1 = *(const bf16x8*)&Ks[(ct * 16 + lr) * 68 + 32 + kg * 8];
      acc[ct] = __builtin_amdgcn_mfma_f32_16x16x32_bf16(aq0, bk0, acc[ct], 0, 0, 0);
      acc[ct] = __builtin_amdgcn_mfma_f32_16x16x32_bf16(aq1, bk1, acc[ct], 0, 0, 0);
    }

    float mx[4], sm[4], inv[4];
    #pragma unroll
    for (int r = 0; r < 4; ++r) mx[r] = -1e30f;
    #pragma unroll
    for (int ct = 0; ct < 13; ++ct)
      #pragma unroll
      for (int r = 0; r < 4; ++r) {
        float s = acc[ct][r] * 0.125f;
        if (ct * 16 + lr >= 197) s = -1e30f;
        acc[ct][r] = s;
        mx[r] = fmaxf(mx[r], s);
      }
    #pragma unroll
    for (int o = 1; o < 16; o <<= 1)
      #pragma unroll
      for (int r = 0; r < 4; ++r) mx[r] = fmaxf(mx[r], __shfl_xor(mx[r], o));
    #pragma unroll
    for (int r = 0; r < 4; ++r) sm[r] = 0.f;
    #pragma unroll
    for (int ct = 0; ct < 13; ++ct)
      #pragma unroll
      for (int r = 0; r < 4; ++r) {
        float p = __expf(acc[ct][r] - mx[r]);
        acc[ct][r] = p;
        sm[r] += p;
      }
    #pragma unroll
    for (int o = 1; o < 16; o <<= 1)
      #pragma unroll
      for (int r = 0; r < 4; ++r) sm[r] += __shfl_xor(sm[r], o);
    #pragma unroll
    for (int r = 0; r < 4; ++r) inv[r] = 1.f / sm[r];

    #pragma unroll
    for (int ct = 0; ct < 13; ++ct)
      #pragma unroll
      for (int r = 0; r < 4; ++r)
        pw[(kg * 4 + r) * 228 + ct * 16 + lr] = f2bf(acc[ct][r]);
    asm volatile("s_waitcnt lgkmcnt(0)" ::: "memory");
    __builtin_amdgcn_sched_barrier(0);

    f32x4 accO[4];
    #pragma unroll
    for (int dt = 0; dt < 4; ++dt) accO[dt] = z4;
    #pragma unroll
    for (int kt = 0; kt < 7; ++kt) {
      const bf16x8 ap = *(const bf16x8*)&pw[lr * 228 + kt * 32 + kg * 8];
      #pragma unroll
      for (int dt = 0; dt < 4; ++dt) {
        const bf16x8 bv = *(const bf16x8*)&Vt[(dt * 16 + lr) * 226 + kt * 32 + kg * 8];
        accO[dt] = __builtin_amdgcn_mfma_f32_16x16x32_bf16(ap, bv, accO[dt], 0, 0, 0);
      }
    }

    #pragma unroll
    for (int r = 0; r < 4; ++r) {
      const int q = q0 + kg * 4 + r;
      if (q < NTOK) {
        const size_t base = ((size_t)(b * NTOK + q)) * DIM + h * 64;
        #pragma unroll
        for (int dt = 0; dt < 4; ++dt)
          ao[base + dt * 16 + lr] = f2bf(accO[dt][r] * inv[r]);
      }
    }
  }
}

// ---------------- ring gemm: BM=BN=128, 3-buffer, counted vmcnt ----------------
// TC>0 = L2-chunked hierarchical block order; TC==0 = bijective XCD swizzle.
// PROJ/FC2 residual now read as bf16 (xnb) — the single change this round.
template<int EPI>
__global__ __launch_bounds__(256)
void gemm_bt(const u16* __restrict__ A, int lda,
             const u16* __restrict__ Bw, int ldb,
             int M, int K, int gm, int gn, int TC, int mpx,
             const float* __restrict__ bias,
             const u16* __restrict__ res,
             float* __restrict__ outF, u16* __restrict__ outB, int ldo,
             const float* __restrict__ aux)
{
  __shared__ u16 SA[3][4096];   // [128 rows][32 k] x3 ring
  __shared__ u16 SB[3][4096];
  const int tid = threadIdx.x;
  const int lane = tid & 63, wv = tid >> 6;
  const int lr = lane & 15, kg = lane >> 4;
  const int wm = wv >> 1, wn = wv & 1;

  int tm, tn;
  if (TC > 0) {
    const int xcd = blockIdx.x & 7, loc = blockIdx.x >> 3;
    const int c    = loc / (mpx * TC);
    const int rem  = loc - c * (mpx * TC);
    const int mloc = rem / TC;
    tm = xcd * mpx + mloc;
    tn = c * TC + (rem - mloc * TC);
    if (tm >= gm) return;               // pad block: exits before any barrier
  } else {
    const int nwg = gridDim.x;
    const int qq = nwg >> 3, rr2 = nwg & 7;
    const int xcd = blockIdx.x & 7, loc = blockIdx.x >> 3;
    const int v = (xcd < rr2 ? xcd * (qq + 1) : rr2 * (qq + 1) + (xcd - rr2) * qq) + loc;
    tm = v / gn; tn = v - tm * gn;
  }

  const int c0 = tid, c1 = tid + 256;
  const int r0 = c0 >> 2, q0 = (c0 & 3) ^ (r0 & 3) ^ ((r0 >> 2) & 3);
  const int r1 = c1 >> 2, q1 = (c1 & 3) ^ (r1 & 3) ^ ((r1 >> 2) & 3);
  int am0 = tm * 128 + r0; if (am0 >= M) am0 = M - 1;
  int am1 = tm * 128 + r1; if (am1 >= M) am1 = M - 1;
  const u16* aS0 = A  + (size_t)am0 * lda + q0 * 8;
  const u16* aS1 = A  + (size_t)am1 * lda + q1 * 8;
  const u16* bS0 = Bw + (size_t)(tn * 128 + r0) * ldb + q0 * 8;
  const u16* bS1 = Bw + (size_t)(tn * 128 + r1) * ldb + q1 * 8;

  f32x4 acc[4][4];
  const f32x4 z = {0.f, 0.f, 0.f, 0.f};
  #pragma unroll
  for (int m = 0; m < 4; ++m)
    #pragma unroll
    for (int n = 0; n < 4; ++n) acc[m][n] = z;

#define STG(buf, ko) do { \
    u16* aD = &SA[buf][wv * 512]; u16* bD = &SB[buf][wv * 512]; \
    gld_lds16(aS0 + (ko), aD);        gld_lds16(aS1 + (ko), aD + 2048); \
    gld_lds16(bS0 + (ko), bD);        gld_lds16(bS1 + (ko), bD + 2048); \
  } while (0)

  const int KT = K >> 5;   // 24 or 96
  STG(0, 0);
  STG(1, 32);
  asm volatile("s_waitcnt vmcnt(4)" ::: "memory");
  __builtin_amdgcn_s_barrier();
  __builtin_amdgcn_sched_barrier(0);

  for (int t = 0; t < KT; ++t) {
    const int buf = t % 3;
    if (t) {
      asm volatile("s_waitcnt lgkmcnt(0)" ::: "memory");
      __builtin_amdgcn_sched_barrier(0);
      if (t + 1 < KT) asm volatile("s_waitcnt vmcnt(4)" ::: "memory");
      else            asm volatile("s_waitcnt vmcnt(0)" ::: "memory");
      __builtin_amdgcn_s_barrier();
      __builtin_amdgcn_sched_barrier(0);
    }
    if (t + 2 < KT) STG((t + 2) % 3, (t + 2) * 32);
    bf16x8 af[4], bfr[4];
    #pragma unroll
    for (int m = 0; m < 4; ++m) {
      int row = wm * 64 + m * 16 + lr;
      af[m] = *(const bf16x8*)&SA[buf][row * 32 + (((kg ^ row ^ (row >> 2)) & 3) << 3)];
    }
    #pragma unroll
    for (int n = 0; n < 4; ++n) {
      int row = wn * 64 + n * 16 + lr;
      bfr[n] = *(const bf16x8*)&SB[buf][row * 32 + (((kg ^ row ^ (row >> 2)) & 3) << 3)];
    }
    #pragma unroll
    for (int m = 0; m < 4; ++m)
      #pragma unroll
      for (int n = 0; n < 4; ++n)
        acc[m][n] = __builtin_amdgcn_mfma_f32_16x16x32_bf16(af[m], bfr[n], acc[m][n], 0, 0, 0);
  }
#undef STG
  __syncthreads();   // all waves done with LDS before epilogue reuse

  // ---- epilogue: LDS transpose -> full-line vector stores ----
  const int gr0 = tm * 128 + wm * 64;
  const int gc0 = tn * 128 + wn * 64;
  if constexpr (EPI == EPI_BF16 || EPI == EPI_GELU) {
    u16* T = (u16*)SA + wv * 1152;            // [16][72] per wave
    #pragma unroll
    for (int m = 0; m < 4; ++m) {
      #pragma unroll
      for (int n = 0; n < 4; ++n) {
        #pragma unroll
        for (int r = 0; r < 4; ++r) {
          float val = acc[m][n][r];
          if constexpr (EPI == EPI_GELU) {
            float u = val + bias[gc0 + n * 16 + lr];
            val = 0.5f * u * (1.f + erff(u * 0.70710678118654752f));
          }
          T[(kg * 4 + r) * 72 + n * 16 + lr] = f2bf(val);
        }
      }
      asm volatile("s_waitcnt lgkmcnt(0)" ::: "memory");
      __builtin_amdgcn_sched_barrier(0);
      #pragma unroll
      for (int half = 0; half < 2; ++half) {
        int row = (lane >> 3) + half * 8;
        int c8 = lane & 7;
        u16x8 vv = *(const u16x8*)&T[row * 72 + c8 * 8];
        int gr = gr0 + m * 16 + row;
        if (gr < M) *(u16x8*)&outB[(size_t)gr * ldo + gc0 + c8 * 8] = vv;
      }
      asm volatile("s_waitcnt lgkmcnt(0)" ::: "memory");   // reads done before T reuse
      __builtin_amdgcn_sched_barrier(0);
    }
  } else {
    float* T = (float*)SA + wv * 1088;        // [16][68] per wave
    #pragma unroll
    for (int m = 0; m < 4; ++m) {
      #pragma unroll
      for (int n = 0; n < 4; ++n)
        #pragma unroll
        for (int r = 0; r < 4; ++r)
          T[(kg * 4 + r) * 68 + n * 16 + lr] = acc[m][n][r];
      asm volatile("s_waitcnt lgkmcnt(0)" ::: "memory");
      __builtin_amdgcn_sched_barrier(0);
      #pragma unroll
      for (int qu = 0; qu < 4; ++qu) {
        int row = (lane >> 4) + qu * 4;
        int c4 = lane & 15;
        f32x4 vv = *(const f32x4*)&T[row * 68 + c4 * 4];
        int gr = gr0 + m * 16 + row;
        int gc = gc0 + c4 * 4;
        if (gr < M) {
          f32x4 bv = *(const f32x4*)&bias[gc];
          if constexpr (EPI == EPI_PROJ) {
            size_t o = (size_t)gr * ldo + gc;
            ushort4 rv = *(const ushort4*)&res[o];        // bf16 residual (xn)
            f32x4 ov;
            ov[0] = vv[0] + bv[0] + 2.f * bf2f(rv.x);
            ov[1] = vv[1] + bv[1] + 2.f * bf2f(rv.y);
            ov[2] = vv[2] + bv[2] + 2.f * bf2f(rv.z);
            ov[3] = vv[3] + bv[3] + 2.f * bf2f(rv.w);
            *(f32x4*)&outF[o] = ov;
          } else if constexpr (EPI == EPI_FC2) {
            size_t o = (size_t)gr * ldo + gc;
            ushort4 rv = *(const ushort4*)&res[o];        // bf16 residual (t2)
            f32x4 ov;
            ov[0] = vv[0] + bv[0] + bf2f(rv.x);
            ov[1] = vv[1] + bv[1] + bf2f(rv.y);
            ov[2] = vv[2] + bv[2] + bf2f(rv.z);
            ov[3] = vv[3] + bv[3] + bf2f(rv.w);
            *(f32x4*)&outF[o] = ov;
          } else {  // EPI_PATCH
            int pb = gr / 196, pp = gr - pb * 196;
            size_t o = ((size_t)pb * NTOK + 1 + pp) * DIM + gc;
            f32x4 av = *(const f32x4*)&aux[(size_t)(1 + pp) * DIM + gc];
            f32x4 ov;
            #pragma unroll
            for (int j = 0; j < 4; ++j) ov[j] = sinf(vv[j] + bv[j]) + av[j];
            *(f32x4*)&outF[o] = ov;
          }
        }
      }
      asm volatile("s_waitcnt lgkmcnt(0)" ::: "memory");
      __builtin_amdgcn_sched_barrier(0);
    }
  }
}

// ---------------- host ----------------
extern "C" void kernel_launch(void* const* d_in, const int* in_sizes, int n_in,
                              void* d_out, int out_size, void* d_ws, size_t ws_size,
                              hipStream_t stream)
{
  (void)in_sizes; (void)n_in;
  const float* X     = (const float*)d_in[0];
  const float* LAT   = (const float*)d_in[1];
  const float* CONVW = (const float*)d_in[2];
  const float* CONVB = (const float*)d_in[3];
  const float* CLS   = (const float*)d_in[4];
  const float* POS   = (const float*)d_in[5];
  const float* G1W   = (const float*)d_in[6];
  const float* G1B   = (const float*)d_in[7];
  const float* B1W   = (const float*)d_in[8];
  const float* B1B   = (const float*)d_in[9];
  const float* QKVW  = (const float*)d_in[10];
  const float* PROJW = (const float*)d_in[11];
  const float* PROJB = (const float*)d_in[12];
  const float* G2W   = (const float*)d_in[13];
  const float* G2B   = (const float*)d_in[14];
  const float* B2W   = (const float*)d_in[15];
  const float* B2B   = (const float*)d_in[16];
  const float* FC1W  = (const float*)d_in[17];
  const float* FC1B  = (const float*)d_in[18];
  const float* FC2W  = (const float*)d_in[19];
  const float* FC2B  = (const float*)d_in[20];
  const float* GNW   = (const float*)d_in[21];
  const float* GNB   = (const float*)d_in[22];
  const float* BNW   = (const float*)d_in[23];
  const float* BNB   = (const float*)d_in[24];

  char* p = (char*)d_ws;
  auto carve = [&](size_t bytes) { char* r = p; p += (bytes + 255) & ~(size_t)255; return r; };

  // union buffer: patches (pre-loop) / qkvb (qkv->attn) / hb (fc1->fc2)
  char* Ubuf  = carve((size_t)MROWS * HID_ * 2);            // 77.5 MB
  u16* patches = (u16*)Ubuf;
  u16* qkvb    = (u16*)Ubuf;
  u16* hb      = (u16*)Ubuf;
  u16* wconv  = (u16*)carve((size_t)768 * 768 * 2);
  u16* wqkv_l = (u16*)carve((size_t)2304 * 768 * 2);
  u16* wproj_l= (u16*)carve((size_t)768 * 768 * 2);
  u16* wfc1_l = (u16*)carve((size_t)3072 * 768 * 2);
  u16* wfc2_l = (u16*)carve((size_t)768 * 3072 * 2);
  float* tf   = (float*)carve((size_t)MROWS * 768 * 4);
  u16* xnb    = (u16*)carve((size_t)MROWS * 768 * 2);      // xn / t2 bf16 (GEMM input + residual)
  u16* aob    = (u16*)carve((size_t)MROWS * 768 * 2);
  float* gam1 = (float*)carve((size_t)B_ * 9216 * 4);
  float* bet1 = (float*)carve((size_t)B_ * 9216 * 4);
  float* gam2 = (float*)carve((size_t)B_ * 9216 * 4);
  float* bet2 = (float*)carve((size_t)B_ * 9216 * 4);
  float* gamN = (float*)carve((size_t)B_ * 768 * 4);
  float* betN = (float*)carve((size_t)B_ * 768 * 4);

  // canary: if guard returns, d_out stays 1e9 -> visible failure mode
  fill_k<<<1, 64, 0, stream>>>((float*)d_out, 1e9f, 1);
  if ((size_t)(p - (char*)d_ws) > ws_size) {
    fill_k<<<256, 256, 0, stream>>>((float*)d_out, 1e9f, out_size);
    return;
  }

  // modulation gammas/betas (fp32, exact)
  modk<<<dim3(12, 12), 256, 0, stream>>>(LAT, G1W, G1B, gam1, 9216);
  modk<<<dim3(12, 12), 256, 0, stream>>>(LAT, B1W, B1B, bet1, 9216);
  modk<<<dim3(12, 12), 256, 0, stream>>>(LAT, G2W, G2B, gam2, 9216);
  modk<<<dim3(12, 12), 256, 0, stream>>>(LAT, B2W, B2B, bet2, 9216);
  modk<<<dim3(12, 1),  256, 0, stream>>>(LAT, GNW, GNB, gamN, 768);
  modk<<<dim3(12, 1),  256, 0, stream>>>(LAT, BNW, BNB, betN, 768);

  // patch embed
  {
    int n4 = 768 * 768 / 4;
    cvt_bf16<<<(n4 + 255) / 256, 256, 0, stream>>>(CONVW, wconv, n4);
  }
  im2col_k<<<4096, 256, 0, stream>>>(X, patches);
  gemm_bt<EPI_PATCH><<<98 * 6, 256, 0, stream>>>(patches, 768, wconv, 768, 12544, 768, 98, 6, 0, 0,
                                                 CONVB, nullptr, tf, nullptr, 768, POS);
  clspos_k<<<(B_ * DIM + 255) / 256, 256, 0, stream>>>(CLS, POS, tf);

  const int n4_qkv = 2304 * 768 / 4, n4_pro = 768 * 768 / 4, n4_fc = 3072 * 768 / 4;
  for (int l = 0; l < LAY; ++l) {
    cvt4_k<<<4096, 256, 0, stream>>>(QKVW + (size_t)l * 2304 * 768, PROJW + (size_t)l * 768 * 768,
                                     FC1W + (size_t)l * 3072 * 768, FC2W + (size_t)l * 768 * 3072,
                                     wqkv_l, wproj_l, wfc1_l, wfc2_l,
                                     n4_qkv, n4_pro, n4_fc, n4_fc);
    smln_k<<<MROWS, 256, 0, stream>>>(tf, gam1 + l * 768, bet1 + l * 768, 9216, nullptr, xnb);
    // qkv: L2-chunked (gm=99, gn=18, TC=6, mpx=13)
    gemm_bt<EPI_BF16><<<1872, 256, 0, stream>>>(xnb, 768, wqkv_l, 768, MROWS, 768, 99, 18, 6, 13,
                                                nullptr, nullptr, nullptr, qkvb, 2304, nullptr);
    attn_k<<<B_ * NH, 256, 0, stream>>>(qkvb, aob);
    gemm_bt<EPI_PROJ><<<99 * 6, 256, 0, stream>>>(aob, 768, wproj_l, 768, MROWS, 768, 99, 6, 0, 0,
                                                  PROJB + l * 768, xnb, tf, nullptr, 768, nullptr);
    smln_k<<<MROWS, 256, 0, stream>>>(tf, gam2 + l * 768, bet2 + l * 768, 9216, nullptr, xnb);
    // fc1: L2-chunked (gm=99, gn=24, TC=8, mpx=13)
    gemm_bt<EPI_GELU><<<2496, 256, 0, stream>>>(xnb, 768, wfc1_l, 768, MROWS, 768, 99, 24, 8, 13,
                                                FC1B + l * 3072, nullptr, nullptr, hb, 3072, nullptr);
    gemm_bt<EPI_FC2><<<99 * 6, 256, 0, stream>>>(hb, 3072, wfc2_l, 3072, MROWS, 3072, 99, 6, 0, 0,
                                                 FC2B + l * 768, xnb, tf, nullptr, 768, nullptr);
  }
  smln_k<<<MROWS, 256, 0, stream>>>(tf, gamN, betN, 768, (float*)d_out, nullptr);
}